// Round 4
// baseline (1647.571 us; speedup 1.0000x reference)
//
#include <hip/hip_runtime.h>
#include <hip/hip_bf16.h>
#include <stdint.h>

typedef __hip_bfloat16 bf16;
typedef __attribute__((ext_vector_type(8))) short bf16x8;
typedef __attribute__((ext_vector_type(4))) float f32x4;

#define DEV static __device__ __forceinline__

DEV float b2f(bf16 v) { return __bfloat162float(v); }
DEV bf16  f2b(float v) { return __float2bfloat16(v); }

DEV void gload16(const void* g, void* l) {
  __builtin_amdgcn_global_load_lds(
      (__attribute__((address_space(1))) void*)(void*)g,
      (__attribute__((address_space(3))) void*)l, 16, 0, 0);
}

DEV f32x4 mfma16(bf16x8 a, bf16x8 b, f32x4 c) {
  return __builtin_amdgcn_mfma_f32_16x16x32_bf16(a, b, c, 0, 0, 0);
}

// XCD-chunked bijective swizzle (nwg % 8 == 0 at every call site)
DEV int xcd_swizzle(int wid, int nwg) {
  return (wid & 7) * (nwg >> 3) + (wid >> 3);
}

// ---------------- embed: x = emb[tok]*32 + pe (all f32) ----------------
__global__ __launch_bounds__(256) void embed_kernel(
    const int* __restrict__ tok, const float* __restrict__ emb,
    const float* __restrict__ pe, float* __restrict__ x)
{
  const int r = blockIdx.x, t = threadIdx.x;
  const int s = r & 1023;
  const int tk = tok[r];
  const int d = t * 4;
  const float* ep = emb + (size_t)tk * 1024 + d;
  const float* pp = pe + (size_t)s * 1024 + d;
  float* xp = x + (size_t)r * 1024 + d;
  #pragma unroll
  for (int j = 0; j < 4; ++j)
    xp[j] = ep[j] * 32.0f + pp[j];
}

// ---------------- layernorm: h = LN(x)*g + b (f32 in, bf16 out) ----------------
__global__ __launch_bounds__(256) void ln_kernel(
    const float* __restrict__ x, const float* __restrict__ g,
    const float* __restrict__ be, bf16* __restrict__ h)
{
  const int r = blockIdx.x, t = threadIdx.x;
  const float4 v = ((const float4*)(x + (size_t)r * 1024))[t];
  float s  = v.x + v.y + v.z + v.w;
  float sq = v.x * v.x + v.y * v.y + v.z * v.z + v.w * v.w;
  #pragma unroll
  for (int d = 1; d < 64; d <<= 1) {
    s  += __shfl_xor(s, d);
    sq += __shfl_xor(sq, d);
  }
  __shared__ float red[8];
  const int w = t >> 6, l = t & 63;
  if (l == 0) { red[w] = s; red[4 + w] = sq; }
  __syncthreads();
  s  = red[0] + red[1] + red[2] + red[3];
  sq = red[4] + red[5] + red[6] + red[7];
  const float mean = s * (1.0f / 1024.0f);
  const float var  = sq * (1.0f / 1024.0f) - mean * mean;
  const float inv  = 1.0f / sqrtf(var + 1e-5f);
  bf16* hp = h + (size_t)r * 1024 + t * 4;
  const float* gp = g + t * 4;
  const float* bp = be + t * 4;
  const float vv[4] = {v.x, v.y, v.z, v.w};
  #pragma unroll
  for (int j = 0; j < 4; ++j)
    hp[j] = f2b((vv[j] - mean) * inv * gp[j] + bp[j]);
}

// ------------- 64x64 transpose+cast tile body -------------
DEV void transpose_tile(const float* __restrict__ in, bf16* __restrict__ out,
                        int ldin, int ldout, int r0, int c0, int t)
{
  __shared__ bf16 tile[64][64];
  #pragma unroll
  for (int i = 0; i < 4; ++i) {
    const int r = i * 16 + (t >> 4), c = (t & 15) * 4;
    const float4 v = *(const float4*)&in[(size_t)(r0 + r) * ldin + c0 + c];
    tile[r][c + 0] = f2b(v.x);
    tile[r][c + 1] = f2b(v.y);
    tile[r][c + 2] = f2b(v.z);
    tile[r][c + 3] = f2b(v.w);
  }
  __syncthreads();
  #pragma unroll
  for (int i = 0; i < 2; ++i) {
    const int oc = i * 32 + (t >> 3);
    const int rr = (t & 7) * 8;
    unsigned short tmp[8] __attribute__((aligned(16)));
    #pragma unroll
    for (int j = 0; j < 8; ++j)
      tmp[j] = ((const unsigned short*)tile)[(rr + j) * 64 + oc];
    *(uint4*)&out[(size_t)(c0 + oc) * ldout + r0 + rr] = *(const uint4*)tmp;
  }
}

// generic single-matrix transpose+cast (used for Wout)
__global__ __launch_bounds__(256) void transpose_cast_kernel(
    const float* __restrict__ in, bf16* __restrict__ out, int ldin, int ldout)
{
  transpose_tile(in, out, ldin, ldout, blockIdx.y * 64, blockIdx.x * 64, threadIdx.x);
}

// dispatch one 64x64 tile of the per-layer weight set (3072 tiles/layer)
DEV void prep_dispatch(int wid,
    const float* Wq, const float* Wk, const float* Wv, const float* Wo,
    const float* W1, const float* W2,
    bf16* WqkvT, bf16* WoT, bf16* W1T, bf16* W2T, int t)
{
  const float* src; bf16* dst; int ldin, ldout, tx, ty;
  if (wid < 768) {
    const int m = wid >> 8, tt = wid & 255;
    src = (m == 0) ? Wq : (m == 1) ? Wk : Wv;
    dst = WqkvT + (size_t)m * 1024 * 1024;
    ldin = 1024; ldout = 1024; tx = tt & 15; ty = tt >> 4;
  } else if (wid < 1024) {
    const int tt = wid - 768;
    src = Wo; dst = WoT; ldin = 1024; ldout = 1024; tx = tt & 15; ty = tt >> 4;
  } else if (wid < 2048) {
    const int tt = wid - 1024;
    src = W1; dst = W1T; ldin = 4096; ldout = 1024; tx = tt & 63; ty = tt >> 6;
  } else {
    const int tt = wid - 2048;
    src = W2; dst = W2T; ldin = 1024; ldout = 4096; tx = tt & 15; ty = tt >> 4;
  }
  transpose_tile(src, dst, ldin, ldout, ty * 64, tx * 64, t);
}

// per-layer weight prep (fallback path)
__global__ __launch_bounds__(256) void prep_layer_kernel(
    const float* __restrict__ Wq, const float* __restrict__ Wk,
    const float* __restrict__ Wv, const float* __restrict__ Wo,
    const float* __restrict__ W1, const float* __restrict__ W2,
    bf16* __restrict__ WqkvT, bf16* __restrict__ WoT,
    bf16* __restrict__ W1T, bf16* __restrict__ W2T)
{
  prep_dispatch(blockIdx.x, Wq, Wk, Wv, Wo, W1, W2,
                WqkvT, WoT, W1T, W2T, threadIdx.x);
}

// all-layers weight prep (when ws permits): 6*3072 blocks
__global__ __launch_bounds__(256) void prep_all_kernel(
    const float* __restrict__ Wq, const float* __restrict__ Wk,
    const float* __restrict__ Wv, const float* __restrict__ Wo,
    const float* __restrict__ W1, const float* __restrict__ W2,
    bf16* __restrict__ WqkvT, bf16* __restrict__ WoT,
    bf16* __restrict__ W1T, bf16* __restrict__ W2T)
{
  const int layer = blockIdx.x / 3072;
  const int wid = blockIdx.x - layer * 3072;
  const size_t DD = (size_t)1024 * 1024, DF = (size_t)1024 * 4096;
  prep_dispatch(wid,
      Wq + layer * DD, Wk + layer * DD, Wv + layer * DD, Wo + layer * DD,
      W1 + layer * DF, W2 + layer * DF,
      WqkvT + layer * 3 * DD, WoT + layer * DD,
      W1T + layer * DF, W2T + layer * DF, threadIdx.x);
}

// ---- v transpose (bf16->bf16): vT[bh][dk][s] = qkv[b*S+s][2048+h*64+dk] ----
// grid: (S/64, B*H), block 256
__global__ __launch_bounds__(256) void transpose_v_kernel(
    const bf16* __restrict__ qkv, bf16* __restrict__ vT)
{
  __shared__ bf16 tile[64][64];
  const int t = threadIdx.x;
  const int s0 = blockIdx.x * 64;
  const int bh = blockIdx.y;
  const int b = bh >> 4, h = bh & 15;
  const bf16* in = qkv + (size_t)(b * 1024) * 3072 + 2048 + h * 64;
  #pragma unroll
  for (int i = 0; i < 2; ++i) {
    const int r = i * 32 + (t >> 3), c = (t & 7) * 8;
    *(uint4*)&tile[r][c] = *(const uint4*)&in[(size_t)(s0 + r) * 3072 + c];
  }
  __syncthreads();
  bf16* out = vT + (size_t)(bh * 64) * 1024;
  #pragma unroll
  for (int i = 0; i < 2; ++i) {
    const int oc = i * 32 + (t >> 3);   // dk
    const int rr = (t & 7) * 8;         // s offset
    unsigned short tmp[8] __attribute__((aligned(16)));
    #pragma unroll
    for (int j = 0; j < 8; ++j)
      tmp[j] = ((const unsigned short*)tile)[(rr + j) * 64 + oc];
    *(uint4*)&out[(size_t)oc * 1024 + s0 + rr] = *(const uint4*)tmp;
  }
}

// ---------------- GEMM: C(MxN) = A(MxK,row) * BT(NxK,row)^T (+epilogue) ------
// EPI: 0 = bf16 store; 1 = +bias f32 nontemporal store (logits);
//      2 = gelu(acc+bias) bf16; 3 = f32 residual atomicAdd (+bias on z==0)
// grid: (M/BM, N/128, KSLICES), block 256 (4 waves), K-slice length ksl
template<int EPI, int BM>
__global__ __launch_bounds__(256) void gemm_bt(
    const bf16* __restrict__ A, int lda,
    const bf16* __restrict__ BT, int ldb,
    void* __restrict__ Cp, int ldc,
    const float* __restrict__ bias,
    int ksl)
{
  __shared__ bf16 As[BM * 32];
  __shared__ bf16 Bs[128 * 32];
  constexpr int MR = BM / 32;           // m-fragment repeats per wave
  const int t = threadIdx.x;

  // XCD-chunked swizzle over the x-y plane (nwg_xy % 8 == 0 everywhere)
  const int nbm = gridDim.x;
  const int nwg = nbm * gridDim.y;
  int wid = blockIdx.x + nbm * blockIdx.y;
  wid = xcd_swizzle(wid, nwg);
  const int bm = wid % nbm, bn = wid / nbm;

  const int w = t >> 6, l = t & 63;
  const int wr = (w >> 1) * (BM / 2), wc = (w & 1) * 64;
  const int l15 = l & 15, l4 = l >> 4;

  const bf16* gA = A  + (size_t)(bm * BM  + (t >> 2)) * lda + (t & 3) * 8;
  const bf16* gB = BT + (size_t)(bn * 128 + (t >> 2)) * ldb + (t & 3) * 8;
  bf16* lA = As + w * 512;
  bf16* lB = Bs + w * 512;

  f32x4 acc[MR][4];
  #pragma unroll
  for (int m = 0; m < MR; ++m)
    #pragma unroll
    for (int n = 0; n < 4; ++n)
      acc[m][n] = (f32x4){0.f, 0.f, 0.f, 0.f};

  const int kbeg = blockIdx.z * ksl;
  for (int k0 = kbeg; k0 < kbeg + ksl; k0 += 32) {
    gload16(gA + k0, lA);
    if constexpr (BM == 128) gload16(gA + (size_t)64 * lda + k0, lA + 2048);
    gload16(gB + k0, lB);
    gload16(gB + (size_t)64 * ldb + k0, lB + 2048);
    __syncthreads();
    bf16x8 af[MR], bfr[4];
    #pragma unroll
    for (int m = 0; m < MR; ++m)
      af[m] = *(const bf16x8*)&As[(wr + m * 16 + l15) * 32 + l4 * 8];
    #pragma unroll
    for (int n = 0; n < 4; ++n)
      bfr[n] = *(const bf16x8*)&Bs[(wc + n * 16 + l15) * 32 + l4 * 8];
    #pragma unroll
    for (int m = 0; m < MR; ++m)
      #pragma unroll
      for (int n = 0; n < 4; ++n)
        acc[m][n] = mfma16(af[m], bfr[n], acc[m][n]);
    __syncthreads();
  }

  const int crow = bm * BM + wr, ccol = bn * 128 + wc;
  #pragma unroll
  for (int n = 0; n < 4; ++n) {
    const int col = ccol + n * 16 + l15;
    float bv = 0.f;
    if (EPI == 1 || EPI == 2) bv = bias[col];
    if (EPI == 3 && blockIdx.z == 0) bv = bias[col];
    #pragma unroll
    for (int m = 0; m < MR; ++m) {
      const int row = crow + m * 16 + l4 * 4;
      #pragma unroll
      for (int r = 0; r < 4; ++r) {
        const float v = acc[m][n][r];
        if (EPI == 0) {
          ((bf16*)Cp)[(size_t)(row + r) * ldc + col] = f2b(v);
        } else if (EPI == 1) {
          __builtin_nontemporal_store(
              v + bv, &((float*)Cp)[(size_t)(row + r) * ldc + col]);
        } else if (EPI == 2) {
          const float u = v + bv;
          const float gel = 0.5f * u * (1.0f + erff(u * 0.70710678118654752f));
          ((bf16*)Cp)[(size_t)(row + r) * ldc + col] = f2b(gel);
        } else {
          atomicAdd(&((float*)Cp)[(size_t)(row + r) * ldc + col], v + bv);
        }
      }
    }
  }
}

// ---------------- flash attention (LDS XOR-swizzled) ----------------
// grid: (S/128, B*H), block 256 (4 waves; wave w owns q-rows w*32..w*32+31)
// LDS layouts: Ks[key][c ^ ((key&7)*8)], VTs[dk][c ^ ((dk&15)*8)],
//              Ps[row][c ^ ((row&15)*8)]  (elem-index XOR, multiples of 8)
__global__ __launch_bounds__(256) void attn_kernel(
    const bf16* __restrict__ qkv, const bf16* __restrict__ vT,
    const int* __restrict__ tokens, bf16* __restrict__ ctx)
{
  __shared__ bf16 Ks[128 * 64];
  __shared__ bf16 VTs[64 * 128];
  __shared__ bf16 Ps[128 * 128];

  // XCD swizzle: 256 blocks -> each XCD gets 4 consecutive (b,h) panels
  int wid = blockIdx.x + 8 * blockIdx.y;
  wid = xcd_swizzle(wid, 256);
  const int qt = wid & 7;
  const int bh = wid >> 3;

  const int b = bh >> 4, h = bh & 15;
  const int t = threadIdx.x, w = t >> 6, l = t & 63;
  const int l15 = l & 15, l4 = l >> 4;
  const int q0 = qt * 128;

  // Q fragments in registers (each wave its own 32 rows)
  bf16x8 aq[2][2];
  #pragma unroll
  for (int m = 0; m < 2; ++m)
    #pragma unroll
    for (int ks = 0; ks < 2; ++ks)
      aq[m][ks] = *(const bf16x8*)(qkv +
          (size_t)(b * 1024 + q0 + w * 32 + m * 16 + l15) * 3072 +
          h * 64 + ks * 32 + l4 * 8);

  f32x4 o[2][4];
  float m_run[2][4], l_run[2][4];
  #pragma unroll
  for (int m = 0; m < 2; ++m)
    #pragma unroll
    for (int r = 0; r < 4; ++r) { m_run[m][r] = -1e30f; l_run[m][r] = 0.f; }
  #pragma unroll
  for (int m = 0; m < 2; ++m)
    #pragma unroll
    for (int nn = 0; nn < 4; ++nn)
      o[m][nn] = (f32x4){0.f, 0.f, 0.f, 0.f};

  const bf16* kb = qkv + (size_t)(b * 1024) * 3072 + 1024 + h * 64;
  const bf16* vb = vT + (size_t)(bh * 64) * 1024;
  const int* tb = tokens + b * 1024;

  // staging swizzle offsets (pre-swizzled GLOBAL source, linear LDS dest)
  const int kSrcCol = ((t & 7) ^ ((t >> 3) & 7)) * 8;   // K: row&7 = (t>>3)&7
  const int vSrcCol = ((t & 15) ^ (t >> 4)) * 8;        // V: row&15 = t>>4

  for (int jt = 0; jt <= qt; ++jt) {
    const int j0 = jt * 128;
    __syncthreads();  // previous iteration's LDS reads complete
    #pragma unroll
    for (int i = 0; i < 4; ++i)
      gload16(kb + (size_t)(j0 + i * 32 + (t >> 3)) * 3072 + kSrcCol,
              Ks + i * 2048 + w * 512);
    #pragma unroll
    for (int i = 0; i < 4; ++i)
      gload16(vb + (size_t)(i * 16 + (t >> 4)) * 1024 + j0 + vSrcCol,
              VTs + i * 2048 + w * 512);
    __syncthreads();  // staged tiles visible

    // S = Q K^T for this wave's 32 rows x 128 cols
    f32x4 s[2][8];
    #pragma unroll
    for (int m = 0; m < 2; ++m)
      #pragma unroll
      for (int n = 0; n < 8; ++n)
        s[m][n] = (f32x4){0.f, 0.f, 0.f, 0.f};
    #pragma unroll
    for (int ks = 0; ks < 2; ++ks) {
      #pragma unroll
      for (int n = 0; n < 8; ++n) {
        const bf16x8 bk = *(const bf16x8*)
            &Ks[(n * 16 + l15) * 64 + ((ks * 32 + l4 * 8) ^ ((l15 & 7) * 8))];
        #pragma unroll
        for (int m = 0; m < 2; ++m)
          s[m][n] = mfma16(aq[m][ks], bk, s[m][n]);
      }
    }

    // per-lane pad flags for its 8 key columns
    float padv[8];
    #pragma unroll
    for (int n = 0; n < 8; ++n)
      padv[n] = (tb[j0 + n * 16 + l15] == 0) ? 1.f : 0.f;

    // online softmax per q-row; write P to LDS (swizzled)
    #pragma unroll
    for (int m = 0; m < 2; ++m) {
      #pragma unroll
      for (int r = 0; r < 4; ++r) {
        const int rloc = l4 * 4 + r;                      // row&15 at write
        const int qrow = q0 + w * 32 + m * 16 + rloc;
        float vals[8];
        float mx = -1e30f;
        #pragma unroll
        for (int n = 0; n < 8; ++n) {
          const int jg = j0 + n * 16 + l15;
          float v = s[m][n][r] * 0.125f;
          if (jg > qrow || padv[n] != 0.f) v = -1e9f;
          vals[n] = v;
          mx = fmaxf(mx, v);
        }
        #pragma unroll
        for (int d = 1; d < 16; d <<= 1) mx = fmaxf(mx, __shfl_xor(mx, d));
        const float newm = fmaxf(m_run[m][r], mx);
        const float sc = __expf(m_run[m][r] - newm);
        m_run[m][r] = newm;
        float rs = 0.f;
        #pragma unroll
        for (int n = 0; n < 8; ++n) {
          const float pv = __expf(vals[n] - newm);
          vals[n] = pv;
          rs += pv;
        }
        #pragma unroll
        for (int d = 1; d < 16; d <<= 1) rs += __shfl_xor(rs, d);
        l_run[m][r] = l_run[m][r] * sc + rs;
        #pragma unroll
        for (int nn = 0; nn < 4; ++nn) o[m][nn][r] = o[m][nn][r] * sc;
        #pragma unroll
        for (int n = 0; n < 8; ++n)
          Ps[(w * 32 + m * 16 + rloc) * 128 +
             ((n * 16 + l15) ^ (rloc * 8))] = f2b(vals[n]);
      }
    }
    __syncthreads();  // P visible

    // O += P V
    #pragma unroll
    for (int ks = 0; ks < 4; ++ks) {
      bf16x8 ap[2];
      #pragma unroll
      for (int m = 0; m < 2; ++m)
        ap[m] = *(const bf16x8*)
            &Ps[(w * 32 + m * 16 + l15) * 128 + ((ks * 32 + l4 * 8) ^ (l15 * 8))];
      #pragma unroll
      for (int nn = 0; nn < 4; ++nn) {
        const bf16x8 bv = *(const bf16x8*)
            &VTs[(nn * 16 + l15) * 128 + ((ks * 32 + l4 * 8) ^ (l15 * 8))];
        #pragma unroll
        for (int m = 0; m < 2; ++m)
          o[m][nn] = mfma16(ap[m], bv, o[m][nn]);
      }
    }
  }

  // epilogue: ctx = O / l
  #pragma unroll
  for (int m = 0; m < 2; ++m) {
    #pragma unroll
    for (int r = 0; r < 4; ++r) {
      const float inv = 1.0f / l_run[m][r];
      const int qrow = q0 + w * 32 + m * 16 + l4 * 4 + r;
      #pragma unroll
      for (int nn = 0; nn < 4; ++nn)
        ctx[(size_t)(b * 1024 + qrow) * 1024 + h * 64 + nn * 16 + l15] =
            f2b(o[m][nn][r] * inv);
    }
  }
}

// ------------- fixup for all-masked rows (leading pad tokens) -------------
__global__ __launch_bounds__(64) void attn_fixup_kernel(
    const int* __restrict__ tokens, const bf16* __restrict__ vT,
    bf16* __restrict__ ctx)
{
  const int bh = blockIdx.x;
  const int b = bh >> 4, h = bh & 15;
  __shared__ int p0s;
  if (threadIdx.x == 0) {
    int p = 0;
    const int* tb = tokens + b * 1024;
    while (p < 1024 && tb[p] == 0) ++p;
    p0s = p;
  }
  __syncthreads();
  const int P0 = p0s;
  if (P0 == 0) return;
  const int dk = threadIdx.x;
  const bf16* vrow = vT + (size_t)(bh * 64 + dk) * 1024;
  float sum = 0.f;
  for (int sIdx = 0; sIdx < 1024; ++sIdx) sum += b2f(vrow[sIdx]);
  const bf16 mv = f2b(sum * (1.0f / 1024.0f));
  for (int q = 0; q < P0; ++q)
    ctx[(size_t)(b * 1024 + q) * 1024 + h * 64 + dk] = mv;
}

// ---------------- host ----------------
extern "C" void kernel_launch(void* const* d_in, const int* in_sizes, int n_in,
                              void* d_out, int out_size, void* d_ws, size_t ws_size,
                              hipStream_t stream)
{
  (void)in_sizes; (void)n_in; (void)out_size;
  const int*   tokens = (const int*)d_in[0];
  const float* emb  = (const float*)d_in[1];
  const float* pe   = (const float*)d_in[2];
  const float* Wq   = (const float*)d_in[3];
  const float* Wk   = (const float*)d_in[4];
  const float* Wv   = (const float*)d_in[5];
  const float* Wo   = (const float*)d_in[6];
  const float* bo   = (const float*)d_in[7];
  const float* g1   = (const float*)d_in[8];
  const float* be1  = (const float*)d_in[9];
  const float* g2   = (const float*)d_in[10];
  const float* be2  = (const float*)d_in[11];
  const float* W1   = (const float*)d_in[12];
  const float* b1   = (const float*)d_in[13];
  const float* W2   = (const float*)d_in[14];
  const float* b2   = (const float*)d_in[15];
  const float* gf   = (const float*)d_in[16];
  const float* bff  = (const float*)d_in[17];
  const float* Wout = (const float*)d_in[18];
  const float* bout = (const float*)d_in[19];
  float* out = (float*)d_out;

  char* p = (char*)d_ws;
  auto alloc = [&](size_t bytes) {
    char* q = p;
    p += (bytes + 255) & ~(size_t)255;
    return q;
  };
  float* x    = (float*)alloc((size_t)2048 * 1024 * 4);
  bf16* h     = (bf16*)alloc((size_t)2048 * 1024 * 2);
  bf16* qkv   = (bf16*)alloc((size_t)2048 * 3072 * 2);
  bf16* vT    = (bf16*)alloc((size_t)2048 * 1024 * 2);
  bf16* ctx   = (bf16*)alloc((size_t)2048 * 1024 * 2);
  bf16* ff    = (bf16*)alloc((size_t)2048 * 4096 * 2);
  bf16* WoutT = (bf16*)alloc((size_t)32000 * 1024 * 2);

  const size_t DD = (size_t)1024 * 1024;
  const size_t DF = (size_t)1024 * 4096;

  // weight buffers: all-layers if workspace permits, else per-layer reuse
  const size_t perLayerW = (3 * DD + DD + DF + DF) * 2;  // bytes per layer
  const size_t used = (size_t)(p - (char*)d_ws);
  const bool fullprep = ws_size >= used + 6 * perLayerW + 8192;
  const int NL = fullprep ? 6 : 1;
  bf16* WqkvT = (bf16*)alloc((size_t)NL * 3 * DD * 2);
  bf16* WoT   = (bf16*)alloc((size_t)NL * DD * 2);
  bf16* W1T   = (bf16*)alloc((size_t)NL * DF * 2);
  bf16* W2T   = (bf16*)alloc((size_t)NL * DF * 2);

  if (fullprep)
    prep_all_kernel<<<6 * 3072, 256, 0, stream>>>(
        Wq, Wk, Wv, Wo, W1, W2, WqkvT, WoT, W1T, W2T);

  embed_kernel<<<2048, 256, 0, stream>>>(tokens, emb, pe, x);

  for (int l = 0; l < 6; ++l) {
    const bf16* wqkvt; const bf16* wot; const bf16* w1t; const bf16* w2t;
    if (fullprep) {
      wqkvt = WqkvT + (size_t)l * 3 * DD;
      wot   = WoT   + (size_t)l * DD;
      w1t   = W1T   + (size_t)l * DF;
      w2t   = W2T   + (size_t)l * DF;
    } else {
      prep_layer_kernel<<<3072, 256, 0, stream>>>(
          Wq + l * DD, Wk + l * DD, Wv + l * DD, Wo + l * DD,
          W1 + l * DF, W2 + l * DF, WqkvT, WoT, W1T, W2T);
      wqkvt = WqkvT; wot = WoT; w1t = W1T; w2t = W2T;
    }

    ln_kernel<<<2048, 256, 0, stream>>>(x, g1 + l * 1024, be1 + l * 1024, h);
    // QKV: M=2048 N=3072 K=1024, BM=64 -> 768 blocks (3/CU)
    gemm_bt<0, 64><<<dim3(32, 24, 1), 256, 0, stream>>>(
        h, 1024, wqkvt, 1024, qkv, 3072, (const float*)nullptr, 1024);
    transpose_v_kernel<<<dim3(16, 32), 256, 0, stream>>>(qkv, vT);
    attn_kernel<<<dim3(8, 32), 256, 0, stream>>>(qkv, vT, tokens, ctx);
    attn_fixup_kernel<<<32, 64, 0, stream>>>(tokens, vT, ctx);
    // Wo: M=2048 N=1024 K=1024, BM=64 + splitK2 -> 512 blocks (2/CU)
    gemm_bt<3, 64><<<dim3(32, 8, 2), 256, 0, stream>>>(
        ctx, 1024, wot, 1024, x, 1024, bo + l * 1024, 512);
    ln_kernel<<<2048, 256, 0, stream>>>(x, g2 + l * 1024, be2 + l * 1024, h);
    // FFN1: M=2048 N=4096 K=1024, BM=128 -> 512 blocks (2/CU)
    gemm_bt<2, 128><<<dim3(16, 32, 1), 256, 0, stream>>>(
        h, 1024, w1t, 1024, ff, 4096, b1 + l * 4096, 1024);
    // FFN2: M=2048 N=1024 K=4096, BM=128 + splitK4 -> 512 blocks (2/CU)
    gemm_bt<3, 128><<<dim3(16, 8, 4), 256, 0, stream>>>(
        ff, 4096, w2t, 4096, x, 1024, b2 + l * 1024, 1024);
  }

  ln_kernel<<<2048, 256, 0, stream>>>(x, gf, bff, h);
  transpose_cast_kernel<<<dim3(500, 16), 256, 0, stream>>>(Wout, WoutT, 32000, 1024);
  // logits: M=2048 N=32000 K=1024, BM=128 -> 4000 blocks (swizzled)
  gemm_bt<1, 128><<<dim3(16, 250, 1), 256, 0, stream>>>(
      h, 1024, WoutT, 1024, out, 32000, bout, 1024);
}

// Round 5
// 1602.558 us; speedup vs baseline: 1.0281x; 1.0281x over previous
//
#include <hip/hip_runtime.h>
#include <hip/hip_bf16.h>
#include <stdint.h>

typedef __hip_bfloat16 bf16;
typedef __attribute__((ext_vector_type(8))) short bf16x8;
typedef __attribute__((ext_vector_type(4))) float f32x4;

#define DEV static __device__ __forceinline__

DEV float b2f(bf16 v) { return __bfloat162float(v); }
DEV bf16  f2b(float v) { return __float2bfloat16(v); }

DEV void gload16(const void* g, void* l) {
  __builtin_amdgcn_global_load_lds(
      (__attribute__((address_space(1))) void*)(void*)g,
      (__attribute__((address_space(3))) void*)l, 16, 0, 0);
}

DEV f32x4 mfma16(bf16x8 a, bf16x8 b, f32x4 c) {
  return __builtin_amdgcn_mfma_f32_16x16x32_bf16(a, b, c, 0, 0, 0);
}

// ---------------- embed: x = emb[tok]*32 + pe (all f32) ----------------
__global__ __launch_bounds__(256) void embed_kernel(
    const int* __restrict__ tok, const float* __restrict__ emb,
    const float* __restrict__ pe, float* __restrict__ x)
{
  const int r = blockIdx.x, t = threadIdx.x;
  const int s = r & 1023;
  const int tk = tok[r];
  const int d = t * 4;
  const float* ep = emb + (size_t)tk * 1024 + d;
  const float* pp = pe + (size_t)s * 1024 + d;
  float* xp = x + (size_t)r * 1024 + d;
  #pragma unroll
  for (int j = 0; j < 4; ++j)
    xp[j] = ep[j] * 32.0f + pp[j];
}

// ---------------- layernorm: h = LN(x)*g + b (f32 in, bf16 out) ----------------
__global__ __launch_bounds__(256) void ln_kernel(
    const float* __restrict__ x, const float* __restrict__ g,
    const float* __restrict__ be, bf16* __restrict__ h)
{
  const int r = blockIdx.x, t = threadIdx.x;
  const float4 v = ((const float4*)(x + (size_t)r * 1024))[t];
  float s  = v.x + v.y + v.z + v.w;
  float sq = v.x * v.x + v.y * v.y + v.z * v.z + v.w * v.w;
  #pragma unroll
  for (int d = 1; d < 64; d <<= 1) {
    s  += __shfl_xor(s, d);
    sq += __shfl_xor(sq, d);
  }
  __shared__ float red[8];
  const int w = t >> 6, l = t & 63;
  if (l == 0) { red[w] = s; red[4 + w] = sq; }
  __syncthreads();
  s  = red[0] + red[1] + red[2] + red[3];
  sq = red[4] + red[5] + red[6] + red[7];
  const float mean = s * (1.0f / 1024.0f);
  const float var  = sq * (1.0f / 1024.0f) - mean * mean;
  const float inv  = 1.0f / sqrtf(var + 1e-5f);
  bf16* hp = h + (size_t)r * 1024 + t * 4;
  const float* gp = g + t * 4;
  const float* bp = be + t * 4;
  const float vv[4] = {v.x, v.y, v.z, v.w};
  #pragma unroll
  for (int j = 0; j < 4; ++j)
    hp[j] = f2b((vv[j] - mean) * inv * gp[j] + bp[j]);
}

// ------------- 64x64 transpose+cast tile body -------------
DEV void transpose_tile(const float* __restrict__ in, bf16* __restrict__ out,
                        int ldin, int ldout, int r0, int c0, int t)
{
  __shared__ bf16 tile[64][64];
  #pragma unroll
  for (int i = 0; i < 4; ++i) {
    const int r = i * 16 + (t >> 4), c = (t & 15) * 4;
    const float4 v = *(const float4*)&in[(size_t)(r0 + r) * ldin + c0 + c];
    tile[r][c + 0] = f2b(v.x);
    tile[r][c + 1] = f2b(v.y);
    tile[r][c + 2] = f2b(v.z);
    tile[r][c + 3] = f2b(v.w);
  }
  __syncthreads();
  #pragma unroll
  for (int i = 0; i < 2; ++i) {
    const int oc = i * 32 + (t >> 3);
    const int rr = (t & 7) * 8;
    unsigned short tmp[8] __attribute__((aligned(16)));
    #pragma unroll
    for (int j = 0; j < 8; ++j)
      tmp[j] = ((const unsigned short*)tile)[(rr + j) * 64 + oc];
    *(uint4*)&out[(size_t)(c0 + oc) * ldout + r0 + rr] = *(const uint4*)tmp;
  }
}

// generic single-matrix transpose+cast (used for Wout)
__global__ __launch_bounds__(256) void transpose_cast_kernel(
    const float* __restrict__ in, bf16* __restrict__ out, int ldin, int ldout)
{
  transpose_tile(in, out, ldin, ldout, blockIdx.y * 64, blockIdx.x * 64, threadIdx.x);
}

// dispatch one 64x64 tile of the per-layer weight set (3072 tiles/layer)
DEV void prep_dispatch(int wid,
    const float* Wq, const float* Wk, const float* Wv, const float* Wo,
    const float* W1, const float* W2,
    bf16* WqkvT, bf16* WoT, bf16* W1T, bf16* W2T, int t)
{
  const float* src; bf16* dst; int ldin, ldout, tx, ty;
  if (wid < 768) {
    const int m = wid >> 8, tt = wid & 255;
    src = (m == 0) ? Wq : (m == 1) ? Wk : Wv;
    dst = WqkvT + (size_t)m * 1024 * 1024;
    ldin = 1024; ldout = 1024; tx = tt & 15; ty = tt >> 4;
  } else if (wid < 1024) {
    const int tt = wid - 768;
    src = Wo; dst = WoT; ldin = 1024; ldout = 1024; tx = tt & 15; ty = tt >> 4;
  } else if (wid < 2048) {
    const int tt = wid - 1024;
    src = W1; dst = W1T; ldin = 4096; ldout = 1024; tx = tt & 63; ty = tt >> 6;
  } else {
    const int tt = wid - 2048;
    src = W2; dst = W2T; ldin = 1024; ldout = 4096; tx = tt & 15; ty = tt >> 4;
  }
  transpose_tile(src, dst, ldin, ldout, ty * 64, tx * 64, t);
}

// per-layer weight prep (fallback path)
__global__ __launch_bounds__(256) void prep_layer_kernel(
    const float* __restrict__ Wq, const float* __restrict__ Wk,
    const float* __restrict__ Wv, const float* __restrict__ Wo,
    const float* __restrict__ W1, const float* __restrict__ W2,
    bf16* __restrict__ WqkvT, bf16* __restrict__ WoT,
    bf16* __restrict__ W1T, bf16* __restrict__ W2T)
{
  prep_dispatch(blockIdx.x, Wq, Wk, Wv, Wo, W1, W2,
                WqkvT, WoT, W1T, W2T, threadIdx.x);
}

// all-layers weight prep (when ws permits): 6*3072 blocks
__global__ __launch_bounds__(256) void prep_all_kernel(
    const float* __restrict__ Wq, const float* __restrict__ Wk,
    const float* __restrict__ Wv, const float* __restrict__ Wo,
    const float* __restrict__ W1, const float* __restrict__ W2,
    bf16* __restrict__ WqkvT, bf16* __restrict__ WoT,
    bf16* __restrict__ W1T, bf16* __restrict__ W2T)
{
  const int layer = blockIdx.x / 3072;
  const int wid = blockIdx.x - layer * 3072;
  const size_t DD = (size_t)1024 * 1024, DF = (size_t)1024 * 4096;
  prep_dispatch(wid,
      Wq + layer * DD, Wk + layer * DD, Wv + layer * DD, Wo + layer * DD,
      W1 + layer * DF, W2 + layer * DF,
      WqkvT + layer * 3 * DD, WoT + layer * DD,
      W1T + layer * DF, W2T + layer * DF, threadIdx.x);
}

// ---- v transpose (bf16->bf16): vT[bh][dk][s] = qkv[b*S+s][2048+h*64+dk] ----
// grid: (S/64, B*H), block 256
__global__ __launch_bounds__(256) void transpose_v_kernel(
    const bf16* __restrict__ qkv, bf16* __restrict__ vT)
{
  __shared__ bf16 tile[64][64];
  const int t = threadIdx.x;
  const int s0 = blockIdx.x * 64;
  const int bh = blockIdx.y;
  const int b = bh >> 4, h = bh & 15;
  const bf16* in = qkv + (size_t)(b * 1024) * 3072 + 2048 + h * 64;
  #pragma unroll
  for (int i = 0; i < 2; ++i) {
    const int r = i * 32 + (t >> 3), c = (t & 7) * 8;
    *(uint4*)&tile[r][c] = *(const uint4*)&in[(size_t)(s0 + r) * 3072 + c];
  }
  __syncthreads();
  bf16* out = vT + (size_t)(bh * 64) * 1024;
  #pragma unroll
  for (int i = 0; i < 2; ++i) {
    const int oc = i * 32 + (t >> 3);   // dk
    const int rr = (t & 7) * 8;         // s offset
    unsigned short tmp[8] __attribute__((aligned(16)));
    #pragma unroll
    for (int j = 0; j < 8; ++j)
      tmp[j] = ((const unsigned short*)tile)[(rr + j) * 64 + oc];
    *(uint4*)&out[(size_t)oc * 1024 + s0 + rr] = *(const uint4*)tmp;
  }
}

// ------------- pipelined GEMM: C(MxN) = A(MxK,row) * BT(NxK,row)^T -------------
// 3-buffer LDS, 2-tiles-ahead prefetch, counted vmcnt (T4), raw barriers.
// EPI: 0 = bf16 store; 1 = +bias f32 store (logits); 2 = gelu(acc+bias) bf16;
//      3 = f32 residual atomicAdd (+bias on z==0)
// grid: (M/BM, N/128, KSLICES), block 256 (4 waves), K-slice length ksl (mult of 96? no: >=96 and mult of 32)
template<int EPI, int BM, int SWZ>
__global__ __launch_bounds__(256) void gemm_pl(
    const bf16* __restrict__ A, int lda,
    const bf16* __restrict__ BT, int ldb,
    void* __restrict__ Cp, int ldc,
    const float* __restrict__ bias,
    int ksl)
{
  constexpr int ABUF = BM * 32;               // elems per A buffer
  constexpr int MR = BM / 32;                 // m-fragment repeats per wave
  __shared__ bf16 As[3 * ABUF];
  __shared__ bf16 Bs[3 * 4096];
  const int t = threadIdx.x;

  int bm, bn;
  if constexpr (SWZ) {                        // XCD-chunked swizzle (nwg%8==0)
    const int nbm = gridDim.x;
    const int nwg = nbm * gridDim.y;
    int wid = blockIdx.x + nbm * blockIdx.y;
    wid = (wid & 7) * (nwg >> 3) + (wid >> 3);
    bm = wid % nbm; bn = wid / nbm;
  } else {
    bm = blockIdx.x; bn = blockIdx.y;
  }

  const int w = t >> 6, l = t & 63;
  const int wr = (w >> 1) * (BM / 2), wc = (w & 1) * 64;
  const int l15 = l & 15, l4 = l >> 4;
  const int kbeg = blockIdx.z * ksl;
  const int ntiles = ksl >> 5;

  const bf16* gA = A  + (size_t)(bm * BM  + (t >> 2)) * lda + (t & 3) * 8 + kbeg;
  const bf16* gB = BT + (size_t)(bn * 128 + (t >> 2)) * ldb + (t & 3) * 8 + kbeg;
  bf16* lA = As + w * 512;
  bf16* lB = Bs + w * 512;

  auto stage = [&](int tile, int buf) {
    const int k0 = tile * 32;
    gload16(gA + k0, lA + buf * ABUF);
    if constexpr (BM == 128)
      gload16(gA + (size_t)64 * lda + k0, lA + buf * ABUF + 2048);
    gload16(gB + k0, lB + buf * 4096);
    gload16(gB + (size_t)64 * ldb + k0, lB + buf * 4096 + 2048);
  };

  f32x4 acc[MR][4];
  #pragma unroll
  for (int m = 0; m < MR; ++m)
    #pragma unroll
    for (int n = 0; n < 4; ++n)
      acc[m][n] = (f32x4){0.f, 0.f, 0.f, 0.f};

  stage(0, 0);
  stage(1, 1);

  int buf = 0;
  for (int kt = 0; kt < ntiles; ++kt) {
    // issue prefetch of tile kt+2 into buf (kt+2)%3 (dead since iter kt-1),
    // then wait so tile kt's loads are landed; kt+1, kt+2 stay in flight.
    if (kt + 2 < ntiles) {
      int pb = buf + 2; if (pb >= 3) pb -= 3;
      stage(kt + 2, pb);
      __builtin_amdgcn_sched_barrier(0);
      if constexpr (BM == 128) asm volatile("s_waitcnt vmcnt(8)" ::: "memory");
      else                     asm volatile("s_waitcnt vmcnt(6)" ::: "memory");
    } else if (kt + 1 < ntiles) {
      if constexpr (BM == 128) asm volatile("s_waitcnt vmcnt(4)" ::: "memory");
      else                     asm volatile("s_waitcnt vmcnt(3)" ::: "memory");
    } else {
      asm volatile("s_waitcnt vmcnt(0)" ::: "memory");
    }
    __builtin_amdgcn_s_barrier();          // all waves: tile kt resident
    __builtin_amdgcn_sched_barrier(0);     // no ds_read hoists above barrier

    const bf16* Ab = As + buf * ABUF;
    const bf16* Bb = Bs + buf * 4096;
    bf16x8 af[MR], bfr[4];
    #pragma unroll
    for (int m = 0; m < MR; ++m)
      af[m] = *(const bf16x8*)&Ab[(wr + m * 16 + l15) * 32 + l4 * 8];
    #pragma unroll
    for (int n = 0; n < 4; ++n)
      bfr[n] = *(const bf16x8*)&Bb[(wc + n * 16 + l15) * 32 + l4 * 8];
    #pragma unroll
    for (int m = 0; m < MR; ++m)
      #pragma unroll
      for (int n = 0; n < 4; ++n)
        acc[m][n] = mfma16(af[m], bfr[n], acc[m][n]);

    __builtin_amdgcn_sched_barrier(0);     // reads stay before barrier
    __builtin_amdgcn_s_barrier();          // buf kt now dead for overwrite
    if (++buf >= 3) buf = 0;
  }

  const int crow = bm * BM + wr, ccol = bn * 128 + wc;
  #pragma unroll
  for (int n = 0; n < 4; ++n) {
    const int col = ccol + n * 16 + l15;
    float bv = 0.f;
    if (EPI == 1 || EPI == 2) bv = bias[col];
    if (EPI == 3 && blockIdx.z == 0) bv = bias[col];
    #pragma unroll
    for (int m = 0; m < MR; ++m) {
      const int row = crow + m * 16 + l4 * 4;
      #pragma unroll
      for (int r = 0; r < 4; ++r) {
        const float v = acc[m][n][r];
        if (EPI == 0) {
          ((bf16*)Cp)[(size_t)(row + r) * ldc + col] = f2b(v);
        } else if (EPI == 1) {
          ((float*)Cp)[(size_t)(row + r) * ldc + col] = v + bv;
        } else if (EPI == 2) {
          const float u = v + bv;
          const float gel = 0.5f * u * (1.0f + erff(u * 0.70710678118654752f));
          ((bf16*)Cp)[(size_t)(row + r) * ldc + col] = f2b(gel);
        } else {
          atomicAdd(&((float*)Cp)[(size_t)(row + r) * ldc + col], v + bv);
        }
      }
    }
  }
}

// ---------------- flash attention (LDS XOR-swizzled) ----------------
// grid: (S/128, B*H), block 256 (4 waves; wave w owns q-rows w*32..w*32+31)
__global__ __launch_bounds__(256) void attn_kernel(
    const bf16* __restrict__ qkv, const bf16* __restrict__ vT,
    const int* __restrict__ tokens, bf16* __restrict__ ctx)
{
  __shared__ bf16 Ks[128 * 64];
  __shared__ bf16 VTs[64 * 128];
  __shared__ bf16 Ps[128 * 128];

  const int qt = blockIdx.x;
  const int bh = blockIdx.y;
  const int b = bh >> 4, h = bh & 15;
  const int t = threadIdx.x, w = t >> 6, l = t & 63;
  const int l15 = l & 15, l4 = l >> 4;
  const int q0 = qt * 128;

  bf16x8 aq[2][2];
  #pragma unroll
  for (int m = 0; m < 2; ++m)
    #pragma unroll
    for (int ks = 0; ks < 2; ++ks)
      aq[m][ks] = *(const bf16x8*)(qkv +
          (size_t)(b * 1024 + q0 + w * 32 + m * 16 + l15) * 3072 +
          h * 64 + ks * 32 + l4 * 8);

  f32x4 o[2][4];
  float m_run[2][4], l_run[2][4];
  #pragma unroll
  for (int m = 0; m < 2; ++m)
    #pragma unroll
    for (int r = 0; r < 4; ++r) { m_run[m][r] = -1e30f; l_run[m][r] = 0.f; }
  #pragma unroll
  for (int m = 0; m < 2; ++m)
    #pragma unroll
    for (int nn = 0; nn < 4; ++nn)
      o[m][nn] = (f32x4){0.f, 0.f, 0.f, 0.f};

  const bf16* kb = qkv + (size_t)(b * 1024) * 3072 + 1024 + h * 64;
  const bf16* vb = vT + (size_t)(bh * 64) * 1024;
  const int* tb = tokens + b * 1024;

  const int kSrcCol = ((t & 7) ^ ((t >> 3) & 7)) * 8;
  const int vSrcCol = ((t & 15) ^ (t >> 4)) * 8;

  for (int jt = 0; jt <= qt; ++jt) {
    const int j0 = jt * 128;
    __syncthreads();
    #pragma unroll
    for (int i = 0; i < 4; ++i)
      gload16(kb + (size_t)(j0 + i * 32 + (t >> 3)) * 3072 + kSrcCol,
              Ks + i * 2048 + w * 512);
    #pragma unroll
    for (int i = 0; i < 4; ++i)
      gload16(vb + (size_t)(i * 16 + (t >> 4)) * 1024 + j0 + vSrcCol,
              VTs + i * 2048 + w * 512);
    __syncthreads();

    f32x4 s[2][8];
    #pragma unroll
    for (int m = 0; m < 2; ++m)
      #pragma unroll
      for (int n = 0; n < 8; ++n)
        s[m][n] = (f32x4){0.f, 0.f, 0.f, 0.f};
    #pragma unroll
    for (int ks = 0; ks < 2; ++ks) {
      #pragma unroll
      for (int n = 0; n < 8; ++n) {
        const bf16x8 bk = *(const bf16x8*)
            &Ks[(n * 16 + l15) * 64 + ((ks * 32 + l4 * 8) ^ ((l15 & 7) * 8))];
        #pragma unroll
        for (int m = 0; m < 2; ++m)
          s[m][n] = mfma16(aq[m][ks], bk, s[m][n]);
      }
    }

    float padv[8];
    #pragma unroll
    for (int n = 0; n < 8; ++n)
      padv[n] = (tb[j0 + n * 16 + l15] == 0) ? 1.f : 0.f;

    #pragma unroll
    for (int m = 0; m < 2; ++m) {
      #pragma unroll
      for (int r = 0; r < 4; ++r) {
        const int rloc = l4 * 4 + r;
        const int qrow = q0 + w * 32 + m * 16 + rloc;
        float vals[8];
        float mx = -1e30f;
        #pragma unroll
        for (int n = 0; n < 8; ++n) {
          const int jg = j0 + n * 16 + l15;
          float v = s[m][n][r] * 0.125f;
          if (jg > qrow || padv[n] != 0.f) v = -1e9f;
          vals[n] = v;
          mx = fmaxf(mx, v);
        }
        #pragma unroll
        for (int d = 1; d < 16; d <<= 1) mx = fmaxf(mx, __shfl_xor(mx, d));
        const float newm = fmaxf(m_run[m][r], mx);
        const float sc = __expf(m_run[m][r] - newm);
        m_run[m][r] = newm;
        float rs = 0.f;
        #pragma unroll
        for (int n = 0; n < 8; ++n) {
          const float pv = __expf(vals[n] - newm);
          vals[n] = pv;
          rs += pv;
        }
        #pragma unroll
        for (int d = 1; d < 16; d <<= 1) rs += __shfl_xor(rs, d);
        l_run[m][r] = l_run[m][r] * sc + rs;
        #pragma unroll
        for (int nn = 0; nn < 4; ++nn) o[m][nn][r] = o[m][nn][r] * sc;
        #pragma unroll
        for (int n = 0; n < 8; ++n)
          Ps[(w * 32 + m * 16 + rloc) * 128 +
             ((n * 16 + l15) ^ (rloc * 8))] = f2b(vals[n]);
      }
    }
    __syncthreads();

    #pragma unroll
    for (int ks = 0; ks < 4; ++ks) {
      bf16x8 ap[2];
      #pragma unroll
      for (int m = 0; m < 2; ++m)
        ap[m] = *(const bf16x8*)
            &Ps[(w * 32 + m * 16 + l15) * 128 + ((ks * 32 + l4 * 8) ^ (l15 * 8))];
      #pragma unroll
      for (int nn = 0; nn < 4; ++nn) {
        const bf16x8 bv = *(const bf16x8*)
            &VTs[(nn * 16 + l15) * 128 + ((ks * 32 + l4 * 8) ^ (l15 * 8))];
        #pragma unroll
        for (int m = 0; m < 2; ++m)
          o[m][nn] = mfma16(ap[m], bv, o[m][nn]);
      }
    }
  }

  #pragma unroll
  for (int m = 0; m < 2; ++m) {
    #pragma unroll
    for (int r = 0; r < 4; ++r) {
      const float inv = 1.0f / l_run[m][r];
      const int qrow = q0 + w * 32 + m * 16 + l4 * 4 + r;
      #pragma unroll
      for (int nn = 0; nn < 4; ++nn)
        ctx[(size_t)(b * 1024 + qrow) * 1024 + h * 64 + nn * 16 + l15] =
            f2b(o[m][nn][r] * inv);
    }
  }
}

// ------------- fixup for all-masked rows (leading pad tokens) -------------
__global__ __launch_bounds__(64) void attn_fixup_kernel(
    const int* __restrict__ tokens, const bf16* __restrict__ vT,
    bf16* __restrict__ ctx)
{
  const int bh = blockIdx.x;
  const int b = bh >> 4, h = bh & 15;
  __shared__ int p0s;
  if (threadIdx.x == 0) {
    int p = 0;
    const int* tb = tokens + b * 1024;
    while (p < 1024 && tb[p] == 0) ++p;
    p0s = p;
  }
  __syncthreads();
  const int P0 = p0s;
  if (P0 == 0) return;
  const int dk = threadIdx.x;
  const bf16* vrow = vT + (size_t)(bh * 64 + dk) * 1024;
  float sum = 0.f;
  for (int sIdx = 0; sIdx < 1024; ++sIdx) sum += b2f(vrow[sIdx]);
  const bf16 mv = f2b(sum * (1.0f / 1024.0f));
  for (int q = 0; q < P0; ++q)
    ctx[(size_t)(b * 1024 + q) * 1024 + h * 64 + dk] = mv;
}

// ---------------- host ----------------
extern "C" void kernel_launch(void* const* d_in, const int* in_sizes, int n_in,
                              void* d_out, int out_size, void* d_ws, size_t ws_size,
                              hipStream_t stream)
{
  (void)in_sizes; (void)n_in; (void)out_size;
  const int*   tokens = (const int*)d_in[0];
  const float* emb  = (const float*)d_in[1];
  const float* pe   = (const float*)d_in[2];
  const float* Wq   = (const float*)d_in[3];
  const float* Wk   = (const float*)d_in[4];
  const float* Wv   = (const float*)d_in[5];
  const float* Wo   = (const float*)d_in[6];
  const float* bo   = (const float*)d_in[7];
  const float* g1   = (const float*)d_in[8];
  const float* be1  = (const float*)d_in[9];
  const float* g2   = (const float*)d_in[10];
  const float* be2  = (const float*)d_in[11];
  const float* W1   = (const float*)d_in[12];
  const float* b1   = (const float*)d_in[13];
  const float* W2   = (const float*)d_in[14];
  const float* b2   = (const float*)d_in[15];
  const float* gf   = (const float*)d_in[16];
  const float* bff  = (const float*)d_in[17];
  const float* Wout = (const float*)d_in[18];
  const float* bout = (const float*)d_in[19];
  float* out = (float*)d_out;

  char* p = (char*)d_ws;
  auto alloc = [&](size_t bytes) {
    char* q = p;
    p += (bytes + 255) & ~(size_t)255;
    return q;
  };
  float* x    = (float*)alloc((size_t)2048 * 1024 * 4);
  bf16* h     = (bf16*)alloc((size_t)2048 * 1024 * 2);
  bf16* qkv   = (bf16*)alloc((size_t)2048 * 3072 * 2);
  bf16* vT    = (bf16*)alloc((size_t)2048 * 1024 * 2);
  bf16* ctx   = (bf16*)alloc((size_t)2048 * 1024 * 2);
  bf16* ff    = (bf16*)alloc((size_t)2048 * 4096 * 2);
  bf16* WoutT = (bf16*)alloc((size_t)32000 * 1024 * 2);

  const size_t DD = (size_t)1024 * 1024;
  const size_t DF = (size_t)1024 * 4096;

  const size_t perLayerW = (3 * DD + DD + DF + DF) * 2;
  const size_t used = (size_t)(p - (char*)d_ws);
  const bool fullprep = ws_size >= used + 6 * perLayerW + 8192;
  const int NL = fullprep ? 6 : 1;
  bf16* WqkvT = (bf16*)alloc((size_t)NL * 3 * DD * 2);
  bf16* WoT   = (bf16*)alloc((size_t)NL * DD * 2);
  bf16* W1T   = (bf16*)alloc((size_t)NL * DF * 2);
  bf16* W2T   = (bf16*)alloc((size_t)NL * DF * 2);

  if (fullprep)
    prep_all_kernel<<<6 * 3072, 256, 0, stream>>>(
        Wq, Wk, Wv, Wo, W1, W2, WqkvT, WoT, W1T, W2T);

  embed_kernel<<<2048, 256, 0, stream>>>(tokens, emb, pe, x);

  for (int l = 0; l < 6; ++l) {
    const bf16* wqkvt; const bf16* wot; const bf16* w1t; const bf16* w2t;
    if (fullprep) {
      wqkvt = WqkvT + (size_t)l * 3 * DD;
      wot   = WoT   + (size_t)l * DD;
      w1t   = W1T   + (size_t)l * DF;
      w2t   = W2T   + (size_t)l * DF;
    } else {
      prep_layer_kernel<<<3072, 256, 0, stream>>>(
          Wq + l * DD, Wk + l * DD, Wv + l * DD, Wo + l * DD,
          W1 + l * DF, W2 + l * DF, WqkvT, WoT, W1T, W2T);
      wqkvt = WqkvT; wot = WoT; w1t = W1T; w2t = W2T;
    }

    ln_kernel<<<2048, 256, 0, stream>>>(x, g1 + l * 1024, be1 + l * 1024, h);
    // QKV: M=2048 N=3072 K=1024, BM=64 -> 768 blocks
    gemm_pl<0, 64, 0><<<dim3(32, 24, 1), 256, 0, stream>>>(
        h, 1024, wqkvt, 1024, qkv, 3072, (const float*)nullptr, 1024);
    transpose_v_kernel<<<dim3(16, 32), 256, 0, stream>>>(qkv, vT);
    attn_kernel<<<dim3(8, 32), 256, 0, stream>>>(qkv, vT, tokens, ctx);
    attn_fixup_kernel<<<32, 64, 0, stream>>>(tokens, vT, ctx);
    // Wo: M=2048 N=1024 K=1024, BM=64 + splitK2 -> 512 blocks
    gemm_pl<3, 64, 0><<<dim3(32, 8, 2), 256, 0, stream>>>(
        ctx, 1024, wot, 1024, x, 1024, bo + l * 1024, 512);
    ln_kernel<<<2048, 256, 0, stream>>>(x, g2 + l * 1024, be2 + l * 1024, h);
    // FFN1: M=2048 N=4096 K=1024, BM=128 -> 512 blocks
    gemm_pl<2, 128, 0><<<dim3(16, 32, 1), 256, 0, stream>>>(
        h, 1024, w1t, 1024, ff, 4096, b1 + l * 4096, 1024);
    // FFN2: M=2048 N=1024 K=4096, BM=128 + splitK4 -> 512 blocks
    gemm_pl<3, 128, 0><<<dim3(16, 8, 4), 256, 0, stream>>>(
        ff, 4096, w2t, 4096, x, 1024, b2 + l * 1024, 1024);
  }

  ln_kernel<<<2048, 256, 0, stream>>>(x, gf, bff, h);
  transpose_cast_kernel<<<dim3(500, 16), 256, 0, stream>>>(Wout, WoutT, 32000, 1024);
  // logits: M=2048 N=32000 K=1024, BM=128 -> 4000 blocks (swizzled)
  gemm_pl<1, 128, 1><<<dim3(16, 250, 1), 256, 0, stream>>>(
      h, 1024, WoutT, 1024, out, 32000, bout, 1024);
}

// Round 6
// 1495.891 us; speedup vs baseline: 1.1014x; 1.0713x over previous
//
#include <hip/hip_runtime.h>
#include <hip/hip_bf16.h>
#include <stdint.h>

typedef __hip_bfloat16 bf16;
typedef __attribute__((ext_vector_type(8))) short bf16x8;
typedef __attribute__((ext_vector_type(4))) float f32x4;

#define DEV static __device__ __forceinline__

DEV float b2f(bf16 v) { return __bfloat162float(v); }
DEV bf16  f2b(float v) { return __float2bfloat16(v); }

DEV void gload16(const void* g, void* l) {
  __builtin_amdgcn_global_load_lds(
      (__attribute__((address_space(1))) void*)(void*)g,
      (__attribute__((address_space(3))) void*)l, 16, 0, 0);
}

DEV f32x4 mfma16(bf16x8 a, bf16x8 b, f32x4 c) {
  return __builtin_amdgcn_mfma_f32_16x16x32_bf16(a, b, c, 0, 0, 0);
}

// ---------------- embed: x = emb[tok]*32 + pe (all f32) ----------------
__global__ __launch_bounds__(256) void embed_kernel(
    const int* __restrict__ tok, const float* __restrict__ emb,
    const float* __restrict__ pe, float* __restrict__ x)
{
  const int r = blockIdx.x, t = threadIdx.x;
  const int s = r & 1023;
  const int tk = tok[r];
  const int d = t * 4;
  const float* ep = emb + (size_t)tk * 1024 + d;
  const float* pp = pe + (size_t)s * 1024 + d;
  float* xp = x + (size_t)r * 1024 + d;
  #pragma unroll
  for (int j = 0; j < 4; ++j)
    xp[j] = ep[j] * 32.0f + pp[j];
}

// ---------------- layernorm: h = LN(x)*g + b (f32 in, bf16 out) ----------------
__global__ __launch_bounds__(256) void ln_kernel(
    const float* __restrict__ x, const float* __restrict__ g,
    const float* __restrict__ be, bf16* __restrict__ h)
{
  const int r = blockIdx.x, t = threadIdx.x;
  const float4 v = ((const float4*)(x + (size_t)r * 1024))[t];
  float s  = v.x + v.y + v.z + v.w;
  float sq = v.x * v.x + v.y * v.y + v.z * v.z + v.w * v.w;
  #pragma unroll
  for (int d = 1; d < 64; d <<= 1) {
    s  += __shfl_xor(s, d);
    sq += __shfl_xor(sq, d);
  }
  __shared__ float red[8];
  const int w = t >> 6, l = t & 63;
  if (l == 0) { red[w] = s; red[4 + w] = sq; }
  __syncthreads();
  s  = red[0] + red[1] + red[2] + red[3];
  sq = red[4] + red[5] + red[6] + red[7];
  const float mean = s * (1.0f / 1024.0f);
  const float var  = sq * (1.0f / 1024.0f) - mean * mean;
  const float inv  = 1.0f / sqrtf(var + 1e-5f);
  bf16* hp = h + (size_t)r * 1024 + t * 4;
  const float* gp = g + t * 4;
  const float* bp = be + t * 4;
  const float vv[4] = {v.x, v.y, v.z, v.w};
  #pragma unroll
  for (int j = 0; j < 4; ++j)
    hp[j] = f2b((vv[j] - mean) * inv * gp[j] + bp[j]);
}

// ------- fused residual + layernorm: x += sum(P[0..np)) + bias; h = LN(x)*g+be
__global__ __launch_bounds__(256) void ln_res_kernel(
    float* __restrict__ x, const float* __restrict__ P, int np,
    const float* __restrict__ bias, const float* __restrict__ g,
    const float* __restrict__ be, bf16* __restrict__ h)
{
  const int r = blockIdx.x, t = threadIdx.x;
  float4 v = ((const float4*)(x + (size_t)r * 1024))[t];
  for (int i = 0; i < np; ++i) {
    const float4 pv = ((const float4*)(P + ((size_t)i * 2048 + r) * 1024))[t];
    v.x += pv.x; v.y += pv.y; v.z += pv.z; v.w += pv.w;
  }
  const float4 bv = ((const float4*)bias)[t];
  v.x += bv.x; v.y += bv.y; v.z += bv.z; v.w += bv.w;

  float s  = v.x + v.y + v.z + v.w;
  float sq = v.x * v.x + v.y * v.y + v.z * v.z + v.w * v.w;
  #pragma unroll
  for (int d = 1; d < 64; d <<= 1) {
    s  += __shfl_xor(s, d);
    sq += __shfl_xor(sq, d);
  }
  __shared__ float red[8];
  const int w = t >> 6, l = t & 63;
  if (l == 0) { red[w] = s; red[4 + w] = sq; }
  __syncthreads();
  s  = red[0] + red[1] + red[2] + red[3];
  sq = red[4] + red[5] + red[6] + red[7];
  const float mean = s * (1.0f / 1024.0f);
  const float var  = sq * (1.0f / 1024.0f) - mean * mean;
  const float inv  = 1.0f / sqrtf(var + 1e-5f);

  ((float4*)(x + (size_t)r * 1024))[t] = v;
  bf16* hp = h + (size_t)r * 1024 + t * 4;
  const float* gp = g + t * 4;
  const float* bp = be + t * 4;
  const float vv[4] = {v.x, v.y, v.z, v.w};
  #pragma unroll
  for (int j = 0; j < 4; ++j)
    hp[j] = f2b((vv[j] - mean) * inv * gp[j] + bp[j]);
}

// ------------- 64x64 transpose+cast tile body -------------
DEV void transpose_tile(const float* __restrict__ in, bf16* __restrict__ out,
                        int ldin, int ldout, int r0, int c0, int t)
{
  __shared__ bf16 tile[64][64];
  #pragma unroll
  for (int i = 0; i < 4; ++i) {
    const int r = i * 16 + (t >> 4), c = (t & 15) * 4;
    const float4 v = *(const float4*)&in[(size_t)(r0 + r) * ldin + c0 + c];
    tile[r][c + 0] = f2b(v.x);
    tile[r][c + 1] = f2b(v.y);
    tile[r][c + 2] = f2b(v.z);
    tile[r][c + 3] = f2b(v.w);
  }
  __syncthreads();
  #pragma unroll
  for (int i = 0; i < 2; ++i) {
    const int oc = i * 32 + (t >> 3);
    const int rr = (t & 7) * 8;
    unsigned short tmp[8] __attribute__((aligned(16)));
    #pragma unroll
    for (int j = 0; j < 8; ++j)
      tmp[j] = ((const unsigned short*)tile)[(rr + j) * 64 + oc];
    *(uint4*)&out[(size_t)(c0 + oc) * ldout + r0 + rr] = *(const uint4*)tmp;
  }
}

// generic single-matrix transpose+cast (used for Wout)
__global__ __launch_bounds__(256) void transpose_cast_kernel(
    const float* __restrict__ in, bf16* __restrict__ out, int ldin, int ldout)
{
  transpose_tile(in, out, ldin, ldout, blockIdx.y * 64, blockIdx.x * 64, threadIdx.x);
}

// dispatch one 64x64 tile of the per-layer weight set (3072 tiles/layer)
DEV void prep_dispatch(int wid,
    const float* Wq, const float* Wk, const float* Wv, const float* Wo,
    const float* W1, const float* W2,
    bf16* WqkvT, bf16* WoT, bf16* W1T, bf16* W2T, int t)
{
  const float* src; bf16* dst; int ldin, ldout, tx, ty;
  if (wid < 768) {
    const int m = wid >> 8, tt = wid & 255;
    src = (m == 0) ? Wq : (m == 1) ? Wk : Wv;
    dst = WqkvT + (size_t)m * 1024 * 1024;
    ldin = 1024; ldout = 1024; tx = tt & 15; ty = tt >> 4;
  } else if (wid < 1024) {
    const int tt = wid - 768;
    src = Wo; dst = WoT; ldin = 1024; ldout = 1024; tx = tt & 15; ty = tt >> 4;
  } else if (wid < 2048) {
    const int tt = wid - 1024;
    src = W1; dst = W1T; ldin = 4096; ldout = 1024; tx = tt & 63; ty = tt >> 6;
  } else {
    const int tt = wid - 2048;
    src = W2; dst = W2T; ldin = 1024; ldout = 4096; tx = tt & 15; ty = tt >> 4;
  }
  transpose_tile(src, dst, ldin, ldout, ty * 64, tx * 64, t);
}

// per-layer weight prep (fallback path)
__global__ __launch_bounds__(256) void prep_layer_kernel(
    const float* __restrict__ Wq, const float* __restrict__ Wk,
    const float* __restrict__ Wv, const float* __restrict__ Wo,
    const float* __restrict__ W1, const float* __restrict__ W2,
    bf16* __restrict__ WqkvT, bf16* __restrict__ WoT,
    bf16* __restrict__ W1T, bf16* __restrict__ W2T)
{
  prep_dispatch(blockIdx.x, Wq, Wk, Wv, Wo, W1, W2,
                WqkvT, WoT, W1T, W2T, threadIdx.x);
}

// all-layers weight prep (when ws permits): 6*3072 blocks
__global__ __launch_bounds__(256) void prep_all_kernel(
    const float* __restrict__ Wq, const float* __restrict__ Wk,
    const float* __restrict__ Wv, const float* __restrict__ Wo,
    const float* __restrict__ W1, const float* __restrict__ W2,
    bf16* __restrict__ WqkvT, bf16* __restrict__ WoT,
    bf16* __restrict__ W1T, bf16* __restrict__ W2T)
{
  const int layer = blockIdx.x / 3072;
  const int wid = blockIdx.x - layer * 3072;
  const size_t DD = (size_t)1024 * 1024, DF = (size_t)1024 * 4096;
  prep_dispatch(wid,
      Wq + layer * DD, Wk + layer * DD, Wv + layer * DD, Wo + layer * DD,
      W1 + layer * DF, W2 + layer * DF,
      WqkvT + layer * 3 * DD, WoT + layer * DD,
      W1T + layer * DF, W2T + layer * DF, threadIdx.x);
}

// ---- v transpose (bf16->bf16): vT[bh][dk][s] = qkv[b*S+s][2048+h*64+dk] ----
// grid: (S/64, B*H), block 256
__global__ __launch_bounds__(256) void transpose_v_kernel(
    const bf16* __restrict__ qkv, bf16* __restrict__ vT)
{
  __shared__ bf16 tile[64][64];
  const int t = threadIdx.x;
  const int s0 = blockIdx.x * 64;
  const int bh = blockIdx.y;
  const int b = bh >> 4, h = bh & 15;
  const bf16* in = qkv + (size_t)(b * 1024) * 3072 + 2048 + h * 64;
  #pragma unroll
  for (int i = 0; i < 2; ++i) {
    const int r = i * 32 + (t >> 3), c = (t & 7) * 8;
    *(uint4*)&tile[r][c] = *(const uint4*)&in[(size_t)(s0 + r) * 3072 + c];
  }
  __syncthreads();
  bf16* out = vT + (size_t)(bh * 64) * 1024;
  #pragma unroll
  for (int i = 0; i < 2; ++i) {
    const int oc = i * 32 + (t >> 3);   // dk
    const int rr = (t & 7) * 8;         // s offset
    unsigned short tmp[8] __attribute__((aligned(16)));
    #pragma unroll
    for (int j = 0; j < 8; ++j)
      tmp[j] = ((const unsigned short*)tile)[(rr + j) * 64 + oc];
    *(uint4*)&out[(size_t)oc * 1024 + s0 + rr] = *(const uint4*)tmp;
  }
}

// ------------- pipelined GEMM: C(MxN) = A(MxK,row) * BT(NxK,row)^T -------------
// 3-buffer LDS, 2-tiles-ahead prefetch, counted vmcnt (T4), raw barriers,
// T2 bank-conflict XOR swizzle (pre-swizzled global source + swizzled ds_read).
// EPI: 0 = bf16 store; 1 = +bias f32 store (logits); 2 = gelu(acc+bias) bf16;
//      3 = f32 K-slice partial store P[z][M][N] (no bias; reduced in ln_res)
// grid: (M/BM, N/128, KSLICES), block 256 (4 waves), K-slice length ksl
template<int EPI, int BM, int SWZ>
__global__ __launch_bounds__(256) void gemm_pl(
    const bf16* __restrict__ A, int lda,
    const bf16* __restrict__ BT, int ldb,
    void* __restrict__ Cp, int ldc,
    const float* __restrict__ bias,
    int ksl)
{
  constexpr int ABUF = BM * 32;               // elems per A buffer
  constexpr int MR = BM / 32;                 // m-fragment repeats per wave
  __shared__ bf16 As[3 * ABUF];
  __shared__ bf16 Bs[3 * 4096];
  const int t = threadIdx.x;

  int bm, bn;
  if constexpr (SWZ) {                        // XCD-chunked swizzle (nwg%8==0)
    const int nbm = gridDim.x;
    const int nwg = nbm * gridDim.y;
    int wid = blockIdx.x + nbm * blockIdx.y;
    wid = (wid & 7) * (nwg >> 3) + (wid >> 3);
    bm = wid % nbm; bn = wid / nbm;
  } else {
    bm = blockIdx.x; bn = blockIdx.y;
  }

  const int w = t >> 6, l = t & 63;
  const int wr = (w >> 1) * (BM / 2), wc = (w & 1) * 64;
  const int l15 = l & 15, l4 = l >> 4;
  const int kbeg = blockIdx.z * ksl;
  const int ntiles = ksl >> 5;

  // T2: pre-swizzled global column-block; key = (lds_row>>1)&3 = (t>>3)&3
  const int colblk = (((t & 3) ^ ((t >> 3) & 3))) * 8;
  const bf16* gA = A  + (size_t)(bm * BM  + (t >> 2)) * lda + colblk + kbeg;
  const bf16* gB = BT + (size_t)(bn * 128 + (t >> 2)) * ldb + colblk + kbeg;
  bf16* lA = As + w * 512;
  bf16* lB = Bs + w * 512;

  auto stage = [&](int tile, int buf) {
    const int k0 = tile * 32;
    gload16(gA + k0, lA + buf * ABUF);
    if constexpr (BM == 128)
      gload16(gA + (size_t)64 * lda + k0, lA + buf * ABUF + 2048);
    gload16(gB + k0, lB + buf * 4096);
    gload16(gB + (size_t)64 * ldb + k0, lB + buf * 4096 + 2048);
  };

  f32x4 acc[MR][4];
  #pragma unroll
  for (int m = 0; m < MR; ++m)
    #pragma unroll
    for (int n = 0; n < 4; ++n)
      acc[m][n] = (f32x4){0.f, 0.f, 0.f, 0.f};

  stage(0, 0);
  stage(1, 1);

  // T2 read-side swizzle: column-block = l4 ^ ((row>>1)&3); row%16 == l15
  const int rdcol = ((l4 ^ ((l15 >> 1) & 3))) * 8;

  int buf = 0;
  for (int kt = 0; kt < ntiles; ++kt) {
    if (kt + 2 < ntiles) {
      int pb = buf + 2; if (pb >= 3) pb -= 3;
      stage(kt + 2, pb);
      __builtin_amdgcn_sched_barrier(0);
      if constexpr (BM == 128) asm volatile("s_waitcnt vmcnt(8)" ::: "memory");
      else                     asm volatile("s_waitcnt vmcnt(6)" ::: "memory");
    } else if (kt + 1 < ntiles) {
      if constexpr (BM == 128) asm volatile("s_waitcnt vmcnt(4)" ::: "memory");
      else                     asm volatile("s_waitcnt vmcnt(3)" ::: "memory");
    } else {
      asm volatile("s_waitcnt vmcnt(0)" ::: "memory");
    }
    __builtin_amdgcn_s_barrier();          // all waves: tile kt resident
    __builtin_amdgcn_sched_barrier(0);     // no ds_read hoists above barrier

    const bf16* Ab = As + buf * ABUF;
    const bf16* Bb = Bs + buf * 4096;
    bf16x8 af[MR], bfr[4];
    #pragma unroll
    for (int m = 0; m < MR; ++m)
      af[m] = *(const bf16x8*)&Ab[(wr + m * 16 + l15) * 32 + rdcol];
    #pragma unroll
    for (int n = 0; n < 4; ++n)
      bfr[n] = *(const bf16x8*)&Bb[(wc + n * 16 + l15) * 32 + rdcol];
    #pragma unroll
    for (int m = 0; m < MR; ++m)
      #pragma unroll
      for (int n = 0; n < 4; ++n)
        acc[m][n] = mfma16(af[m], bfr[n], acc[m][n]);

    __builtin_amdgcn_sched_barrier(0);     // reads stay before barrier
    __builtin_amdgcn_s_barrier();          // buf kt now dead for overwrite
    if (++buf >= 3) buf = 0;
  }

  const int crow = bm * BM + wr, ccol = bn * 128 + wc;
  #pragma unroll
  for (int n = 0; n < 4; ++n) {
    const int col = ccol + n * 16 + l15;
    float bv = 0.f;
    if (EPI == 1 || EPI == 2) bv = bias[col];
    #pragma unroll
    for (int m = 0; m < MR; ++m) {
      const int row = crow + m * 16 + l4 * 4;
      #pragma unroll
      for (int r = 0; r < 4; ++r) {
        const float v = acc[m][n][r];
        if (EPI == 0) {
          ((bf16*)Cp)[(size_t)(row + r) * ldc + col] = f2b(v);
        } else if (EPI == 1) {
          ((float*)Cp)[(size_t)(row + r) * ldc + col] = v + bv;
        } else if (EPI == 2) {
          const float u = v + bv;
          const float gel = 0.5f * u * (1.0f + erff(u * 0.70710678118654752f));
          ((bf16*)Cp)[(size_t)(row + r) * ldc + col] = f2b(gel);
        } else {
          const int M = gridDim.x * BM;
          ((float*)Cp)[((size_t)blockIdx.z * M + row + r) * ldc + col] = v;
        }
      }
    }
  }
}

// ---------------- flash attention (LDS XOR-swizzled) ----------------
// grid: (S/128, B*H), block 256 (4 waves; wave w owns q-rows w*32..w*32+31)
__global__ __launch_bounds__(256) void attn_kernel(
    const bf16* __restrict__ qkv, const bf16* __restrict__ vT,
    const int* __restrict__ tokens, bf16* __restrict__ ctx)
{
  __shared__ bf16 Ks[128 * 64];
  __shared__ bf16 VTs[64 * 128];
  __shared__ bf16 Ps[128 * 128];

  const int qt = blockIdx.x;
  const int bh = blockIdx.y;
  const int b = bh >> 4, h = bh & 15;
  const int t = threadIdx.x, w = t >> 6, l = t & 63;
  const int l15 = l & 15, l4 = l >> 4;
  const int q0 = qt * 128;

  bf16x8 aq[2][2];
  #pragma unroll
  for (int m = 0; m < 2; ++m)
    #pragma unroll
    for (int ks = 0; ks < 2; ++ks)
      aq[m][ks] = *(const bf16x8*)(qkv +
          (size_t)(b * 1024 + q0 + w * 32 + m * 16 + l15) * 3072 +
          h * 64 + ks * 32 + l4 * 8);

  f32x4 o[2][4];
  float m_run[2][4], l_run[2][4];
  #pragma unroll
  for (int m = 0; m < 2; ++m)
    #pragma unroll
    for (int r = 0; r < 4; ++r) { m_run[m][r] = -1e30f; l_run[m][r] = 0.f; }
  #pragma unroll
  for (int m = 0; m < 2; ++m)
    #pragma unroll
    for (int nn = 0; nn < 4; ++nn)
      o[m][nn] = (f32x4){0.f, 0.f, 0.f, 0.f};

  const bf16* kb = qkv + (size_t)(b * 1024) * 3072 + 1024 + h * 64;
  const bf16* vb = vT + (size_t)(bh * 64) * 1024;
  const int* tb = tokens + b * 1024;

  const int kSrcCol = ((t & 7) ^ ((t >> 3) & 7)) * 8;
  const int vSrcCol = ((t & 15) ^ (t >> 4)) * 8;

  for (int jt = 0; jt <= qt; ++jt) {
    const int j0 = jt * 128;
    __syncthreads();
    #pragma unroll
    for (int i = 0; i < 4; ++i)
      gload16(kb + (size_t)(j0 + i * 32 + (t >> 3)) * 3072 + kSrcCol,
              Ks + i * 2048 + w * 512);
    #pragma unroll
    for (int i = 0; i < 4; ++i)
      gload16(vb + (size_t)(i * 16 + (t >> 4)) * 1024 + j0 + vSrcCol,
              VTs + i * 2048 + w * 512);
    __syncthreads();

    f32x4 s[2][8];
    #pragma unroll
    for (int m = 0; m < 2; ++m)
      #pragma unroll
      for (int n = 0; n < 8; ++n)
        s[m][n] = (f32x4){0.f, 0.f, 0.f, 0.f};
    #pragma unroll
    for (int ks = 0; ks < 2; ++ks) {
      #pragma unroll
      for (int n = 0; n < 8; ++n) {
        const bf16x8 bk = *(const bf16x8*)
            &Ks[(n * 16 + l15) * 64 + ((ks * 32 + l4 * 8) ^ ((l15 & 7) * 8))];
        #pragma unroll
        for (int m = 0; m < 2; ++m)
          s[m][n] = mfma16(aq[m][ks], bk, s[m][n]);
      }
    }

    float padv[8];
    #pragma unroll
    for (int n = 0; n < 8; ++n)
      padv[n] = (tb[j0 + n * 16 + l15] == 0) ? 1.f : 0.f;

    #pragma unroll
    for (int m = 0; m < 2; ++m) {
      #pragma unroll
      for (int r = 0; r < 4; ++r) {
        const int rloc = l4 * 4 + r;
        const int qrow = q0 + w * 32 + m * 16 + rloc;
        float vals[8];
        float mx = -1e30f;
        #pragma unroll
        for (int n = 0; n < 8; ++n) {
          const int jg = j0 + n * 16 + l15;
          float v = s[m][n][r] * 0.125f;
          if (jg > qrow || padv[n] != 0.f) v = -1e9f;
          vals[n] = v;
          mx = fmaxf(mx, v);
        }
        #pragma unroll
        for (int d = 1; d < 16; d <<= 1) mx = fmaxf(mx, __shfl_xor(mx, d));
        const float newm = fmaxf(m_run[m][r], mx);
        const float sc = __expf(m_run[m][r] - newm);
        m_run[m][r] = newm;
        float rs = 0.f;
        #pragma unroll
        for (int n = 0; n < 8; ++n) {
          const float pv = __expf(vals[n] - newm);
          vals[n] = pv;
          rs += pv;
        }
        #pragma unroll
        for (int d = 1; d < 16; d <<= 1) rs += __shfl_xor(rs, d);
        l_run[m][r] = l_run[m][r] * sc + rs;
        #pragma unroll
        for (int nn = 0; nn < 4; ++nn) o[m][nn][r] = o[m][nn][r] * sc;
        #pragma unroll
        for (int n = 0; n < 8; ++n)
          Ps[(w * 32 + m * 16 + rloc) * 128 +
             ((n * 16 + l15) ^ (rloc * 8))] = f2b(vals[n]);
      }
    }
    __syncthreads();

    #pragma unroll
    for (int ks = 0; ks < 4; ++ks) {
      bf16x8 ap[2];
      #pragma unroll
      for (int m = 0; m < 2; ++m)
        ap[m] = *(const bf16x8*)
            &Ps[(w * 32 + m * 16 + l15) * 128 + ((ks * 32 + l4 * 8) ^ (l15 * 8))];
      #pragma unroll
      for (int nn = 0; nn < 4; ++nn) {
        const bf16x8 bv = *(const bf16x8*)
            &VTs[(nn * 16 + l15) * 128 + ((ks * 32 + l4 * 8) ^ (l15 * 8))];
        #pragma unroll
        for (int m = 0; m < 2; ++m)
          o[m][nn] = mfma16(ap[m], bv, o[m][nn]);
      }
    }
  }

  #pragma unroll
  for (int m = 0; m < 2; ++m) {
    #pragma unroll
    for (int r = 0; r < 4; ++r) {
      const float inv = 1.0f / l_run[m][r];
      const int qrow = q0 + w * 32 + m * 16 + l4 * 4 + r;
      #pragma unroll
      for (int nn = 0; nn < 4; ++nn)
        ctx[(size_t)(b * 1024 + qrow) * 1024 + h * 64 + nn * 16 + l15] =
            f2b(o[m][nn][r] * inv);
    }
  }
}

// ------------- fixup for all-masked rows (leading pad tokens) -------------
__global__ __launch_bounds__(64) void attn_fixup_kernel(
    const int* __restrict__ tokens, const bf16* __restrict__ vT,
    bf16* __restrict__ ctx)
{
  const int bh = blockIdx.x;
  const int b = bh >> 4, h = bh & 15;
  __shared__ int p0s;
  if (threadIdx.x == 0) {
    int p = 0;
    const int* tb = tokens + b * 1024;
    while (p < 1024 && tb[p] == 0) ++p;
    p0s = p;
  }
  __syncthreads();
  const int P0 = p0s;
  if (P0 == 0) return;
  const int dk = threadIdx.x;
  const bf16* vrow = vT + (size_t)(bh * 64 + dk) * 1024;
  float sum = 0.f;
  for (int sIdx = 0; sIdx < 1024; ++sIdx) sum += b2f(vrow[sIdx]);
  const bf16 mv = f2b(sum * (1.0f / 1024.0f));
  for (int q = 0; q < P0; ++q)
    ctx[(size_t)(b * 1024 + q) * 1024 + h * 64 + dk] = mv;
}

// ---------------- host ----------------
extern "C" void kernel_launch(void* const* d_in, const int* in_sizes, int n_in,
                              void* d_out, int out_size, void* d_ws, size_t ws_size,
                              hipStream_t stream)
{
  (void)in_sizes; (void)n_in; (void)out_size;
  const int*   tokens = (const int*)d_in[0];
  const float* emb  = (const float*)d_in[1];
  const float* pe   = (const float*)d_in[2];
  const float* Wq   = (const float*)d_in[3];
  const float* Wk   = (const float*)d_in[4];
  const float* Wv   = (const float*)d_in[5];
  const float* Wo   = (const float*)d_in[6];
  const float* bo   = (const float*)d_in[7];
  const float* g1   = (const float*)d_in[8];
  const float* be1  = (const float*)d_in[9];
  const float* g2   = (const float*)d_in[10];
  const float* be2  = (const float*)d_in[11];
  const float* W1   = (const float*)d_in[12];
  const float* b1   = (const float*)d_in[13];
  const float* W2   = (const float*)d_in[14];
  const float* b2   = (const float*)d_in[15];
  const float* gf   = (const float*)d_in[16];
  const float* bff  = (const float*)d_in[17];
  const float* Wout = (const float*)d_in[18];
  const float* bout = (const float*)d_in[19];
  float* out = (float*)d_out;

  char* p = (char*)d_ws;
  auto alloc = [&](size_t bytes) {
    char* q = p;
    p += (bytes + 255) & ~(size_t)255;
    return q;
  };
  float* x    = (float*)alloc((size_t)2048 * 1024 * 4);
  float* Pp   = (float*)alloc((size_t)4 * 2048 * 1024 * 4);  // K-slice partials
  bf16* h     = (bf16*)alloc((size_t)2048 * 1024 * 2);
  bf16* qkv   = (bf16*)alloc((size_t)2048 * 3072 * 2);
  bf16* vT    = (bf16*)alloc((size_t)2048 * 1024 * 2);
  bf16* ctx   = (bf16*)alloc((size_t)2048 * 1024 * 2);
  bf16* ff    = (bf16*)alloc((size_t)2048 * 4096 * 2);
  bf16* WoutT = (bf16*)alloc((size_t)32000 * 1024 * 2);

  const size_t DD = (size_t)1024 * 1024;
  const size_t DF = (size_t)1024 * 4096;

  const size_t perLayerW = (3 * DD + DD + DF + DF) * 2;
  const size_t used = (size_t)(p - (char*)d_ws);
  const bool fullprep = ws_size >= used + 6 * perLayerW + 8192;
  const int NL = fullprep ? 6 : 1;
  bf16* WqkvT = (bf16*)alloc((size_t)NL * 3 * DD * 2);
  bf16* WoT   = (bf16*)alloc((size_t)NL * DD * 2);
  bf16* W1T   = (bf16*)alloc((size_t)NL * DF * 2);
  bf16* W2T   = (bf16*)alloc((size_t)NL * DF * 2);

  if (fullprep)
    prep_all_kernel<<<6 * 3072, 256, 0, stream>>>(
        Wq, Wk, Wv, Wo, W1, W2, WqkvT, WoT, W1T, W2T);

  embed_kernel<<<2048, 256, 0, stream>>>(tokens, emb, pe, x);

  for (int l = 0; l < 6; ++l) {
    const bf16* wqkvt; const bf16* wot; const bf16* w1t; const bf16* w2t;
    if (fullprep) {
      wqkvt = WqkvT + (size_t)l * 3 * DD;
      wot   = WoT   + (size_t)l * DD;
      w1t   = W1T   + (size_t)l * DF;
      w2t   = W2T   + (size_t)l * DF;
    } else {
      prep_layer_kernel<<<3072, 256, 0, stream>>>(
          Wq + l * DD, Wk + l * DD, Wv + l * DD, Wo + l * DD,
          W1 + l * DF, W2 + l * DF, WqkvT, WoT, W1T, W2T);
      wqkvt = WqkvT; wot = WoT; w1t = W1T; w2t = W2T;
    }

    // ln1: layer 0 plain; later layers fold the previous FFN2 partials
    if (l == 0)
      ln_kernel<<<2048, 256, 0, stream>>>(x, g1, be1, h);
    else
      ln_res_kernel<<<2048, 256, 0, stream>>>(
          x, Pp, 4, b2 + (l - 1) * 1024, g1 + l * 1024, be1 + l * 1024, h);

    // QKV: M=2048 N=3072 K=1024, BM=64 -> 768 blocks
    gemm_pl<0, 64, 0><<<dim3(32, 24, 1), 256, 0, stream>>>(
        h, 1024, wqkvt, 1024, qkv, 3072, (const float*)nullptr, 1024);
    transpose_v_kernel<<<dim3(16, 32), 256, 0, stream>>>(qkv, vT);
    attn_kernel<<<dim3(8, 32), 256, 0, stream>>>(qkv, vT, tokens, ctx);
    attn_fixup_kernel<<<32, 64, 0, stream>>>(tokens, vT, ctx);
    // Wo: M=2048 N=1024 K=1024, BM=64 + splitK2 -> 512 blocks, partials
    gemm_pl<3, 64, 0><<<dim3(32, 8, 2), 256, 0, stream>>>(
        ctx, 1024, wot, 1024, Pp, 1024, (const float*)nullptr, 512);
    // ln2: x += Pw0+Pw1 + bo; h = LN(x)
    ln_res_kernel<<<2048, 256, 0, stream>>>(
        x, Pp, 2, bo + l * 1024, g2 + l * 1024, be2 + l * 1024, h);
    // FFN1: M=2048 N=4096 K=1024, BM=128 -> 512 blocks
    gemm_pl<2, 128, 0><<<dim3(16, 32, 1), 256, 0, stream>>>(
        h, 1024, w1t, 1024, ff, 4096, b1 + l * 4096, 1024);
    // FFN2: M=2048 N=1024 K=4096, BM=128 + splitK4 -> 512 blocks, partials
    gemm_pl<3, 128, 0><<<dim3(16, 8, 4), 256, 0, stream>>>(
        ff, 4096, w2t, 4096, Pp, 1024, (const float*)nullptr, 1024);
  }

  // final LN folds layer-5 FFN2 partials
  ln_res_kernel<<<2048, 256, 0, stream>>>(x, Pp, 4, b2 + 5 * 1024, gf, bff, h);
  transpose_cast_kernel<<<dim3(500, 16), 256, 0, stream>>>(Wout, WoutT, 32000, 1024);
  // logits: M=2048 N=32000 K=1024, BM=128 -> 4000 blocks (swizzled)
  gemm_pl<1, 128, 1><<<dim3(16, 250, 1), 256, 0, stream>>>(
      h, 1024, WoutT, 1024, out, 32000, bout, 1024);
}

// Round 7
// 1492.869 us; speedup vs baseline: 1.1036x; 1.0020x over previous
//
#include <hip/hip_runtime.h>
#include <hip/hip_bf16.h>
#include <stdint.h>

typedef __hip_bfloat16 bf16;
typedef __attribute__((ext_vector_type(8))) short bf16x8;
typedef __attribute__((ext_vector_type(4))) float f32x4;

#define DEV static __device__ __forceinline__

DEV float b2f(bf16 v) { return __bfloat162float(v); }
DEV bf16  f2b(float v) { return __float2bfloat16(v); }

DEV void gload16(const void* g, void* l) {
  __builtin_amdgcn_global_load_lds(
      (__attribute__((address_space(1))) void*)(void*)g,
      (__attribute__((address_space(3))) void*)l, 16, 0, 0);
}

DEV f32x4 mfma16(bf16x8 a, bf16x8 b, f32x4 c) {
  return __builtin_amdgcn_mfma_f32_16x16x32_bf16(a, b, c, 0, 0, 0);
}

// ---------------- embed: x = emb[tok]*32 + pe (all f32) ----------------
__global__ __launch_bounds__(256) void embed_kernel(
    const int* __restrict__ tok, const float* __restrict__ emb,
    const float* __restrict__ pe, float* __restrict__ x)
{
  const int r = blockIdx.x, t = threadIdx.x;
  const int s = r & 1023;
  const int tk = tok[r];
  const int d = t * 4;
  const float* ep = emb + (size_t)tk * 1024 + d;
  const float* pp = pe + (size_t)s * 1024 + d;
  float* xp = x + (size_t)r * 1024 + d;
  #pragma unroll
  for (int j = 0; j < 4; ++j)
    xp[j] = ep[j] * 32.0f + pp[j];
}

// ---------------- layernorm: h = LN(x)*g + b (f32 in, bf16 out) ----------------
__global__ __launch_bounds__(256) void ln_kernel(
    const float* __restrict__ x, const float* __restrict__ g,
    const float* __restrict__ be, bf16* __restrict__ h)
{
  const int r = blockIdx.x, t = threadIdx.x;
  const float4 v = ((const float4*)(x + (size_t)r * 1024))[t];
  float s  = v.x + v.y + v.z + v.w;
  float sq = v.x * v.x + v.y * v.y + v.z * v.z + v.w * v.w;
  #pragma unroll
  for (int d = 1; d < 64; d <<= 1) {
    s  += __shfl_xor(s, d);
    sq += __shfl_xor(sq, d);
  }
  __shared__ float red[8];
  const int w = t >> 6, l = t & 63;
  if (l == 0) { red[w] = s; red[4 + w] = sq; }
  __syncthreads();
  s  = red[0] + red[1] + red[2] + red[3];
  sq = red[4] + red[5] + red[6] + red[7];
  const float mean = s * (1.0f / 1024.0f);
  const float var  = sq * (1.0f / 1024.0f) - mean * mean;
  const float inv  = 1.0f / sqrtf(var + 1e-5f);
  bf16* hp = h + (size_t)r * 1024 + t * 4;
  const float* gp = g + t * 4;
  const float* bp = be + t * 4;
  const float vv[4] = {v.x, v.y, v.z, v.w};
  #pragma unroll
  for (int j = 0; j < 4; ++j)
    hp[j] = f2b((vv[j] - mean) * inv * gp[j] + bp[j]);
}

// ------- fused residual + layernorm: x += sum(P[0..np)) + bias; h = LN(x)*g+be
__global__ __launch_bounds__(256) void ln_res_kernel(
    float* __restrict__ x, const float* __restrict__ P, int np,
    const float* __restrict__ bias, const float* __restrict__ g,
    const float* __restrict__ be, bf16* __restrict__ h)
{
  const int r = blockIdx.x, t = threadIdx.x;
  float4 v = ((const float4*)(x + (size_t)r * 1024))[t];
  for (int i = 0; i < np; ++i) {
    const float4 pv = ((const float4*)(P + ((size_t)i * 2048 + r) * 1024))[t];
    v.x += pv.x; v.y += pv.y; v.z += pv.z; v.w += pv.w;
  }
  const float4 bv = ((const float4*)bias)[t];
  v.x += bv.x; v.y += bv.y; v.z += bv.z; v.w += bv.w;

  float s  = v.x + v.y + v.z + v.w;
  float sq = v.x * v.x + v.y * v.y + v.z * v.z + v.w * v.w;
  #pragma unroll
  for (int d = 1; d < 64; d <<= 1) {
    s  += __shfl_xor(s, d);
    sq += __shfl_xor(sq, d);
  }
  __shared__ float red[8];
  const int w = t >> 6, l = t & 63;
  if (l == 0) { red[w] = s; red[4 + w] = sq; }
  __syncthreads();
  s  = red[0] + red[1] + red[2] + red[3];
  sq = red[4] + red[5] + red[6] + red[7];
  const float mean = s * (1.0f / 1024.0f);
  const float var  = sq * (1.0f / 1024.0f) - mean * mean;
  const float inv  = 1.0f / sqrtf(var + 1e-5f);

  ((float4*)(x + (size_t)r * 1024))[t] = v;
  bf16* hp = h + (size_t)r * 1024 + t * 4;
  const float* gp = g + t * 4;
  const float* bp = be + t * 4;
  const float vv[4] = {v.x, v.y, v.z, v.w};
  #pragma unroll
  for (int j = 0; j < 4; ++j)
    hp[j] = f2b((vv[j] - mean) * inv * gp[j] + bp[j]);
}

// ------------- 64x64 transpose+cast tile body -------------
DEV void transpose_tile(const float* __restrict__ in, bf16* __restrict__ out,
                        int ldin, int ldout, int r0, int c0, int t)
{
  __shared__ bf16 tile[64][64];
  #pragma unroll
  for (int i = 0; i < 4; ++i) {
    const int r = i * 16 + (t >> 4), c = (t & 15) * 4;
    const float4 v = *(const float4*)&in[(size_t)(r0 + r) * ldin + c0 + c];
    tile[r][c + 0] = f2b(v.x);
    tile[r][c + 1] = f2b(v.y);
    tile[r][c + 2] = f2b(v.z);
    tile[r][c + 3] = f2b(v.w);
  }
  __syncthreads();
  #pragma unroll
  for (int i = 0; i < 2; ++i) {
    const int oc = i * 32 + (t >> 3);
    const int rr = (t & 7) * 8;
    unsigned short tmp[8] __attribute__((aligned(16)));
    #pragma unroll
    for (int j = 0; j < 8; ++j)
      tmp[j] = ((const unsigned short*)tile)[(rr + j) * 64 + oc];
    *(uint4*)&out[(size_t)(c0 + oc) * ldout + r0 + rr] = *(const uint4*)tmp;
  }
}

// generic single-matrix transpose+cast (used for Wout)
__global__ __launch_bounds__(256) void transpose_cast_kernel(
    const float* __restrict__ in, bf16* __restrict__ out, int ldin, int ldout)
{
  transpose_tile(in, out, ldin, ldout, blockIdx.y * 64, blockIdx.x * 64, threadIdx.x);
}

// dispatch one 64x64 tile of the per-layer weight set (3072 tiles/layer)
DEV void prep_dispatch(int wid,
    const float* Wq, const float* Wk, const float* Wv, const float* Wo,
    const float* W1, const float* W2,
    bf16* WqkvT, bf16* WoT, bf16* W1T, bf16* W2T, int t)
{
  const float* src; bf16* dst; int ldin, ldout, tx, ty;
  if (wid < 768) {
    const int m = wid >> 8, tt = wid & 255;
    src = (m == 0) ? Wq : (m == 1) ? Wk : Wv;
    dst = WqkvT + (size_t)m * 1024 * 1024;
    ldin = 1024; ldout = 1024; tx = tt & 15; ty = tt >> 4;
  } else if (wid < 1024) {
    const int tt = wid - 768;
    src = Wo; dst = WoT; ldin = 1024; ldout = 1024; tx = tt & 15; ty = tt >> 4;
  } else if (wid < 2048) {
    const int tt = wid - 1024;
    src = W1; dst = W1T; ldin = 4096; ldout = 1024; tx = tt & 63; ty = tt >> 6;
  } else {
    const int tt = wid - 2048;
    src = W2; dst = W2T; ldin = 1024; ldout = 4096; tx = tt & 15; ty = tt >> 4;
  }
  transpose_tile(src, dst, ldin, ldout, ty * 64, tx * 64, t);
}

// per-layer weight prep (fallback path)
__global__ __launch_bounds__(256) void prep_layer_kernel(
    const float* __restrict__ Wq, const float* __restrict__ Wk,
    const float* __restrict__ Wv, const float* __restrict__ Wo,
    const float* __restrict__ W1, const float* __restrict__ W2,
    bf16* __restrict__ WqkvT, bf16* __restrict__ WoT,
    bf16* __restrict__ W1T, bf16* __restrict__ W2T)
{
  prep_dispatch(blockIdx.x, Wq, Wk, Wv, Wo, W1, W2,
                WqkvT, WoT, W1T, W2T, threadIdx.x);
}

// all-layers weight prep (when ws permits): 6*3072 blocks
__global__ __launch_bounds__(256) void prep_all_kernel(
    const float* __restrict__ Wq, const float* __restrict__ Wk,
    const float* __restrict__ Wv, const float* __restrict__ Wo,
    const float* __restrict__ W1, const float* __restrict__ W2,
    bf16* __restrict__ WqkvT, bf16* __restrict__ WoT,
    bf16* __restrict__ W1T, bf16* __restrict__ W2T)
{
  const int layer = blockIdx.x / 3072;
  const int wid = blockIdx.x - layer * 3072;
  const size_t DD = (size_t)1024 * 1024, DF = (size_t)1024 * 4096;
  prep_dispatch(wid,
      Wq + layer * DD, Wk + layer * DD, Wv + layer * DD, Wo + layer * DD,
      W1 + layer * DF, W2 + layer * DF,
      WqkvT + layer * 3 * DD, WoT + layer * DD,
      W1T + layer * DF, W2T + layer * DF, threadIdx.x);
}

// ---- v transpose (bf16->bf16): vT[bh][dk][s] = qkv[b*S+s][2048+h*64+dk] ----
// grid: (S/64, B*H), block 256
__global__ __launch_bounds__(256) void transpose_v_kernel(
    const bf16* __restrict__ qkv, bf16* __restrict__ vT)
{
  __shared__ bf16 tile[64][64];
  const int t = threadIdx.x;
  const int s0 = blockIdx.x * 64;
  const int bh = blockIdx.y;
  const int b = bh >> 4, h = bh & 15;
  const bf16* in = qkv + (size_t)(b * 1024) * 3072 + 2048 + h * 64;
  #pragma unroll
  for (int i = 0; i < 2; ++i) {
    const int r = i * 32 + (t >> 3), c = (t & 7) * 8;
    *(uint4*)&tile[r][c] = *(const uint4*)&in[(size_t)(s0 + r) * 3072 + c];
  }
  __syncthreads();
  bf16* out = vT + (size_t)(bh * 64) * 1024;
  #pragma unroll
  for (int i = 0; i < 2; ++i) {
    const int oc = i * 32 + (t >> 3);   // dk
    const int rr = (t & 7) * 8;         // s offset
    unsigned short tmp[8] __attribute__((aligned(16)));
    #pragma unroll
    for (int j = 0; j < 8; ++j)
      tmp[j] = ((const unsigned short*)tile)[(rr + j) * 64 + oc];
    *(uint4*)&out[(size_t)oc * 1024 + s0 + rr] = *(const uint4*)tmp;
  }
}

// ------------- pipelined GEMM: C(MxN) = A(MxK,row) * BT(NxK,row)^T -------------
// 3-buffer LDS, 2-tiles-ahead prefetch, counted vmcnt (T4), raw barriers,
// T2 bank-conflict XOR swizzle (pre-swizzled global source + swizzled ds_read).
// EPI: 0 = bf16 store; 1 = +bias f32 store (logits); 2 = gelu(acc+bias) bf16;
//      3 = f32 K-slice partial store P[z][M][N] (no bias; reduced in ln_res)
// grid: (M/BM, N/128, KSLICES), block 256 (4 waves), K-slice length ksl
template<int EPI, int BM, int SWZ>
__global__ __launch_bounds__(256) void gemm_pl(
    const bf16* __restrict__ A, int lda,
    const bf16* __restrict__ BT, int ldb,
    void* __restrict__ Cp, int ldc,
    const float* __restrict__ bias,
    int ksl)
{
  constexpr int ABUF = BM * 32;               // elems per A buffer
  constexpr int MR = BM / 32;                 // m-fragment repeats per wave
  __shared__ bf16 As[3 * ABUF];
  __shared__ bf16 Bs[3 * 4096];
  const int t = threadIdx.x;

  int bm, bn;
  if constexpr (SWZ) {                        // XCD-chunked swizzle (nwg%8==0)
    const int nbm = gridDim.x;
    const int nwg = nbm * gridDim.y;
    int wid = blockIdx.x + nbm * blockIdx.y;
    wid = (wid & 7) * (nwg >> 3) + (wid >> 3);
    bm = wid % nbm; bn = wid / nbm;
  } else {
    bm = blockIdx.x; bn = blockIdx.y;
  }

  const int w = t >> 6, l = t & 63;
  const int wr = (w >> 1) * (BM / 2), wc = (w & 1) * 64;
  const int l15 = l & 15, l4 = l >> 4;
  const int kbeg = blockIdx.z * ksl;
  const int ntiles = ksl >> 5;

  // T2: pre-swizzled global column-block; key = (lds_row>>1)&3 = (t>>3)&3
  const int colblk = (((t & 3) ^ ((t >> 3) & 3))) * 8;
  const bf16* gA = A  + (size_t)(bm * BM  + (t >> 2)) * lda + colblk + kbeg;
  const bf16* gB = BT + (size_t)(bn * 128 + (t >> 2)) * ldb + colblk + kbeg;
  bf16* lA = As + w * 512;
  bf16* lB = Bs + w * 512;

  auto stage = [&](int tile, int buf) {
    const int k0 = tile * 32;
    gload16(gA + k0, lA + buf * ABUF);
    if constexpr (BM == 128)
      gload16(gA + (size_t)64 * lda + k0, lA + buf * ABUF + 2048);
    gload16(gB + k0, lB + buf * 4096);
    gload16(gB + (size_t)64 * ldb + k0, lB + buf * 4096 + 2048);
  };

  f32x4 acc[MR][4];
  #pragma unroll
  for (int m = 0; m < MR; ++m)
    #pragma unroll
    for (int n = 0; n < 4; ++n)
      acc[m][n] = (f32x4){0.f, 0.f, 0.f, 0.f};

  stage(0, 0);
  stage(1, 1);

  // T2 read-side swizzle: column-block = l4 ^ ((row>>1)&3); row%16 == l15
  const int rdcol = ((l4 ^ ((l15 >> 1) & 3))) * 8;

  int buf = 0;
  for (int kt = 0; kt < ntiles; ++kt) {
    if (kt + 2 < ntiles) {
      int pb = buf + 2; if (pb >= 3) pb -= 3;
      stage(kt + 2, pb);
      __builtin_amdgcn_sched_barrier(0);
      if constexpr (BM == 128) asm volatile("s_waitcnt vmcnt(8)" ::: "memory");
      else                     asm volatile("s_waitcnt vmcnt(6)" ::: "memory");
    } else if (kt + 1 < ntiles) {
      if constexpr (BM == 128) asm volatile("s_waitcnt vmcnt(4)" ::: "memory");
      else                     asm volatile("s_waitcnt vmcnt(3)" ::: "memory");
    } else {
      asm volatile("s_waitcnt vmcnt(0)" ::: "memory");
    }
    __builtin_amdgcn_s_barrier();          // all waves: tile kt resident
    __builtin_amdgcn_sched_barrier(0);     // no ds_read hoists above barrier

    const bf16* Ab = As + buf * ABUF;
    const bf16* Bb = Bs + buf * 4096;
    bf16x8 af[MR], bfr[4];
    #pragma unroll
    for (int m = 0; m < MR; ++m)
      af[m] = *(const bf16x8*)&Ab[(wr + m * 16 + l15) * 32 + rdcol];
    #pragma unroll
    for (int n = 0; n < 4; ++n)
      bfr[n] = *(const bf16x8*)&Bb[(wc + n * 16 + l15) * 32 + rdcol];
    #pragma unroll
    for (int m = 0; m < MR; ++m)
      #pragma unroll
      for (int n = 0; n < 4; ++n)
        acc[m][n] = mfma16(af[m], bfr[n], acc[m][n]);

    __builtin_amdgcn_sched_barrier(0);     // reads stay before barrier
    __builtin_amdgcn_s_barrier();          // buf kt now dead for overwrite
    if (++buf >= 3) buf = 0;
  }

  const int crow = bm * BM + wr, ccol = bn * 128 + wc;
  #pragma unroll
  for (int n = 0; n < 4; ++n) {
    const int col = ccol + n * 16 + l15;
    float bv = 0.f;
    if (EPI == 1 || EPI == 2) bv = bias[col];
    #pragma unroll
    for (int m = 0; m < MR; ++m) {
      const int row = crow + m * 16 + l4 * 4;
      #pragma unroll
      for (int r = 0; r < 4; ++r) {
        const float v = acc[m][n][r];
        if (EPI == 0) {
          ((bf16*)Cp)[(size_t)(row + r) * ldc + col] = f2b(v);
        } else if (EPI == 1) {
          ((float*)Cp)[(size_t)(row + r) * ldc + col] = v + bv;
        } else if (EPI == 2) {
          const float u = v + bv;
          const float gel = 0.5f * u * (1.0f + erff(u * 0.70710678118654752f));
          ((bf16*)Cp)[(size_t)(row + r) * ldc + col] = f2b(gel);
        } else {
          const int M = gridDim.x * BM;
          ((float*)Cp)[((size_t)blockIdx.z * M + row + r) * ldc + col] = v;
        }
      }
    }
  }
}

// ------------- 256x256 8-wave pipelined GEMM (logits): C = A*BT^T + bias, f32 out
// 512 threads (2Mx4N waves), BK=64, 2 LDS buffers (128 KB), counted vmcnt(8),
// conflict-free XOR swizzle (pre-swizzled global source, swizzled ds_read).
// grid: (M/256, N/256), nwg % 8 == 0 (XCD swizzle).
__global__ __launch_bounds__(512, 2) void gemm256(
    const bf16* __restrict__ A, int lda,
    const bf16* __restrict__ BT, int ldb,
    float* __restrict__ C, int ldc,
    const float* __restrict__ bias, int K)
{
  __shared__ bf16 As[2][16384];
  __shared__ bf16 Bs[2][16384];
  const int t = threadIdx.x;

  const int nbm = gridDim.x;
  const int nwg = nbm * gridDim.y;
  int wid = blockIdx.x + nbm * blockIdx.y;
  wid = (wid & 7) * (nwg >> 3) + (wid >> 3);
  const int bm = wid % nbm, bn = wid / nbm;

  const int w = t >> 6, l = t & 63;
  const int wm = w >> 2, wn = w & 3;
  const int l15 = l & 15, l4 = l >> 4;

  // staging: batch i covers rows i*64+(t>>3); global col pre-swizzled so the
  // linear LDS dest [row][ (t&7)*8 ] holds col-block ((t&7)^(row&7))
  const int scol = ((t & 7) ^ ((t >> 3) & 7)) * 8;
  const bf16* gA = A  + (size_t)(bm * 256 + (t >> 3)) * lda + scol;
  const bf16* gB = BT + (size_t)(bn * 256 + (t >> 3)) * ldb + scol;
  const int ldst = w * 512;  // + implicit lane*8 elems from gload_lds

  auto stage = [&](int kt, int buf) {
    const int k0 = kt * 64;
    #pragma unroll
    for (int i = 0; i < 4; ++i)
      gload16(gA + (size_t)(i * 64) * lda + k0, &As[buf][i * 4096 + ldst]);
    #pragma unroll
    for (int i = 0; i < 4; ++i)
      gload16(gB + (size_t)(i * 64) * ldb + k0, &Bs[buf][i * 4096 + ldst]);
  };

  f32x4 acc[8][4];
  #pragma unroll
  for (int m = 0; m < 8; ++m)
    #pragma unroll
    for (int n = 0; n < 4; ++n)
      acc[m][n] = (f32x4){0.f, 0.f, 0.f, 0.f};

  const int NT = K >> 6;
  stage(0, 0);

  const int arow = wm * 128 + l15;  // + m*16
  const int brow = wn * 64 + l15;   // + n*16

  for (int kt = 0; kt < NT; ++kt) {
    const int buf = kt & 1;
    if (kt + 1 < NT) {
      stage(kt + 1, buf ^ 1);
      __builtin_amdgcn_sched_barrier(0);
      asm volatile("s_waitcnt vmcnt(8)" ::: "memory");  // kt landed; kt+1 in flight
    } else {
      asm volatile("s_waitcnt vmcnt(0)" ::: "memory");
    }
    __builtin_amdgcn_s_barrier();          // tile kt visible to all waves
    __builtin_amdgcn_sched_barrier(0);

    #pragma unroll
    for (int ks = 0; ks < 2; ++ks) {
      const int csw = ((ks * 4 + l4) ^ (l15 & 7)) * 8;
      bf16x8 af[8], bfr[4];
      #pragma unroll
      for (int m = 0; m < 8; ++m)
        af[m] = *(const bf16x8*)&As[buf][(arow + m * 16) * 64 + csw];
      #pragma unroll
      for (int n = 0; n < 4; ++n)
        bfr[n] = *(const bf16x8*)&Bs[buf][(brow + n * 16) * 64 + csw];
      __builtin_amdgcn_s_setprio(1);
      #pragma unroll
      for (int m = 0; m < 8; ++m)
        #pragma unroll
        for (int n = 0; n < 4; ++n)
          acc[m][n] = mfma16(af[m], bfr[n], acc[m][n]);
      __builtin_amdgcn_s_setprio(0);
    }

    __builtin_amdgcn_sched_barrier(0);     // reads complete before barrier
    __builtin_amdgcn_s_barrier();          // buf kt dead -> safe to overwrite
  }

  #pragma unroll
  for (int n = 0; n < 4; ++n) {
    const int col = bn * 256 + wn * 64 + n * 16 + l15;
    const float bv = bias[col];
    #pragma unroll
    for (int m = 0; m < 8; ++m) {
      const int row = bm * 256 + wm * 128 + m * 16 + l4 * 4;
      #pragma unroll
      for (int r = 0; r < 4; ++r)
        C[(size_t)(row + r) * ldc + col] = acc[m][n][r] + bv;
    }
  }
}

// ---------------- flash attention (LDS XOR-swizzled) ----------------
// grid: (S/128, B*H), block 256 (4 waves; wave w owns q-rows w*32..w*32+31)
__global__ __launch_bounds__(256) void attn_kernel(
    const bf16* __restrict__ qkv, const bf16* __restrict__ vT,
    const int* __restrict__ tokens, bf16* __restrict__ ctx)
{
  __shared__ bf16 Ks[128 * 64];
  __shared__ bf16 VTs[64 * 128];
  __shared__ bf16 Ps[128 * 128];

  const int qt = blockIdx.x;
  const int bh = blockIdx.y;
  const int b = bh >> 4, h = bh & 15;
  const int t = threadIdx.x, w = t >> 6, l = t & 63;
  const int l15 = l & 15, l4 = l >> 4;
  const int q0 = qt * 128;

  bf16x8 aq[2][2];
  #pragma unroll
  for (int m = 0; m < 2; ++m)
    #pragma unroll
    for (int ks = 0; ks < 2; ++ks)
      aq[m][ks] = *(const bf16x8*)(qkv +
          (size_t)(b * 1024 + q0 + w * 32 + m * 16 + l15) * 3072 +
          h * 64 + ks * 32 + l4 * 8);

  f32x4 o[2][4];
  float m_run[2][4], l_run[2][4];
  #pragma unroll
  for (int m = 0; m < 2; ++m)
    #pragma unroll
    for (int r = 0; r < 4; ++r) { m_run[m][r] = -1e30f; l_run[m][r] = 0.f; }
  #pragma unroll
  for (int m = 0; m < 2; ++m)
    #pragma unroll
    for (int nn = 0; nn < 4; ++nn)
      o[m][nn] = (f32x4){0.f, 0.f, 0.f, 0.f};

  const bf16* kb = qkv + (size_t)(b * 1024) * 3072 + 1024 + h * 64;
  const bf16* vb = vT + (size_t)(bh * 64) * 1024;
  const int* tb = tokens + b * 1024;

  const int kSrcCol = ((t & 7) ^ ((t >> 3) & 7)) * 8;
  const int vSrcCol = ((t & 15) ^ (t >> 4)) * 8;

  for (int jt = 0; jt <= qt; ++jt) {
    const int j0 = jt * 128;
    __syncthreads();
    #pragma unroll
    for (int i = 0; i < 4; ++i)
      gload16(kb + (size_t)(j0 + i * 32 + (t >> 3)) * 3072 + kSrcCol,
              Ks + i * 2048 + w * 512);
    #pragma unroll
    for (int i = 0; i < 4; ++i)
      gload16(vb + (size_t)(i * 16 + (t >> 4)) * 1024 + j0 + vSrcCol,
              VTs + i * 2048 + w * 512);
    __syncthreads();

    f32x4 s[2][8];
    #pragma unroll
    for (int m = 0; m < 2; ++m)
      #pragma unroll
      for (int n = 0; n < 8; ++n)
        s[m][n] = (f32x4){0.f, 0.f, 0.f, 0.f};
    #pragma unroll
    for (int ks = 0; ks < 2; ++ks) {
      #pragma unroll
      for (int n = 0; n < 8; ++n) {
        const bf16x8 bk = *(const bf16x8*)
            &Ks[(n * 16 + l15) * 64 + ((ks * 32 + l4 * 8) ^ ((l15 & 7) * 8))];
        #pragma unroll
        for (int m = 0; m < 2; ++m)
          s[m][n] = mfma16(aq[m][ks], bk, s[m][n]);
      }
    }

    float padv[8];
    #pragma unroll
    for (int n = 0; n < 8; ++n)
      padv[n] = (tb[j0 + n * 16 + l15] == 0) ? 1.f : 0.f;

    #pragma unroll
    for (int m = 0; m < 2; ++m) {
      #pragma unroll
      for (int r = 0; r < 4; ++r) {
        const int rloc = l4 * 4 + r;
        const int qrow = q0 + w * 32 + m * 16 + rloc;
        float vals[8];
        float mx = -1e30f;
        #pragma unroll
        for (int n = 0; n < 8; ++n) {
          const int jg = j0 + n * 16 + l15;
          float v = s[m][n][r] * 0.125f;
          if (jg > qrow || padv[n] != 0.f) v = -1e9f;
          vals[n] = v;
          mx = fmaxf(mx, v);
        }
        #pragma unroll
        for (int d = 1; d < 16; d <<= 1) mx = fmaxf(mx, __shfl_xor(mx, d));
        const float newm = fmaxf(m_run[m][r], mx);
        const float sc = __expf(m_run[m][r] - newm);
        m_run[m][r] = newm;
        float rs = 0.f;
        #pragma unroll
        for (int n = 0; n < 8; ++n) {
          const float pv = __expf(vals[n] - newm);
          vals[n] = pv;
          rs += pv;
        }
        #pragma unroll
        for (int d = 1; d < 16; d <<= 1) rs += __shfl_xor(rs, d);
        l_run[m][r] = l_run[m][r] * sc + rs;
        #pragma unroll
        for (int nn = 0; nn < 4; ++nn) o[m][nn][r] = o[m][nn][r] * sc;
        #pragma unroll
        for (int n = 0; n < 8; ++n)
          Ps[(w * 32 + m * 16 + rloc) * 128 +
             ((n * 16 + l15) ^ (rloc * 8))] = f2b(vals[n]);
      }
    }
    __syncthreads();

    #pragma unroll
    for (int ks = 0; ks < 4; ++ks) {
      bf16x8 ap[2];
      #pragma unroll
      for (int m = 0; m < 2; ++m)
        ap[m] = *(const bf16x8*)
            &Ps[(w * 32 + m * 16 + l15) * 128 + ((ks * 32 + l4 * 8) ^ (l15 * 8))];
      #pragma unroll
      for (int nn = 0; nn < 4; ++nn) {
        const bf16x8 bv = *(const bf16x8*)
            &VTs[(nn * 16 + l15) * 128 + ((ks * 32 + l4 * 8) ^ (l15 * 8))];
        #pragma unroll
        for (int m = 0; m < 2; ++m)
          o[m][nn] = mfma16(ap[m], bv, o[m][nn]);
      }
    }
  }

  #pragma unroll
  for (int m = 0; m < 2; ++m) {
    #pragma unroll
    for (int r = 0; r < 4; ++r) {
      const float inv = 1.0f / l_run[m][r];
      const int qrow = q0 + w * 32 + m * 16 + l4 * 4 + r;
      #pragma unroll
      for (int nn = 0; nn < 4; ++nn)
        ctx[(size_t)(b * 1024 + qrow) * 1024 + h * 64 + nn * 16 + l15] =
            f2b(o[m][nn][r] * inv);
    }
  }
}

// ------------- fixup for all-masked rows (leading pad tokens) -------------
__global__ __launch_bounds__(64) void attn_fixup_kernel(
    const int* __restrict__ tokens, const bf16* __restrict__ vT,
    bf16* __restrict__ ctx)
{
  const int bh = blockIdx.x;
  const int b = bh >> 4, h = bh & 15;
  __shared__ int p0s;
  if (threadIdx.x == 0) {
    int p = 0;
    const int* tb = tokens + b * 1024;
    while (p < 1024 && tb[p] == 0) ++p;
    p0s = p;
  }
  __syncthreads();
  const int P0 = p0s;
  if (P0 == 0) return;
  const int dk = threadIdx.x;
  const bf16* vrow = vT + (size_t)(bh * 64 + dk) * 1024;
  float sum = 0.f;
  for (int sIdx = 0; sIdx < 1024; ++sIdx) sum += b2f(vrow[sIdx]);
  const bf16 mv = f2b(sum * (1.0f / 1024.0f));
  for (int q = 0; q < P0; ++q)
    ctx[(size_t)(b * 1024 + q) * 1024 + h * 64 + dk] = mv;
}

// ---------------- host ----------------
extern "C" void kernel_launch(void* const* d_in, const int* in_sizes, int n_in,
                              void* d_out, int out_size, void* d_ws, size_t ws_size,
                              hipStream_t stream)
{
  (void)in_sizes; (void)n_in; (void)out_size;
  const int*   tokens = (const int*)d_in[0];
  const float* emb  = (const float*)d_in[1];
  const float* pe   = (const float*)d_in[2];
  const float* Wq   = (const float*)d_in[3];
  const float* Wk   = (const float*)d_in[4];
  const float* Wv   = (const float*)d_in[5];
  const float* Wo   = (const float*)d_in[6];
  const float* bo   = (const float*)d_in[7];
  const float* g1   = (const float*)d_in[8];
  const float* be1  = (const float*)d_in[9];
  const float* g2   = (const float*)d_in[10];
  const float* be2  = (const float*)d_in[11];
  const float* W1   = (const float*)d_in[12];
  const float* b1   = (const float*)d_in[13];
  const float* W2   = (const float*)d_in[14];
  const float* b2   = (const float*)d_in[15];
  const float* gf   = (const float*)d_in[16];
  const float* bff  = (const float*)d_in[17];
  const float* Wout = (const float*)d_in[18];
  const float* bout = (const float*)d_in[19];
  float* out = (float*)d_out;

  char* p = (char*)d_ws;
  auto alloc = [&](size_t bytes) {
    char* q = p;
    p += (bytes + 255) & ~(size_t)255;
    return q;
  };
  float* x    = (float*)alloc((size_t)2048 * 1024 * 4);
  float* Pp   = (float*)alloc((size_t)4 * 2048 * 1024 * 4);  // K-slice partials
  bf16* h     = (bf16*)alloc((size_t)2048 * 1024 * 2);
  bf16* qkv   = (bf16*)alloc((size_t)2048 * 3072 * 2);
  bf16* vT    = (bf16*)alloc((size_t)2048 * 1024 * 2);
  bf16* ctx   = (bf16*)alloc((size_t)2048 * 1024 * 2);
  bf16* ff    = (bf16*)alloc((size_t)2048 * 4096 * 2);
  bf16* WoutT = (bf16*)alloc((size_t)32000 * 1024 * 2);

  const size_t DD = (size_t)1024 * 1024;
  const size_t DF = (size_t)1024 * 4096;

  const size_t perLayerW = (3 * DD + DD + DF + DF) * 2;
  const size_t used = (size_t)(p - (char*)d_ws);
  const bool fullprep = ws_size >= used + 6 * perLayerW + 8192;
  const int NL = fullprep ? 6 : 1;
  bf16* WqkvT = (bf16*)alloc((size_t)NL * 3 * DD * 2);
  bf16* WoT   = (bf16*)alloc((size_t)NL * DD * 2);
  bf16* W1T   = (bf16*)alloc((size_t)NL * DF * 2);
  bf16* W2T   = (bf16*)alloc((size_t)NL * DF * 2);

  if (fullprep)
    prep_all_kernel<<<6 * 3072, 256, 0, stream>>>(
        Wq, Wk, Wv, Wo, W1, W2, WqkvT, WoT, W1T, W2T);

  embed_kernel<<<2048, 256, 0, stream>>>(tokens, emb, pe, x);

  for (int l = 0; l < 6; ++l) {
    const bf16* wqkvt; const bf16* wot; const bf16* w1t; const bf16* w2t;
    if (fullprep) {
      wqkvt = WqkvT + (size_t)l * 3 * DD;
      wot   = WoT   + (size_t)l * DD;
      w1t   = W1T   + (size_t)l * DF;
      w2t   = W2T   + (size_t)l * DF;
    } else {
      prep_layer_kernel<<<3072, 256, 0, stream>>>(
          Wq + l * DD, Wk + l * DD, Wv + l * DD, Wo + l * DD,
          W1 + l * DF, W2 + l * DF, WqkvT, WoT, W1T, W2T);
      wqkvt = WqkvT; wot = WoT; w1t = W1T; w2t = W2T;
    }

    // ln1: layer 0 plain; later layers fold the previous FFN2 partials
    if (l == 0)
      ln_kernel<<<2048, 256, 0, stream>>>(x, g1, be1, h);
    else
      ln_res_kernel<<<2048, 256, 0, stream>>>(
          x, Pp, 4, b2 + (l - 1) * 1024, g1 + l * 1024, be1 + l * 1024, h);

    // QKV: M=2048 N=3072 K=1024, BM=64 -> 768 blocks
    gemm_pl<0, 64, 0><<<dim3(32, 24, 1), 256, 0, stream>>>(
        h, 1024, wqkvt, 1024, qkv, 3072, (const float*)nullptr, 1024);
    transpose_v_kernel<<<dim3(16, 32), 256, 0, stream>>>(qkv, vT);
    attn_kernel<<<dim3(8, 32), 256, 0, stream>>>(qkv, vT, tokens, ctx);
    attn_fixup_kernel<<<32, 64, 0, stream>>>(tokens, vT, ctx);
    // Wo: M=2048 N=1024 K=1024, BM=64 + splitK2 -> 512 blocks, partials
    gemm_pl<3, 64, 0><<<dim3(32, 8, 2), 256, 0, stream>>>(
        ctx, 1024, wot, 1024, Pp, 1024, (const float*)nullptr, 512);
    // ln2: x += Pw0+Pw1 + bo; h = LN(x)
    ln_res_kernel<<<2048, 256, 0, stream>>>(
        x, Pp, 2, bo + l * 1024, g2 + l * 1024, be2 + l * 1024, h);
    // FFN1: M=2048 N=4096 K=1024, BM=128 -> 512 blocks
    gemm_pl<2, 128, 0><<<dim3(16, 32, 1), 256, 0, stream>>>(
        h, 1024, w1t, 1024, ff, 4096, b1 + l * 4096, 1024);
    // FFN2: M=2048 N=1024 K=4096, BM=128 + splitK4 -> 512 blocks, partials
    gemm_pl<3, 128, 0><<<dim3(16, 8, 4), 256, 0, stream>>>(
        ff, 4096, w2t, 4096, Pp, 1024, (const float*)nullptr, 1024);
  }

  // final LN folds layer-5 FFN2 partials
  ln_res_kernel<<<2048, 256, 0, stream>>>(x, Pp, 4, b2 + 5 * 1024, gf, bff, h);
  transpose_cast_kernel<<<dim3(500, 16), 256, 0, stream>>>(Wout, WoutT, 32000, 1024);
  // logits: M=2048 N=32000 K=1024 -> 256x256 8-wave pipeline, 1000 blocks
  gemm256<<<dim3(8, 125), 512, 0, stream>>>(
      h, 1024, WoutT, 1024, out, 32000, bout, 1024);
}

// Round 8
// 1474.977 us; speedup vs baseline: 1.1170x; 1.0121x over previous
//
#include <hip/hip_runtime.h>
#include <hip/hip_bf16.h>
#include <stdint.h>

typedef __hip_bfloat16 bf16;
typedef __attribute__((ext_vector_type(8))) short bf16x8;
typedef __attribute__((ext_vector_type(4))) float f32x4;

#define DEV static __device__ __forceinline__

DEV float b2f(bf16 v) { return __bfloat162float(v); }
DEV bf16  f2b(float v) { return __float2bfloat16(v); }

DEV void gload16(const void* g, void* l) {
  __builtin_amdgcn_global_load_lds(
      (__attribute__((address_space(1))) void*)(void*)g,
      (__attribute__((address_space(3))) void*)l, 16, 0, 0);
}

DEV f32x4 mfma16(bf16x8 a, bf16x8 b, f32x4 c) {
  return __builtin_amdgcn_mfma_f32_16x16x32_bf16(a, b, c, 0, 0, 0);
}

// ---------------- embed: x = emb[tok]*32 + pe (all f32) ----------------
__global__ __launch_bounds__(256) void embed_kernel(
    const int* __restrict__ tok, const float* __restrict__ emb,
    const float* __restrict__ pe, float* __restrict__ x)
{
  const int r = blockIdx.x, t = threadIdx.x;
  const int s = r & 1023;
  const int tk = tok[r];
  const int d = t * 4;
  const float* ep = emb + (size_t)tk * 1024 + d;
  const float* pp = pe + (size_t)s * 1024 + d;
  float* xp = x + (size_t)r * 1024 + d;
  #pragma unroll
  for (int j = 0; j < 4; ++j)
    xp[j] = ep[j] * 32.0f + pp[j];
}

// ---------------- layernorm: h = LN(x)*g + b (f32 in, bf16 out) ----------------
__global__ __launch_bounds__(256) void ln_kernel(
    const float* __restrict__ x, const float* __restrict__ g,
    const float* __restrict__ be, bf16* __restrict__ h)
{
  const int r = blockIdx.x, t = threadIdx.x;
  const float4 v = ((const float4*)(x + (size_t)r * 1024))[t];
  float s  = v.x + v.y + v.z + v.w;
  float sq = v.x * v.x + v.y * v.y + v.z * v.z + v.w * v.w;
  #pragma unroll
  for (int d = 1; d < 64; d <<= 1) {
    s  += __shfl_xor(s, d);
    sq += __shfl_xor(sq, d);
  }
  __shared__ float red[8];
  const int w = t >> 6, l = t & 63;
  if (l == 0) { red[w] = s; red[4 + w] = sq; }
  __syncthreads();
  s  = red[0] + red[1] + red[2] + red[3];
  sq = red[4] + red[5] + red[6] + red[7];
  const float mean = s * (1.0f / 1024.0f);
  const float var  = sq * (1.0f / 1024.0f) - mean * mean;
  const float inv  = 1.0f / sqrtf(var + 1e-5f);
  bf16* hp = h + (size_t)r * 1024 + t * 4;
  const float* gp = g + t * 4;
  const float* bp = be + t * 4;
  const float vv[4] = {v.x, v.y, v.z, v.w};
  #pragma unroll
  for (int j = 0; j < 4; ++j)
    hp[j] = f2b((vv[j] - mean) * inv * gp[j] + bp[j]);
}

// ------- fused residual + layernorm: x += sum(P[0..np)) + bias; h = LN(x)*g+be
__global__ __launch_bounds__(256) void ln_res_kernel(
    float* __restrict__ x, const float* __restrict__ P, int np,
    const float* __restrict__ bias, const float* __restrict__ g,
    const float* __restrict__ be, bf16* __restrict__ h)
{
  const int r = blockIdx.x, t = threadIdx.x;
  float4 v = ((const float4*)(x + (size_t)r * 1024))[t];
  for (int i = 0; i < np; ++i) {
    const float4 pv = ((const float4*)(P + ((size_t)i * 2048 + r) * 1024))[t];
    v.x += pv.x; v.y += pv.y; v.z += pv.z; v.w += pv.w;
  }
  const float4 bv = ((const float4*)bias)[t];
  v.x += bv.x; v.y += bv.y; v.z += bv.z; v.w += bv.w;

  float s  = v.x + v.y + v.z + v.w;
  float sq = v.x * v.x + v.y * v.y + v.z * v.z + v.w * v.w;
  #pragma unroll
  for (int d = 1; d < 64; d <<= 1) {
    s  += __shfl_xor(s, d);
    sq += __shfl_xor(sq, d);
  }
  __shared__ float red[8];
  const int w = t >> 6, l = t & 63;
  if (l == 0) { red[w] = s; red[4 + w] = sq; }
  __syncthreads();
  s  = red[0] + red[1] + red[2] + red[3];
  sq = red[4] + red[5] + red[6] + red[7];
  const float mean = s * (1.0f / 1024.0f);
  const float var  = sq * (1.0f / 1024.0f) - mean * mean;
  const float inv  = 1.0f / sqrtf(var + 1e-5f);

  ((float4*)(x + (size_t)r * 1024))[t] = v;
  bf16* hp = h + (size_t)r * 1024 + t * 4;
  const float* gp = g + t * 4;
  const float* bp = be + t * 4;
  const float vv[4] = {v.x, v.y, v.z, v.w};
  #pragma unroll
  for (int j = 0; j < 4; ++j)
    hp[j] = f2b((vv[j] - mean) * inv * gp[j] + bp[j]);
}

// ------------- 64x64 transpose+cast tile body -------------
DEV void transpose_tile(const float* __restrict__ in, bf16* __restrict__ out,
                        int ldin, int ldout, int r0, int c0, int t)
{
  __shared__ bf16 tile[64][64];
  #pragma unroll
  for (int i = 0; i < 4; ++i) {
    const int r = i * 16 + (t >> 4), c = (t & 15) * 4;
    const float4 v = *(const float4*)&in[(size_t)(r0 + r) * ldin + c0 + c];
    tile[r][c + 0] = f2b(v.x);
    tile[r][c + 1] = f2b(v.y);
    tile[r][c + 2] = f2b(v.z);
    tile[r][c + 3] = f2b(v.w);
  }
  __syncthreads();
  #pragma unroll
  for (int i = 0; i < 2; ++i) {
    const int oc = i * 32 + (t >> 3);
    const int rr = (t & 7) * 8;
    unsigned short tmp[8] __attribute__((aligned(16)));
    #pragma unroll
    for (int j = 0; j < 8; ++j)
      tmp[j] = ((const unsigned short*)tile)[(rr + j) * 64 + oc];
    *(uint4*)&out[(size_t)(c0 + oc) * ldout + r0 + rr] = *(const uint4*)tmp;
  }
}

// generic single-matrix transpose+cast (used for Wout)
__global__ __launch_bounds__(256) void transpose_cast_kernel(
    const float* __restrict__ in, bf16* __restrict__ out, int ldin, int ldout)
{
  transpose_tile(in, out, ldin, ldout, blockIdx.y * 64, blockIdx.x * 64, threadIdx.x);
}

// dispatch one 64x64 tile of the per-layer weight set (3072 tiles/layer)
DEV void prep_dispatch(int wid,
    const float* Wq, const float* Wk, const float* Wv, const float* Wo,
    const float* W1, const float* W2,
    bf16* WqkvT, bf16* WoT, bf16* W1T, bf16* W2T, int t)
{
  const float* src; bf16* dst; int ldin, ldout, tx, ty;
  if (wid < 768) {
    const int m = wid >> 8, tt = wid & 255;
    src = (m == 0) ? Wq : (m == 1) ? Wk : Wv;
    dst = WqkvT + (size_t)m * 1024 * 1024;
    ldin = 1024; ldout = 1024; tx = tt & 15; ty = tt >> 4;
  } else if (wid < 1024) {
    const int tt = wid - 768;
    src = Wo; dst = WoT; ldin = 1024; ldout = 1024; tx = tt & 15; ty = tt >> 4;
  } else if (wid < 2048) {
    const int tt = wid - 1024;
    src = W1; dst = W1T; ldin = 4096; ldout = 1024; tx = tt & 63; ty = tt >> 6;
  } else {
    const int tt = wid - 2048;
    src = W2; dst = W2T; ldin = 1024; ldout = 4096; tx = tt & 15; ty = tt >> 4;
  }
  transpose_tile(src, dst, ldin, ldout, ty * 64, tx * 64, t);
}

// per-layer weight prep (fallback path)
__global__ __launch_bounds__(256) void prep_layer_kernel(
    const float* __restrict__ Wq, const float* __restrict__ Wk,
    const float* __restrict__ Wv, const float* __restrict__ Wo,
    const float* __restrict__ W1, const float* __restrict__ W2,
    bf16* __restrict__ WqkvT, bf16* __restrict__ WoT,
    bf16* __restrict__ W1T, bf16* __restrict__ W2T)
{
  prep_dispatch(blockIdx.x, Wq, Wk, Wv, Wo, W1, W2,
                WqkvT, WoT, W1T, W2T, threadIdx.x);
}

// all-layers weight prep (when ws permits): 6*3072 blocks
__global__ __launch_bounds__(256) void prep_all_kernel(
    const float* __restrict__ Wq, const float* __restrict__ Wk,
    const float* __restrict__ Wv, const float* __restrict__ Wo,
    const float* __restrict__ W1, const float* __restrict__ W2,
    bf16* __restrict__ WqkvT, bf16* __restrict__ WoT,
    bf16* __restrict__ W1T, bf16* __restrict__ W2T)
{
  const int layer = blockIdx.x / 3072;
  const int wid = blockIdx.x - layer * 3072;
  const size_t DD = (size_t)1024 * 1024, DF = (size_t)1024 * 4096;
  prep_dispatch(wid,
      Wq + layer * DD, Wk + layer * DD, Wv + layer * DD, Wo + layer * DD,
      W1 + layer * DF, W2 + layer * DF,
      WqkvT + layer * 3 * DD, WoT + layer * DD,
      W1T + layer * DF, W2T + layer * DF, threadIdx.x);
}

// ---- v transpose (bf16->bf16): vT[bh][dk][s] = qkv[b*S+s][2048+h*64+dk] ----
// grid: (S/64, B*H), block 256
__global__ __launch_bounds__(256) void transpose_v_kernel(
    const bf16* __restrict__ qkv, bf16* __restrict__ vT)
{
  __shared__ bf16 tile[64][64];
  const int t = threadIdx.x;
  const int s0 = blockIdx.x * 64;
  const int bh = blockIdx.y;
  const int b = bh >> 4, h = bh & 15;
  const bf16* in = qkv + (size_t)(b * 1024) * 3072 + 2048 + h * 64;
  #pragma unroll
  for (int i = 0; i < 2; ++i) {
    const int r = i * 32 + (t >> 3), c = (t & 7) * 8;
    *(uint4*)&tile[r][c] = *(const uint4*)&in[(size_t)(s0 + r) * 3072 + c];
  }
  __syncthreads();
  bf16* out = vT + (size_t)(bh * 64) * 1024;
  #pragma unroll
  for (int i = 0; i < 2; ++i) {
    const int oc = i * 32 + (t >> 3);   // dk
    const int rr = (t & 7) * 8;         // s offset
    unsigned short tmp[8] __attribute__((aligned(16)));
    #pragma unroll
    for (int j = 0; j < 8; ++j)
      tmp[j] = ((const unsigned short*)tile)[(rr + j) * 64 + oc];
    *(uint4*)&out[(size_t)oc * 1024 + s0 + rr] = *(const uint4*)tmp;
  }
}

// ------------- pipelined GEMM: C(MxN) = A(MxK,row) * BT(NxK,row)^T -------------
// 3-buffer LDS, 2-tiles-ahead prefetch, counted vmcnt (T4), raw barriers,
// T2 bank-conflict XOR swizzle (pre-swizzled global source + swizzled ds_read).
// EPI: 0 = bf16 store; 1 = +bias f32 store (logits); 2 = gelu(acc+bias) bf16;
//      3 = f32 K-slice partial store P[z][M][N] (no bias; reduced in ln_res)
// grid: (M/BM, N/128, KSLICES), block 256 (4 waves), K-slice length ksl
template<int EPI, int BM, int SWZ>
__global__ __launch_bounds__(256) void gemm_pl(
    const bf16* __restrict__ A, int lda,
    const bf16* __restrict__ BT, int ldb,
    void* __restrict__ Cp, int ldc,
    const float* __restrict__ bias,
    int ksl)
{
  constexpr int ABUF = BM * 32;               // elems per A buffer
  constexpr int MR = BM / 32;                 // m-fragment repeats per wave
  __shared__ bf16 As[3 * ABUF];
  __shared__ bf16 Bs[3 * 4096];
  const int t = threadIdx.x;

  int bm, bn;
  if constexpr (SWZ) {                        // XCD-chunked swizzle (nwg%8==0)
    const int nbm = gridDim.x;
    const int nwg = nbm * gridDim.y;
    int wid = blockIdx.x + nbm * blockIdx.y;
    wid = (wid & 7) * (nwg >> 3) + (wid >> 3);
    bm = wid % nbm; bn = wid / nbm;
  } else {
    bm = blockIdx.x; bn = blockIdx.y;
  }

  const int w = t >> 6, l = t & 63;
  const int wr = (w >> 1) * (BM / 2), wc = (w & 1) * 64;
  const int l15 = l & 15, l4 = l >> 4;
  const int kbeg = blockIdx.z * ksl;
  const int ntiles = ksl >> 5;

  // T2: pre-swizzled global column-block; key = (lds_row>>1)&3 = (t>>3)&3
  const int colblk = (((t & 3) ^ ((t >> 3) & 3))) * 8;
  const bf16* gA = A  + (size_t)(bm * BM  + (t >> 2)) * lda + colblk + kbeg;
  const bf16* gB = BT + (size_t)(bn * 128 + (t >> 2)) * ldb + colblk + kbeg;
  bf16* lA = As + w * 512;
  bf16* lB = Bs + w * 512;

  auto stage = [&](int tile, int buf) {
    const int k0 = tile * 32;
    gload16(gA + k0, lA + buf * ABUF);
    if constexpr (BM == 128)
      gload16(gA + (size_t)64 * lda + k0, lA + buf * ABUF + 2048);
    gload16(gB + k0, lB + buf * 4096);
    gload16(gB + (size_t)64 * ldb + k0, lB + buf * 4096 + 2048);
  };

  f32x4 acc[MR][4];
  #pragma unroll
  for (int m = 0; m < MR; ++m)
    #pragma unroll
    for (int n = 0; n < 4; ++n)
      acc[m][n] = (f32x4){0.f, 0.f, 0.f, 0.f};

  stage(0, 0);
  stage(1, 1);

  // T2 read-side swizzle: column-block = l4 ^ ((row>>1)&3); row%16 == l15
  const int rdcol = ((l4 ^ ((l15 >> 1) & 3))) * 8;

  int buf = 0;
  for (int kt = 0; kt < ntiles; ++kt) {
    if (kt + 2 < ntiles) {
      int pb = buf + 2; if (pb >= 3) pb -= 3;
      stage(kt + 2, pb);
      __builtin_amdgcn_sched_barrier(0);
      if constexpr (BM == 128) asm volatile("s_waitcnt vmcnt(8)" ::: "memory");
      else                     asm volatile("s_waitcnt vmcnt(6)" ::: "memory");
    } else if (kt + 1 < ntiles) {
      if constexpr (BM == 128) asm volatile("s_waitcnt vmcnt(4)" ::: "memory");
      else                     asm volatile("s_waitcnt vmcnt(3)" ::: "memory");
    } else {
      asm volatile("s_waitcnt vmcnt(0)" ::: "memory");
    }
    __builtin_amdgcn_s_barrier();          // all waves: tile kt resident
    __builtin_amdgcn_sched_barrier(0);     // no ds_read hoists above barrier

    const bf16* Ab = As + buf * ABUF;
    const bf16* Bb = Bs + buf * 4096;
    bf16x8 af[MR], bfr[4];
    #pragma unroll
    for (int m = 0; m < MR; ++m)
      af[m] = *(const bf16x8*)&Ab[(wr + m * 16 + l15) * 32 + rdcol];
    #pragma unroll
    for (int n = 0; n < 4; ++n)
      bfr[n] = *(const bf16x8*)&Bb[(wc + n * 16 + l15) * 32 + rdcol];
    #pragma unroll
    for (int m = 0; m < MR; ++m)
      #pragma unroll
      for (int n = 0; n < 4; ++n)
        acc[m][n] = mfma16(af[m], bfr[n], acc[m][n]);

    __builtin_amdgcn_sched_barrier(0);     // reads stay before barrier
    __builtin_amdgcn_s_barrier();          // buf kt now dead for overwrite
    if (++buf >= 3) buf = 0;
  }

  const int crow = bm * BM + wr, ccol = bn * 128 + wc;
  #pragma unroll
  for (int n = 0; n < 4; ++n) {
    const int col = ccol + n * 16 + l15;
    float bv = 0.f;
    if (EPI == 1 || EPI == 2) bv = bias[col];
    #pragma unroll
    for (int m = 0; m < MR; ++m) {
      const int row = crow + m * 16 + l4 * 4;
      #pragma unroll
      for (int r = 0; r < 4; ++r) {
        const float v = acc[m][n][r];
        if (EPI == 0) {
          ((bf16*)Cp)[(size_t)(row + r) * ldc + col] = f2b(v);
        } else if (EPI == 1) {
          ((float*)Cp)[(size_t)(row + r) * ldc + col] = v + bv;
        } else if (EPI == 2) {
          const float u = v + bv;
          const float gel = 0.5f * u * (1.0f + erff(u * 0.70710678118654752f));
          ((bf16*)Cp)[(size_t)(row + r) * ldc + col] = f2b(gel);
        } else {
          const int M = gridDim.x * BM;
          ((float*)Cp)[((size_t)blockIdx.z * M + row + r) * ldc + col] = v;
        }
      }
    }
  }
}

// ------------- 256x256 8-wave phase-interleaved GEMM (logits) -------------
// BK=32, 3-buffer LDS ring (96 KB), 2-tiles-ahead prefetch, counted vmcnt(4),
// per K-tile 2 phases of {ds_read subtile || 2 stage loads -> lgkmcnt(0) ->
// setprio(1) 16 MFMA setprio(0) -> barrier} (m201/T3+T4+T5 schedule).
// Conflict-free XOR swizzle, key=(row>>1)&3 (verified 0-conflict in gemm_pl).
// grid: (M/256, N/256), nwg % 8 == 0 (XCD swizzle). 512 threads (2M x 4N waves).
__global__ __launch_bounds__(512, 2) void gemm256(
    const bf16* __restrict__ A, int lda,
    const bf16* __restrict__ BT, int ldb,
    float* __restrict__ C, int ldc,
    const float* __restrict__ bias, int K)
{
  __shared__ bf16 As[3][8192];
  __shared__ bf16 Bs[3][8192];
  const int t = threadIdx.x;

  const int nbm = gridDim.x;
  const int nwg = nbm * gridDim.y;
  int wid = blockIdx.x + nbm * blockIdx.y;
  wid = (wid & 7) * (nwg >> 3) + (wid >> 3);
  const int bm = wid % nbm, bn = wid / nbm;

  const int w = t >> 6, l = t & 63;
  const int wm = w >> 2, wn = w & 3;
  const int l15 = l & 15, l4 = l >> 4;

  // staging: thread t -> LDS row i*128 + (t>>2), col-block (t&3);
  // pre-swizzled global col-block with key (row>>1)&3 = (t>>3)&3
  const int colblk = ((t & 3) ^ ((t >> 3) & 3)) * 8;
  const bf16* gA = A  + (size_t)(bm * 256 + (t >> 2)) * lda + colblk;
  const bf16* gB = BT + (size_t)(bn * 256 + (t >> 2)) * ldb + colblk;
  const int dst = w * 512;   // wave-uniform LDS base within each 128-row half

  // read-side swizzle: col-block = l4 ^ ((row>>1)&3), row%16 == l15
  const int rd = (l4 ^ ((l15 >> 1) & 3)) * 8;
  const int arow = wm * 128 + l15;
  const int brow = wn * 64 + l15;

  f32x4 acc[8][4];
  #pragma unroll
  for (int m = 0; m < 8; ++m)
    #pragma unroll
    for (int n = 0; n < 4; ++n)
      acc[m][n] = (f32x4){0.f, 0.f, 0.f, 0.f};

  const int NT = K >> 5;

  auto stageA = [&](int kt, int buf) {
    const int k0 = kt * 32;
    gload16(gA + k0, &As[buf][dst]);
    gload16(gA + (size_t)128 * lda + k0, &As[buf][4096 + dst]);
  };
  auto stageB = [&](int kt, int buf) {
    const int k0 = kt * 32;
    gload16(gB + k0, &Bs[buf][dst]);
    gload16(gB + (size_t)128 * ldb + k0, &Bs[buf][4096 + dst]);
  };

  stageA(0, 0); stageB(0, 0);
  stageA(1, 1); stageB(1, 1);

  int buf = 0;
  for (int kt = 0; kt < NT; ++kt) {
    // tile kt's 4 loads landed; kt+1's (newest 4) stay in flight
    if (kt + 1 < NT) asm volatile("s_waitcnt vmcnt(4)" ::: "memory");
    else             asm volatile("s_waitcnt vmcnt(0)" ::: "memory");
    __builtin_amdgcn_s_barrier();           // buf[kt] visible to all waves
    __builtin_amdgcn_sched_barrier(0);

    int pb = buf + 2; if (pb >= 3) pb -= 3;  // ring slot for tile kt+2
    const bf16* Ab = As[buf];
    const bf16* Bb = Bs[buf];

    // ---- phase 0: B frags + A frags m0..3; prefetch A-half of kt+2
    bf16x8 bfr[4], af[4];
    #pragma unroll
    for (int n = 0; n < 4; ++n)
      bfr[n] = *(const bf16x8*)&Bb[(brow + n * 16) * 32 + rd];
    #pragma unroll
    for (int m = 0; m < 4; ++m)
      af[m] = *(const bf16x8*)&Ab[(arow + m * 16) * 32 + rd];
    if (kt + 2 < NT) stageA(kt + 2, pb);
    asm volatile("s_waitcnt lgkmcnt(0)" ::: "memory");
    __builtin_amdgcn_sched_barrier(0);
    __builtin_amdgcn_s_setprio(1);
    #pragma unroll
    for (int m = 0; m < 4; ++m)
      #pragma unroll
      for (int n = 0; n < 4; ++n)
        acc[m][n] = mfma16(af[m], bfr[n], acc[m][n]);
    __builtin_amdgcn_s_setprio(0);
    __builtin_amdgcn_sched_barrier(0);
    __builtin_amdgcn_s_barrier();

    // ---- phase 1: A frags m4..7; prefetch B-half of kt+2
    #pragma unroll
    for (int m = 0; m < 4; ++m)
      af[m] = *(const bf16x8*)&Ab[(arow + (m + 4) * 16) * 32 + rd];
    if (kt + 2 < NT) stageB(kt + 2, pb);
    asm volatile("s_waitcnt lgkmcnt(0)" ::: "memory");
    __builtin_amdgcn_sched_barrier(0);
    __builtin_amdgcn_s_setprio(1);
    #pragma unroll
    for (int m = 0; m < 4; ++m)
      #pragma unroll
      for (int n = 0; n < 4; ++n)
        acc[m + 4][n] = mfma16(af[m], bfr[n], acc[m + 4][n]);
    __builtin_amdgcn_s_setprio(0);
    __builtin_amdgcn_sched_barrier(0);
    __builtin_amdgcn_s_barrier();            // close tile kt; buf free

    if (++buf >= 3) buf = 0;
  }

  #pragma unroll
  for (int n = 0; n < 4; ++n) {
    const int col = bn * 256 + wn * 64 + n * 16 + l15;
    const float bv = bias[col];
    #pragma unroll
    for (int m = 0; m < 8; ++m) {
      const int row = bm * 256 + wm * 128 + m * 16 + l4 * 4;
      #pragma unroll
      for (int r = 0; r < 4; ++r)
        C[(size_t)(row + r) * ldc + col] = acc[m][n][r] + bv;
    }
  }
}

// ---------------- flash attention (LDS XOR-swizzled) ----------------
// grid: (S/128, B*H), block 256 (4 waves; wave w owns q-rows w*32..w*32+31)
__global__ __launch_bounds__(256) void attn_kernel(
    const bf16* __restrict__ qkv, const bf16* __restrict__ vT,
    const int* __restrict__ tokens, bf16* __restrict__ ctx)
{
  __shared__ bf16 Ks[128 * 64];
  __shared__ bf16 VTs[64 * 128];
  __shared__ bf16 Ps[128 * 128];

  const int qt = blockIdx.x;
  const int bh = blockIdx.y;
  const int b = bh >> 4, h = bh & 15;
  const int t = threadIdx.x, w = t >> 6, l = t & 63;
  const int l15 = l & 15, l4 = l >> 4;
  const int q0 = qt * 128;

  bf16x8 aq[2][2];
  #pragma unroll
  for (int m = 0; m < 2; ++m)
    #pragma unroll
    for (int ks = 0; ks < 2; ++ks)
      aq[m][ks] = *(const bf16x8*)(qkv +
          (size_t)(b * 1024 + q0 + w * 32 + m * 16 + l15) * 3072 +
          h * 64 + ks * 32 + l4 * 8);

  f32x4 o[2][4];
  float m_run[2][4], l_run[2][4];
  #pragma unroll
  for (int m = 0; m < 2; ++m)
    #pragma unroll
    for (int r = 0; r < 4; ++r) { m_run[m][r] = -1e30f; l_run[m][r] = 0.f; }
  #pragma unroll
  for (int m = 0; m < 2; ++m)
    #pragma unroll
    for (int nn = 0; nn < 4; ++nn)
      o[m][nn] = (f32x4){0.f, 0.f, 0.f, 0.f};

  const bf16* kb = qkv + (size_t)(b * 1024) * 3072 + 1024 + h * 64;
  const bf16* vb = vT + (size_t)(bh * 64) * 1024;
  const int* tb = tokens + b * 1024;

  const int kSrcCol = ((t & 7) ^ ((t >> 3) & 7)) * 8;
  const int vSrcCol = ((t & 15) ^ (t >> 4)) * 8;

  for (int jt = 0; jt <= qt; ++jt) {
    const int j0 = jt * 128;
    __syncthreads();
    #pragma unroll
    for (int i = 0; i < 4; ++i)
      gload16(kb + (size_t)(j0 + i * 32 + (t >> 3)) * 3072 + kSrcCol,
              Ks + i * 2048 + w * 512);
    #pragma unroll
    for (int i = 0; i < 4; ++i)
      gload16(vb + (size_t)(i * 16 + (t >> 4)) * 1024 + j0 + vSrcCol,
              VTs + i * 2048 + w * 512);
    __syncthreads();

    f32x4 s[2][8];
    #pragma unroll
    for (int m = 0; m < 2; ++m)
      #pragma unroll
      for (int n = 0; n < 8; ++n)
        s[m][n] = (f32x4){0.f, 0.f, 0.f, 0.f};
    #pragma unroll
    for (int ks = 0; ks < 2; ++ks) {
      #pragma unroll
      for (int n = 0; n < 8; ++n) {
        const bf16x8 bk = *(const bf16x8*)
            &Ks[(n * 16 + l15) * 64 + ((ks * 32 + l4 * 8) ^ ((l15 & 7) * 8))];
        #pragma unroll
        for (int m = 0; m < 2; ++m)
          s[m][n] = mfma16(aq[m][ks], bk, s[m][n]);
      }
    }

    float padv[8];
    #pragma unroll
    for (int n = 0; n < 8; ++n)
      padv[n] = (tb[j0 + n * 16 + l15] == 0) ? 1.f : 0.f;

    #pragma unroll
    for (int m = 0; m < 2; ++m) {
      #pragma unroll
      for (int r = 0; r < 4; ++r) {
        const int rloc = l4 * 4 + r;
        const int qrow = q0 + w * 32 + m * 16 + rloc;
        float vals[8];
        float mx = -1e30f;
        #pragma unroll
        for (int n = 0; n < 8; ++n) {
          const int jg = j0 + n * 16 + l15;
          float v = s[m][n][r] * 0.125f;
          if (jg > qrow || padv[n] != 0.f) v = -1e9f;
          vals[n] = v;
          mx = fmaxf(mx, v);
        }
        #pragma unroll
        for (int d = 1; d < 16; d <<= 1) mx = fmaxf(mx, __shfl_xor(mx, d));
        const float newm = fmaxf(m_run[m][r], mx);
        const float sc = __expf(m_run[m][r] - newm);
        m_run[m][r] = newm;
        float rs = 0.f;
        #pragma unroll
        for (int n = 0; n < 8; ++n) {
          const float pv = __expf(vals[n] - newm);
          vals[n] = pv;
          rs += pv;
        }
        #pragma unroll
        for (int d = 1; d < 16; d <<= 1) rs += __shfl_xor(rs, d);
        l_run[m][r] = l_run[m][r] * sc + rs;
        #pragma unroll
        for (int nn = 0; nn < 4; ++nn) o[m][nn][r] = o[m][nn][r] * sc;
        #pragma unroll
        for (int n = 0; n < 8; ++n)
          Ps[(w * 32 + m * 16 + rloc) * 128 +
             ((n * 16 + l15) ^ (rloc * 8))] = f2b(vals[n]);
      }
    }
    __syncthreads();

    #pragma unroll
    for (int ks = 0; ks < 4; ++ks) {
      bf16x8 ap[2];
      #pragma unroll
      for (int m = 0; m < 2; ++m)
        ap[m] = *(const bf16x8*)
            &Ps[(w * 32 + m * 16 + l15) * 128 + ((ks * 32 + l4 * 8) ^ (l15 * 8))];
      #pragma unroll
      for (int nn = 0; nn < 4; ++nn) {
        const bf16x8 bv = *(const bf16x8*)
            &VTs[(nn * 16 + l15) * 128 + ((ks * 32 + l4 * 8) ^ (l15 * 8))];
        #pragma unroll
        for (int m = 0; m < 2; ++m)
          o[m][nn] = mfma16(ap[m], bv, o[m][nn]);
      }
    }
  }

  #pragma unroll
  for (int m = 0; m < 2; ++m) {
    #pragma unroll
    for (int r = 0; r < 4; ++r) {
      const float inv = 1.0f / l_run[m][r];
      const int qrow = q0 + w * 32 + m * 16 + l4 * 4 + r;
      #pragma unroll
      for (int nn = 0; nn < 4; ++nn)
        ctx[(size_t)(b * 1024 + qrow) * 1024 + h * 64 + nn * 16 + l15] =
            f2b(o[m][nn][r] * inv);
    }
  }
}

// ------------- fixup for all-masked rows (leading pad tokens) -------------
__global__ __launch_bounds__(64) void attn_fixup_kernel(
    const int* __restrict__ tokens, const bf16* __restrict__ vT,
    bf16* __restrict__ ctx)
{
  const int bh = blockIdx.x;
  const int b = bh >> 4, h = bh & 15;
  __shared__ int p0s;
  if (threadIdx.x == 0) {
    int p = 0;
    const int* tb = tokens + b * 1024;
    while (p < 1024 && tb[p] == 0) ++p;
    p0s = p;
  }
  __syncthreads();
  const int P0 = p0s;
  if (P0 == 0) return;
  const int dk = threadIdx.x;
  const bf16* vrow = vT + (size_t)(bh * 64 + dk) * 1024;
  float sum = 0.f;
  for (int sIdx = 0; sIdx < 1024; ++sIdx) sum += b2f(vrow[sIdx]);
  const bf16 mv = f2b(sum * (1.0f / 1024.0f));
  for (int q = 0; q < P0; ++q)
    ctx[(size_t)(b * 1024 + q) * 1024 + h * 64 + dk] = mv;
}

// ---------------- host ----------------
extern "C" void kernel_launch(void* const* d_in, const int* in_sizes, int n_in,
                              void* d_out, int out_size, void* d_ws, size_t ws_size,
                              hipStream_t stream)
{
  (void)in_sizes; (void)n_in; (void)out_size;
  const int*   tokens = (const int*)d_in[0];
  const float* emb  = (const float*)d_in[1];
  const float* pe   = (const float*)d_in[2];
  const float* Wq   = (const float*)d_in[3];
  const float* Wk   = (const float*)d_in[4];
  const float* Wv   = (const float*)d_in[5];
  const float* Wo   = (const float*)d_in[6];
  const float* bo   = (const float*)d_in[7];
  const float* g1   = (const float*)d_in[8];
  const float* be1  = (const float*)d_in[9];
  const float* g2   = (const float*)d_in[10];
  const float* be2  = (const float*)d_in[11];
  const float* W1   = (const float*)d_in[12];
  const float* b1   = (const float*)d_in[13];
  const float* W2   = (const float*)d_in[14];
  const float* b2   = (const float*)d_in[15];
  const float* gf   = (const float*)d_in[16];
  const float* bff  = (const float*)d_in[17];
  const float* Wout = (const float*)d_in[18];
  const float* bout = (const float*)d_in[19];
  float* out = (float*)d_out;

  char* p = (char*)d_ws;
  auto alloc = [&](size_t bytes) {
    char* q = p;
    p += (bytes + 255) & ~(size_t)255;
    return q;
  };
  float* x    = (float*)alloc((size_t)2048 * 1024 * 4);
  float* Pp   = (float*)alloc((size_t)4 * 2048 * 1024 * 4);  // K-slice partials
  bf16* h     = (bf16*)alloc((size_t)2048 * 1024 * 2);
  bf16* qkv   = (bf16*)alloc((size_t)2048 * 3072 * 2);
  bf16* vT    = (bf16*)alloc((size_t)2048 * 1024 * 2);
  bf16* ctx   = (bf16*)alloc((size_t)2048 * 1024 * 2);
  bf16* ff    = (bf16*)alloc((size_t)2048 * 4096 * 2);
  bf16* WoutT = (bf16*)alloc((size_t)32000 * 1024 * 2);

  const size_t DD = (size_t)1024 * 1024;
  const size_t DF = (size_t)1024 * 4096;

  const size_t perLayerW = (3 * DD + DD + DF + DF) * 2;
  const size_t used = (size_t)(p - (char*)d_ws);
  const bool fullprep = ws_size >= used + 6 * perLayerW + 8192;
  const int NL = fullprep ? 6 : 1;
  bf16* WqkvT = (bf16*)alloc((size_t)NL * 3 * DD * 2);
  bf16* WoT   = (bf16*)alloc((size_t)NL * DD * 2);
  bf16* W1T   = (bf16*)alloc((size_t)NL * DF * 2);
  bf16* W2T   = (bf16*)alloc((size_t)NL * DF * 2);

  if (fullprep)
    prep_all_kernel<<<6 * 3072, 256, 0, stream>>>(
        Wq, Wk, Wv, Wo, W1, W2, WqkvT, WoT, W1T, W2T);

  embed_kernel<<<2048, 256, 0, stream>>>(tokens, emb, pe, x);

  for (int l = 0; l < 6; ++l) {
    const bf16* wqkvt; const bf16* wot; const bf16* w1t; const bf16* w2t;
    if (fullprep) {
      wqkvt = WqkvT + (size_t)l * 3 * DD;
      wot   = WoT   + (size_t)l * DD;
      w1t   = W1T   + (size_t)l * DF;
      w2t   = W2T   + (size_t)l * DF;
    } else {
      prep_layer_kernel<<<3072, 256, 0, stream>>>(
          Wq + l * DD, Wk + l * DD, Wv + l * DD, Wo + l * DD,
          W1 + l * DF, W2 + l * DF, WqkvT, WoT, W1T, W2T);
      wqkvt = WqkvT; wot = WoT; w1t = W1T; w2t = W2T;
    }

    // ln1: layer 0 plain; later layers fold the previous FFN2 partials
    if (l == 0)
      ln_kernel<<<2048, 256, 0, stream>>>(x, g1, be1, h);
    else
      ln_res_kernel<<<2048, 256, 0, stream>>>(
          x, Pp, 4, b2 + (l - 1) * 1024, g1 + l * 1024, be1 + l * 1024, h);

    // QKV: M=2048 N=3072 K=1024, BM=64 -> 768 blocks
    gemm_pl<0, 64, 0><<<dim3(32, 24, 1), 256, 0, stream>>>(
        h, 1024, wqkvt, 1024, qkv, 3072, (const float*)nullptr, 1024);
    transpose_v_kernel<<<dim3(16, 32), 256, 0, stream>>>(qkv, vT);
    attn_kernel<<<dim3(8, 32), 256, 0, stream>>>(qkv, vT, tokens, ctx);
    attn_fixup_kernel<<<32, 64, 0, stream>>>(tokens, vT, ctx);
    // Wo: M=2048 N=1024 K=1024, BM=64 + splitK2 -> 512 blocks, partials
    gemm_pl<3, 64, 0><<<dim3(32, 8, 2), 256, 0, stream>>>(
        ctx, 1024, wot, 1024, Pp, 1024, (const float*)nullptr, 512);
    // ln2: x += Pw0+Pw1 + bo; h = LN(x)
    ln_res_kernel<<<2048, 256, 0, stream>>>(
        x, Pp, 2, bo + l * 1024, g2 + l * 1024, be2 + l * 1024, h);
    // FFN1: M=2048 N=4096 K=1024, BM=128 -> 512 blocks
    gemm_pl<2, 128, 0><<<dim3(16, 32, 1), 256, 0, stream>>>(
        h, 1024, w1t, 1024, ff, 4096, b1 + l * 4096, 1024);
    // FFN2: M=2048 N=1024 K=4096, BM=128 + splitK4 -> 512 blocks, partials
    gemm_pl<3, 128, 0><<<dim3(16, 8, 4), 256, 0, stream>>>(
        ff, 4096, w2t, 4096, Pp, 1024, (const float*)nullptr, 1024);
  }

  // final LN folds layer-5 FFN2 partials
  ln_res_kernel<<<2048, 256, 0, stream>>>(x, Pp, 4, b2 + 5 * 1024, gf, bff, h);
  transpose_cast_kernel<<<dim3(500, 16), 256, 0, stream>>>(Wout, WoutT, 32000, 1024);
  // logits: M=2048 N=32000 K=1024 -> 256x256 phase-interleaved, 1000 blocks
  gemm256<<<dim3(8, 125), 512, 0, stream>>>(
      h, 1024, WoutT, 1024, out, 32000, bout, 1024);
}

// Round 9
// 1347.475 us; speedup vs baseline: 1.2227x; 1.0946x over previous
//
#include <hip/hip_runtime.h>
#include <hip/hip_bf16.h>
#include <stdint.h>

typedef __hip_bfloat16 bf16;
typedef __attribute__((ext_vector_type(8))) short bf16x8;
typedef __attribute__((ext_vector_type(4))) float f32x4;

#define DEV static __device__ __forceinline__

DEV float b2f(bf16 v) { return __bfloat162float(v); }
DEV bf16  f2b(float v) { return __float2bfloat16(v); }

DEV float u2f(unsigned short u) {
  unsigned int x = (unsigned int)u << 16;
  float f;
  __builtin_memcpy(&f, &x, 4);
  return f;
}

DEV void gload16(const void* g, void* l) {
  __builtin_amdgcn_global_load_lds(
      (__attribute__((address_space(1))) void*)(void*)g,
      (__attribute__((address_space(3))) void*)l, 16, 0, 0);
}

DEV f32x4 mfma16(bf16x8 a, bf16x8 b, f32x4 c) {
  return __builtin_amdgcn_mfma_f32_16x16x32_bf16(a, b, c, 0, 0, 0);
}

// ---------------- embed: x = emb[tok]*32 + pe (all f32) ----------------
__global__ __launch_bounds__(256) void embed_kernel(
    const int* __restrict__ tok, const float* __restrict__ emb,
    const float* __restrict__ pe, float* __restrict__ x)
{
  const int r = blockIdx.x, t = threadIdx.x;
  const int s = r & 1023;
  const int tk = tok[r];
  const int d = t * 4;
  const float* ep = emb + (size_t)tk * 1024 + d;
  const float* pp = pe + (size_t)s * 1024 + d;
  float* xp = x + (size_t)r * 1024 + d;
  #pragma unroll
  for (int j = 0; j < 4; ++j)
    xp[j] = ep[j] * 32.0f + pp[j];
}

// ---------------- layernorm: h = LN(x)*g + b (f32 in, bf16 out) ----------------
__global__ __launch_bounds__(256) void ln_kernel(
    const float* __restrict__ x, const float* __restrict__ g,
    const float* __restrict__ be, bf16* __restrict__ h)
{
  const int r = blockIdx.x, t = threadIdx.x;
  const float4 v = ((const float4*)(x + (size_t)r * 1024))[t];
  float s  = v.x + v.y + v.z + v.w;
  float sq = v.x * v.x + v.y * v.y + v.z * v.z + v.w * v.w;
  #pragma unroll
  for (int d = 1; d < 64; d <<= 1) {
    s  += __shfl_xor(s, d);
    sq += __shfl_xor(sq, d);
  }
  __shared__ float red[8];
  const int w = t >> 6, l = t & 63;
  if (l == 0) { red[w] = s; red[4 + w] = sq; }
  __syncthreads();
  s  = red[0] + red[1] + red[2] + red[3];
  sq = red[4] + red[5] + red[6] + red[7];
  const float mean = s * (1.0f / 1024.0f);
  const float var  = sq * (1.0f / 1024.0f) - mean * mean;
  const float inv  = 1.0f / sqrtf(var + 1e-5f);
  bf16* hp = h + (size_t)r * 1024 + t * 4;
  const float* gp = g + t * 4;
  const float* bp = be + t * 4;
  const float vv[4] = {v.x, v.y, v.z, v.w};
  #pragma unroll
  for (int j = 0; j < 4; ++j)
    hp[j] = f2b((vv[j] - mean) * inv * gp[j] + bp[j]);
}

// -- fused residual + layernorm: x += sum(bf16 P[0..np)) + bias; h = LN(x)*g+be
__global__ __launch_bounds__(256) void ln_res_kernel(
    float* __restrict__ x, const bf16* __restrict__ P, int np,
    const float* __restrict__ bias, const float* __restrict__ g,
    const float* __restrict__ be, bf16* __restrict__ h)
{
  const int r = blockIdx.x, t = threadIdx.x;
  float4 v = ((const float4*)(x + (size_t)r * 1024))[t];
  for (int i = 0; i < np; ++i) {
    const ushort4 pv = ((const ushort4*)(P + ((size_t)i * 2048 + r) * 1024))[t];
    v.x += u2f(pv.x); v.y += u2f(pv.y); v.z += u2f(pv.z); v.w += u2f(pv.w);
  }
  const float4 bv = ((const float4*)bias)[t];
  v.x += bv.x; v.y += bv.y; v.z += bv.z; v.w += bv.w;

  float s  = v.x + v.y + v.z + v.w;
  float sq = v.x * v.x + v.y * v.y + v.z * v.z + v.w * v.w;
  #pragma unroll
  for (int d = 1; d < 64; d <<= 1) {
    s  += __shfl_xor(s, d);
    sq += __shfl_xor(sq, d);
  }
  __shared__ float red[8];
  const int w = t >> 6, l = t & 63;
  if (l == 0) { red[w] = s; red[4 + w] = sq; }
  __syncthreads();
  s  = red[0] + red[1] + red[2] + red[3];
  sq = red[4] + red[5] + red[6] + red[7];
  const float mean = s * (1.0f / 1024.0f);
  const float var  = sq * (1.0f / 1024.0f) - mean * mean;
  const float inv  = 1.0f / sqrtf(var + 1e-5f);

  ((float4*)(x + (size_t)r * 1024))[t] = v;
  bf16* hp = h + (size_t)r * 1024 + t * 4;
  const float* gp = g + t * 4;
  const float* bp = be + t * 4;
  const float vv[4] = {v.x, v.y, v.z, v.w};
  #pragma unroll
  for (int j = 0; j < 4; ++j)
    hp[j] = f2b((vv[j] - mean) * inv * gp[j] + bp[j]);
}

// ------------- 64x64 transpose+cast tile body -------------
DEV void transpose_tile(const float* __restrict__ in, bf16* __restrict__ out,
                        int ldin, int ldout, int r0, int c0, int t)
{
  __shared__ bf16 tile[64][64];
  #pragma unroll
  for (int i = 0; i < 4; ++i) {
    const int r = i * 16 + (t >> 4), c = (t & 15) * 4;
    const float4 v = *(const float4*)&in[(size_t)(r0 + r) * ldin + c0 + c];
    tile[r][c + 0] = f2b(v.x);
    tile[r][c + 1] = f2b(v.y);
    tile[r][c + 2] = f2b(v.z);
    tile[r][c + 3] = f2b(v.w);
  }
  __syncthreads();
  #pragma unroll
  for (int i = 0; i < 2; ++i) {
    const int oc = i * 32 + (t >> 3);
    const int rr = (t & 7) * 8;
    unsigned short tmp[8] __attribute__((aligned(16)));
    #pragma unroll
    for (int j = 0; j < 8; ++j)
      tmp[j] = ((const unsigned short*)tile)[(rr + j) * 64 + oc];
    *(uint4*)&out[(size_t)(c0 + oc) * ldout + r0 + rr] = *(const uint4*)tmp;
  }
}

// generic single-matrix transpose+cast (used for Wout)
__global__ __launch_bounds__(256) void transpose_cast_kernel(
    const float* __restrict__ in, bf16* __restrict__ out, int ldin, int ldout)
{
  transpose_tile(in, out, ldin, ldout, blockIdx.y * 64, blockIdx.x * 64, threadIdx.x);
}

// dispatch one 64x64 tile of the per-layer weight set (3072 tiles/layer)
DEV void prep_dispatch(int wid,
    const float* Wq, const float* Wk, const float* Wv, const float* Wo,
    const float* W1, const float* W2,
    bf16* WqkvT, bf16* WoT, bf16* W1T, bf16* W2T, int t)
{
  const float* src; bf16* dst; int ldin, ldout, tx, ty;
  if (wid < 768) {
    const int m = wid >> 8, tt = wid & 255;
    src = (m == 0) ? Wq : (m == 1) ? Wk : Wv;
    dst = WqkvT + (size_t)m * 1024 * 1024;
    ldin = 1024; ldout = 1024; tx = tt & 15; ty = tt >> 4;
  } else if (wid < 1024) {
    const int tt = wid - 768;
    src = Wo; dst = WoT; ldin = 1024; ldout = 1024; tx = tt & 15; ty = tt >> 4;
  } else if (wid < 2048) {
    const int tt = wid - 1024;
    src = W1; dst = W1T; ldin = 4096; ldout = 1024; tx = tt & 63; ty = tt >> 6;
  } else {
    const int tt = wid - 2048;
    src = W2; dst = W2T; ldin = 1024; ldout = 4096; tx = tt & 15; ty = tt >> 4;
  }
  transpose_tile(src, dst, ldin, ldout, ty * 64, tx * 64, t);
}

// per-layer weight prep (fallback path)
__global__ __launch_bounds__(256) void prep_layer_kernel(
    const float* __restrict__ Wq, const float* __restrict__ Wk,
    const float* __restrict__ Wv, const float* __restrict__ Wo,
    const float* __restrict__ W1, const float* __restrict__ W2,
    bf16* __restrict__ WqkvT, bf16* __restrict__ WoT,
    bf16* __restrict__ W1T, bf16* __restrict__ W2T)
{
  prep_dispatch(blockIdx.x, Wq, Wk, Wv, Wo, W1, W2,
                WqkvT, WoT, W1T, W2T, threadIdx.x);
}

// all-layers weight prep (when ws permits): 6*3072 blocks
__global__ __launch_bounds__(256) void prep_all_kernel(
    const float* __restrict__ Wq, const float* __restrict__ Wk,
    const float* __restrict__ Wv, const float* __restrict__ Wo,
    const float* __restrict__ W1, const float* __restrict__ W2,
    bf16* __restrict__ WqkvT, bf16* __restrict__ WoT,
    bf16* __restrict__ W1T, bf16* __restrict__ W2T)
{
  const int layer = blockIdx.x / 3072;
  const int wid = blockIdx.x - layer * 3072;
  const size_t DD = (size_t)1024 * 1024, DF = (size_t)1024 * 4096;
  prep_dispatch(wid,
      Wq + layer * DD, Wk + layer * DD, Wv + layer * DD, Wo + layer * DD,
      W1 + layer * DF, W2 + layer * DF,
      WqkvT + layer * 3 * DD, WoT + layer * DD,
      W1T + layer * DF, W2T + layer * DF, threadIdx.x);
}

// ---- v transpose (bf16->bf16): vT[bh][dk][s] = qkv[b*S+s][2048+h*64+dk] ----
// grid: (S/64, B*H), block 256
__global__ __launch_bounds__(256) void transpose_v_kernel(
    const bf16* __restrict__ qkv, bf16* __restrict__ vT)
{
  __shared__ bf16 tile[64][64];
  const int t = threadIdx.x;
  const int s0 = blockIdx.x * 64;
  const int bh = blockIdx.y;
  const int b = bh >> 4, h = bh & 15;
  const bf16* in = qkv + (size_t)(b * 1024) * 3072 + 2048 + h * 64;
  #pragma unroll
  for (int i = 0; i < 2; ++i) {
    const int r = i * 32 + (t >> 3), c = (t & 7) * 8;
    *(uint4*)&tile[r][c] = *(const uint4*)&in[(size_t)(s0 + r) * 3072 + c];
  }
  __syncthreads();
  bf16* out = vT + (size_t)(bh * 64) * 1024;
  #pragma unroll
  for (int i = 0; i < 2; ++i) {
    const int oc = i * 32 + (t >> 3);   // dk
    const int rr = (t & 7) * 8;         // s offset
    unsigned short tmp[8] __attribute__((aligned(16)));
    #pragma unroll
    for (int j = 0; j < 8; ++j)
      tmp[j] = ((const unsigned short*)tile)[(rr + j) * 64 + oc];
    *(uint4*)&out[(size_t)oc * 1024 + s0 + rr] = *(const uint4*)tmp;
  }
}

// ------------- pipelined GEMM: C(MxN) = A(MxK,row) * BT(NxK,row)^T -------------
// 3-buffer LDS, 2-tiles-ahead prefetch, counted vmcnt (T4), raw barriers,
// T2 bank-conflict XOR swizzle (pre-swizzled global source + swizzled ds_read).
// EPI: 0 = bf16 store; 1 = +bias f32 store; 2 = gelu(acc+bias) bf16;
//      3 = bf16 K-slice partial store P[z][M][N] (no bias; reduced in ln_res)
// grid: (M/BM, N/128, KSLICES), block 256 (4 waves), K-slice length ksl
template<int EPI, int BM, int SWZ>
__global__ __launch_bounds__(256) void gemm_pl(
    const bf16* __restrict__ A, int lda,
    const bf16* __restrict__ BT, int ldb,
    void* __restrict__ Cp, int ldc,
    const float* __restrict__ bias,
    int ksl)
{
  constexpr int ABUF = BM * 32;               // elems per A buffer
  constexpr int MR = BM / 32;                 // m-fragment repeats per wave
  __shared__ bf16 As[3 * ABUF];
  __shared__ bf16 Bs[3 * 4096];
  const int t = threadIdx.x;

  int bm, bn;
  if constexpr (SWZ) {                        // XCD-chunked swizzle (nwg%8==0)
    const int nbm = gridDim.x;
    const int nwg = nbm * gridDim.y;
    int wid = blockIdx.x + nbm * blockIdx.y;
    wid = (wid & 7) * (nwg >> 3) + (wid >> 3);
    bm = wid % nbm; bn = wid / nbm;
  } else {
    bm = blockIdx.x; bn = blockIdx.y;
  }

  const int w = t >> 6, l = t & 63;
  const int wr = (w >> 1) * (BM / 2), wc = (w & 1) * 64;
  const int l15 = l & 15, l4 = l >> 4;
  const int kbeg = blockIdx.z * ksl;
  const int ntiles = ksl >> 5;

  // T2: pre-swizzled global column-block; key = (lds_row>>1)&3 = (t>>3)&3
  const int colblk = (((t & 3) ^ ((t >> 3) & 3))) * 8;
  const bf16* gA = A  + (size_t)(bm * BM  + (t >> 2)) * lda + colblk + kbeg;
  const bf16* gB = BT + (size_t)(bn * 128 + (t >> 2)) * ldb + colblk + kbeg;
  bf16* lA = As + w * 512;
  bf16* lB = Bs + w * 512;

  auto stage = [&](int tile, int buf) {
    const int k0 = tile * 32;
    gload16(gA + k0, lA + buf * ABUF);
    if constexpr (BM == 128)
      gload16(gA + (size_t)64 * lda + k0, lA + buf * ABUF + 2048);
    gload16(gB + k0, lB + buf * 4096);
    gload16(gB + (size_t)64 * ldb + k0, lB + buf * 4096 + 2048);
  };

  f32x4 acc[MR][4];
  #pragma unroll
  for (int m = 0; m < MR; ++m)
    #pragma unroll
    for (int n = 0; n < 4; ++n)
      acc[m][n] = (f32x4){0.f, 0.f, 0.f, 0.f};

  stage(0, 0);
  stage(1, 1);

  // T2 read-side swizzle: column-block = l4 ^ ((row>>1)&3); row%16 == l15
  const int rdcol = ((l4 ^ ((l15 >> 1) & 3))) * 8;

  int buf = 0;
  for (int kt = 0; kt < ntiles; ++kt) {
    if (kt + 2 < ntiles) {
      int pb = buf + 2; if (pb >= 3) pb -= 3;
      stage(kt + 2, pb);
      __builtin_amdgcn_sched_barrier(0);
      if constexpr (BM == 128) asm volatile("s_waitcnt vmcnt(8)" ::: "memory");
      else                     asm volatile("s_waitcnt vmcnt(6)" ::: "memory");
    } else if (kt + 1 < ntiles) {
      if constexpr (BM == 128) asm volatile("s_waitcnt vmcnt(4)" ::: "memory");
      else                     asm volatile("s_waitcnt vmcnt(3)" ::: "memory");
    } else {
      asm volatile("s_waitcnt vmcnt(0)" ::: "memory");
    }
    __builtin_amdgcn_s_barrier();          // all waves: tile kt resident
    __builtin_amdgcn_sched_barrier(0);     // no ds_read hoists above barrier

    const bf16* Ab = As + buf * ABUF;
    const bf16* Bb = Bs + buf * 4096;
    bf16x8 af[MR], bfr[4];
    #pragma unroll
    for (int m = 0; m < MR; ++m)
      af[m] = *(const bf16x8*)&Ab[(wr + m * 16 + l15) * 32 + rdcol];
    #pragma unroll
    for (int n = 0; n < 4; ++n)
      bfr[n] = *(const bf16x8*)&Bb[(wc + n * 16 + l15) * 32 + rdcol];
    #pragma unroll
    for (int m = 0; m < MR; ++m)
      #pragma unroll
      for (int n = 0; n < 4; ++n)
        acc[m][n] = mfma16(af[m], bfr[n], acc[m][n]);

    __builtin_amdgcn_sched_barrier(0);     // reads stay before barrier
    __builtin_amdgcn_s_barrier();          // buf kt now dead for overwrite
    if (++buf >= 3) buf = 0;
  }

  const int crow = bm * BM + wr, ccol = bn * 128 + wc;
  #pragma unroll
  for (int n = 0; n < 4; ++n) {
    const int col = ccol + n * 16 + l15;
    float bv = 0.f;
    if (EPI == 1 || EPI == 2) bv = bias[col];
    #pragma unroll
    for (int m = 0; m < MR; ++m) {
      const int row = crow + m * 16 + l4 * 4;
      #pragma unroll
      for (int r = 0; r < 4; ++r) {
        const float v = acc[m][n][r];
        if (EPI == 0) {
          ((bf16*)Cp)[(size_t)(row + r) * ldc + col] = f2b(v);
        } else if (EPI == 1) {
          ((float*)Cp)[(size_t)(row + r) * ldc + col] = v + bv;
        } else if (EPI == 2) {
          const float u = v + bv;
          const float gel = 0.5f * u * (1.0f + erff(u * 0.70710678118654752f));
          ((bf16*)Cp)[(size_t)(row + r) * ldc + col] = f2b(gel);
        } else {
          const int M = gridDim.x * BM;
          ((bf16*)Cp)[((size_t)blockIdx.z * M + row + r) * ldc + col] = f2b(v);
        }
      }
    }
  }
}

// ------------- 256x256 8-wave phase-interleaved GEMM (logits) -------------
// BK=32, 3-buffer LDS ring (96 KB), counted vmcnt(4), per K-tile 2 phases
// (m201/T3+T4+T5 schedule). Verified conflict-free swizzle, key=(row>>1)&3.
// grid: (M/256, N/256), nwg % 8 == 0 (XCD swizzle). 512 threads (2M x 4N waves).
__global__ __launch_bounds__(512, 2) void gemm256(
    const bf16* __restrict__ A, int lda,
    const bf16* __restrict__ BT, int ldb,
    float* __restrict__ C, int ldc,
    const float* __restrict__ bias, int K)
{
  __shared__ bf16 As[3][8192];
  __shared__ bf16 Bs[3][8192];
  const int t = threadIdx.x;

  const int nbm = gridDim.x;
  const int nwg = nbm * gridDim.y;
  int wid = blockIdx.x + nbm * blockIdx.y;
  wid = (wid & 7) * (nwg >> 3) + (wid >> 3);
  const int bm = wid % nbm, bn = wid / nbm;

  const int w = t >> 6, l = t & 63;
  const int wm = w >> 2, wn = w & 3;
  const int l15 = l & 15, l4 = l >> 4;

  const int colblk = ((t & 3) ^ ((t >> 3) & 3)) * 8;
  const bf16* gA = A  + (size_t)(bm * 256 + (t >> 2)) * lda + colblk;
  const bf16* gB = BT + (size_t)(bn * 256 + (t >> 2)) * ldb + colblk;
  const int dst = w * 512;

  const int rd = (l4 ^ ((l15 >> 1) & 3)) * 8;
  const int arow = wm * 128 + l15;
  const int brow = wn * 64 + l15;

  f32x4 acc[8][4];
  #pragma unroll
  for (int m = 0; m < 8; ++m)
    #pragma unroll
    for (int n = 0; n < 4; ++n)
      acc[m][n] = (f32x4){0.f, 0.f, 0.f, 0.f};

  const int NT = K >> 5;

  auto stageA = [&](int kt, int buf) {
    const int k0 = kt * 32;
    gload16(gA + k0, &As[buf][dst]);
    gload16(gA + (size_t)128 * lda + k0, &As[buf][4096 + dst]);
  };
  auto stageB = [&](int kt, int buf) {
    const int k0 = kt * 32;
    gload16(gB + k0, &Bs[buf][dst]);
    gload16(gB + (size_t)128 * ldb + k0, &Bs[buf][4096 + dst]);
  };

  stageA(0, 0); stageB(0, 0);
  stageA(1, 1); stageB(1, 1);

  int buf = 0;
  for (int kt = 0; kt < NT; ++kt) {
    if (kt + 1 < NT) asm volatile("s_waitcnt vmcnt(4)" ::: "memory");
    else             asm volatile("s_waitcnt vmcnt(0)" ::: "memory");
    __builtin_amdgcn_s_barrier();
    __builtin_amdgcn_sched_barrier(0);

    int pb = buf + 2; if (pb >= 3) pb -= 3;
    const bf16* Ab = As[buf];
    const bf16* Bb = Bs[buf];

    // ---- phase 0: B frags + A frags m0..3; prefetch A-half of kt+2
    bf16x8 bfr[4], af[4];
    #pragma unroll
    for (int n = 0; n < 4; ++n)
      bfr[n] = *(const bf16x8*)&Bb[(brow + n * 16) * 32 + rd];
    #pragma unroll
    for (int m = 0; m < 4; ++m)
      af[m] = *(const bf16x8*)&Ab[(arow + m * 16) * 32 + rd];
    if (kt + 2 < NT) stageA(kt + 2, pb);
    asm volatile("s_waitcnt lgkmcnt(0)" ::: "memory");
    __builtin_amdgcn_sched_barrier(0);
    __builtin_amdgcn_s_setprio(1);
    #pragma unroll
    for (int m = 0; m < 4; ++m)
      #pragma unroll
      for (int n = 0; n < 4; ++n)
        acc[m][n] = mfma16(af[m], bfr[n], acc[m][n]);
    __builtin_amdgcn_s_setprio(0);
    __builtin_amdgcn_sched_barrier(0);
    __builtin_amdgcn_s_barrier();

    // ---- phase 1: A frags m4..7; prefetch B-half of kt+2
    #pragma unroll
    for (int m = 0; m < 4; ++m)
      af[m] = *(const bf16x8*)&Ab[(arow + (m + 4) * 16) * 32 + rd];
    if (kt + 2 < NT) stageB(kt + 2, pb);
    asm volatile("s_waitcnt lgkmcnt(0)" ::: "memory");
    __builtin_amdgcn_sched_barrier(0);
    __builtin_amdgcn_s_setprio(1);
    #pragma unroll
    for (int m = 0; m < 4; ++m)
      #pragma unroll
      for (int n = 0; n < 4; ++n)
        acc[m + 4][n] = mfma16(af[m], bfr[n], acc[m + 4][n]);
    __builtin_amdgcn_s_setprio(0);
    __builtin_amdgcn_sched_barrier(0);
    __builtin_amdgcn_s_barrier();

    if (++buf >= 3) buf = 0;
  }

  #pragma unroll
  for (int n = 0; n < 4; ++n) {
    const int col = bn * 256 + wn * 64 + n * 16 + l15;
    const float bv = bias[col];
    #pragma unroll
    for (int m = 0; m < 8; ++m) {
      const int row = bm * 256 + wm * 128 + m * 16 + l4 * 4;
      #pragma unroll
      for (int r = 0; r < 4; ++r)
        C[(size_t)(row + r) * ldc + col] = acc[m][n][r] + bv;
    }
  }
}

// ---------------- flash attention (8 waves x 16 q-rows, LDS XOR-swizzled) ----
// grid: (S/128, B*H), block 512 (wave w owns q-rows w*16..w*16+15)
__global__ __launch_bounds__(512) void attn_kernel(
    const bf16* __restrict__ qkv, const bf16* __restrict__ vT,
    const int* __restrict__ tokens, bf16* __restrict__ ctx)
{
  __shared__ bf16 Ks[128 * 64];
  __shared__ bf16 VTs[64 * 128];
  __shared__ bf16 Ps[128 * 128];

  const int qt = blockIdx.x;
  const int bh = blockIdx.y;
  const int b = bh >> 4, h = bh & 15;
  const int t = threadIdx.x, w = t >> 6, l = t & 63;
  const int l15 = l & 15, l4 = l >> 4;
  const int q0 = qt * 128;

  bf16x8 aq[2];
  #pragma unroll
  for (int ks = 0; ks < 2; ++ks)
    aq[ks] = *(const bf16x8*)(qkv +
        (size_t)(b * 1024 + q0 + w * 16 + l15) * 3072 +
        h * 64 + ks * 32 + l4 * 8);

  f32x4 o[4];
  float m_run[4], l_run[4];
  #pragma unroll
  for (int r = 0; r < 4; ++r) { m_run[r] = -1e30f; l_run[r] = 0.f; }
  #pragma unroll
  for (int nn = 0; nn < 4; ++nn)
    o[nn] = (f32x4){0.f, 0.f, 0.f, 0.f};

  const bf16* kb = qkv + (size_t)(b * 1024) * 3072 + 1024 + h * 64;
  const bf16* vb = vT + (size_t)(bh * 64) * 1024;
  const int* tb = tokens + b * 1024;

  // staging swizzle (pre-swizzled global source, linear LDS dest)
  const int kSrcCol = ((t & 7) ^ ((t >> 3) & 7)) * 8;     // K key: row&7
  const int vSrcCol = ((t & 15) ^ ((t >> 4) & 15)) * 8;   // V key: row&15

  for (int jt = 0; jt <= qt; ++jt) {
    const int j0 = jt * 128;
    __syncthreads();  // previous iteration's LDS reads complete
    #pragma unroll
    for (int i = 0; i < 2; ++i)
      gload16(kb + (size_t)(j0 + i * 64 + (t >> 3)) * 3072 + kSrcCol,
              Ks + i * 4096 + w * 512);
    #pragma unroll
    for (int i = 0; i < 2; ++i)
      gload16(vb + (size_t)(i * 32 + (t >> 4)) * 1024 + j0 + vSrcCol,
              VTs + i * 4096 + w * 512);
    __syncthreads();  // staged tiles visible

    // S = Q K^T for this wave's 16 rows x 128 cols
    f32x4 s[8];
    #pragma unroll
    for (int n = 0; n < 8; ++n)
      s[n] = (f32x4){0.f, 0.f, 0.f, 0.f};
    #pragma unroll
    for (int ks = 0; ks < 2; ++ks) {
      #pragma unroll
      for (int n = 0; n < 8; ++n) {
        const bf16x8 bk = *(const bf16x8*)
            &Ks[(n * 16 + l15) * 64 + ((ks * 32 + l4 * 8) ^ ((l15 & 7) * 8))];
        s[n] = mfma16(aq[ks], bk, s[n]);
      }
    }

    float padv[8];
    #pragma unroll
    for (int n = 0; n < 8; ++n)
      padv[n] = (tb[j0 + n * 16 + l15] == 0) ? 1.f : 0.f;

    // online softmax per q-row; write P to LDS (swizzled, wave-local rows)
    #pragma unroll
    for (int r = 0; r < 4; ++r) {
      const int rloc = l4 * 4 + r;
      const int qrow = q0 + w * 16 + rloc;
      float vals[8];
      float mx = -1e30f;
      #pragma unroll
      for (int n = 0; n < 8; ++n) {
        const int jg = j0 + n * 16 + l15;
        float v = s[n][r] * 0.125f;
        if (jg > qrow || padv[n] != 0.f) v = -1e9f;
        vals[n] = v;
        mx = fmaxf(mx, v);
      }
      #pragma unroll
      for (int d = 1; d < 16; d <<= 1) mx = fmaxf(mx, __shfl_xor(mx, d));
      const float newm = fmaxf(m_run[r], mx);
      const float sc = __expf(m_run[r] - newm);
      m_run[r] = newm;
      float rs = 0.f;
      #pragma unroll
      for (int n = 0; n < 8; ++n) {
        const float pv = __expf(vals[n] - newm);
        vals[n] = pv;
        rs += pv;
      }
      #pragma unroll
      for (int d = 1; d < 16; d <<= 1) rs += __shfl_xor(rs, d);
      l_run[r] = l_run[r] * sc + rs;
      #pragma unroll
      for (int nn = 0; nn < 4; ++nn) o[nn][r] = o[nn][r] * sc;
      #pragma unroll
      for (int n = 0; n < 8; ++n)
        Ps[(w * 16 + rloc) * 128 + ((n * 16 + l15) ^ (rloc * 8))] = f2b(vals[n]);
    }
    // wave-local P rows: only need our own ds_writes complete (no block barrier)
    asm volatile("s_waitcnt lgkmcnt(0)" ::: "memory");

    // O += P V
    #pragma unroll
    for (int ks = 0; ks < 4; ++ks) {
      const bf16x8 ap = *(const bf16x8*)
          &Ps[(w * 16 + l15) * 128 + ((ks * 32 + l4 * 8) ^ (l15 * 8))];
      #pragma unroll
      for (int nn = 0; nn < 4; ++nn) {
        const bf16x8 bv = *(const bf16x8*)
            &VTs[(nn * 16 + l15) * 128 + ((ks * 32 + l4 * 8) ^ (l15 * 8))];
        o[nn] = mfma16(ap, bv, o[nn]);
      }
    }
  }

  // epilogue: ctx = O / l
  #pragma unroll
  for (int r = 0; r < 4; ++r) {
    const float inv = 1.0f / l_run[r];
    const int qrow = q0 + w * 16 + l4 * 4 + r;
    #pragma unroll
    for (int nn = 0; nn < 4; ++nn)
      ctx[(size_t)(b * 1024 + qrow) * 1024 + h * 64 + nn * 16 + l15] =
          f2b(o[nn][r] * inv);
  }
}

// ------------- fixup for all-masked rows (leading pad tokens) -------------
__global__ __launch_bounds__(64) void attn_fixup_kernel(
    const int* __restrict__ tokens, const bf16* __restrict__ vT,
    bf16* __restrict__ ctx)
{
  const int bh = blockIdx.x;
  const int b = bh >> 4, h = bh & 15;
  __shared__ int p0s;
  if (threadIdx.x == 0) {
    int p = 0;
    const int* tb = tokens + b * 1024;
    while (p < 1024 && tb[p] == 0) ++p;
    p0s = p;
  }
  __syncthreads();
  const int P0 = p0s;
  if (P0 == 0) return;
  const int dk = threadIdx.x;
  const bf16* vrow = vT + (size_t)(bh * 64 + dk) * 1024;
  float sum = 0.f;
  for (int sIdx = 0; sIdx < 1024; ++sIdx) sum += b2f(vrow[sIdx]);
  const bf16 mv = f2b(sum * (1.0f / 1024.0f));
  for (int q = 0; q < P0; ++q)
    ctx[(size_t)(b * 1024 + q) * 1024 + h * 64 + dk] = mv;
}

// ---------------- host ----------------
extern "C" void kernel_launch(void* const* d_in, const int* in_sizes, int n_in,
                              void* d_out, int out_size, void* d_ws, size_t ws_size,
                              hipStream_t stream)
{
  (void)in_sizes; (void)n_in; (void)out_size;
  const int*   tokens = (const int*)d_in[0];
  const float* emb  = (const float*)d_in[1];
  const float* pe   = (const float*)d_in[2];
  const float* Wq   = (const float*)d_in[3];
  const float* Wk   = (const float*)d_in[4];
  const float* Wv   = (const float*)d_in[5];
  const float* Wo   = (const float*)d_in[6];
  const float* bo   = (const float*)d_in[7];
  const float* g1   = (const float*)d_in[8];
  const float* be1  = (const float*)d_in[9];
  const float* g2   = (const float*)d_in[10];
  const float* be2  = (const float*)d_in[11];
  const float* W1   = (const float*)d_in[12];
  const float* b1   = (const float*)d_in[13];
  const float* W2   = (const float*)d_in[14];
  const float* b2   = (const float*)d_in[15];
  const float* gf   = (const float*)d_in[16];
  const float* bff  = (const float*)d_in[17];
  const float* Wout = (const float*)d_in[18];
  const float* bout = (const float*)d_in[19];
  float* out = (float*)d_out;

  char* p = (char*)d_ws;
  auto alloc = [&](size_t bytes) {
    char* q = p;
    p += (bytes + 255) & ~(size_t)255;
    return q;
  };
  float* x    = (float*)alloc((size_t)2048 * 1024 * 4);
  bf16* Pp    = (bf16*)alloc((size_t)4 * 2048 * 1024 * 2);  // bf16 K-slice partials
  bf16* h     = (bf16*)alloc((size_t)2048 * 1024 * 2);
  bf16* qkv   = (bf16*)alloc((size_t)2048 * 3072 * 2);
  bf16* vT    = (bf16*)alloc((size_t)2048 * 1024 * 2);
  bf16* ctx   = (bf16*)alloc((size_t)2048 * 1024 * 2);
  bf16* ff    = (bf16*)alloc((size_t)2048 * 4096 * 2);
  bf16* WoutT = (bf16*)alloc((size_t)32000 * 1024 * 2);

  const size_t DD = (size_t)1024 * 1024;
  const size_t DF = (size_t)1024 * 4096;

  const size_t perLayerW = (3 * DD + DD + DF + DF) * 2;
  const size_t used = (size_t)(p - (char*)d_ws);
  const bool fullprep = ws_size >= used + 6 * perLayerW + 8192;
  const int NL = fullprep ? 6 : 1;
  bf16* WqkvT = (bf16*)alloc((size_t)NL * 3 * DD * 2);
  bf16* WoT   = (bf16*)alloc((size_t)NL * DD * 2);
  bf16* W1T   = (bf16*)alloc((size_t)NL * DF * 2);
  bf16* W2T   = (bf16*)alloc((size_t)NL * DF * 2);

  if (fullprep)
    prep_all_kernel<<<6 * 3072, 256, 0, stream>>>(
        Wq, Wk, Wv, Wo, W1, W2, WqkvT, WoT, W1T, W2T);

  embed_kernel<<<2048, 256, 0, stream>>>(tokens, emb, pe, x);

  for (int l = 0; l < 6; ++l) {
    const bf16* wqkvt; const bf16* wot; const bf16* w1t; const bf16* w2t;
    if (fullprep) {
      wqkvt = WqkvT + (size_t)l * 3 * DD;
      wot   = WoT   + (size_t)l * DD;
      w1t   = W1T   + (size_t)l * DF;
      w2t   = W2T   + (size_t)l * DF;
    } else {
      prep_layer_kernel<<<3072, 256, 0, stream>>>(
          Wq + l * DD, Wk + l * DD, Wv + l * DD, Wo + l * DD,
          W1 + l * DF, W2 + l * DF, WqkvT, WoT, W1T, W2T);
      wqkvt = WqkvT; wot = WoT; w1t = W1T; w2t = W2T;
    }

    // ln1: layer 0 plain; later layers fold the previous FFN2 partials (np=4)
    if (l == 0)
      ln_kernel<<<2048, 256, 0, stream>>>(x, g1, be1, h);
    else
      ln_res_kernel<<<2048, 256, 0, stream>>>(
          x, Pp, 4, b2 + (l - 1) * 1024, g1 + l * 1024, be1 + l * 1024, h);

    // QKV: M=2048 N=3072 K=1024, BM=128 -> 384 blocks (3 resident/CU)
    gemm_pl<0, 128, 0><<<dim3(16, 24, 1), 256, 0, stream>>>(
        h, 1024, wqkvt, 1024, qkv, 3072, (const float*)nullptr, 1024);
    transpose_v_kernel<<<dim3(16, 32), 256, 0, stream>>>(qkv, vT);
    attn_kernel<<<dim3(8, 32), 512, 0, stream>>>(qkv, vT, tokens, ctx);
    attn_fixup_kernel<<<32, 64, 0, stream>>>(tokens, vT, ctx);
    // Wo: M=2048 N=1024 K=1024, BM=128 + splitK4 -> 512 blocks, bf16 partials
    gemm_pl<3, 128, 0><<<dim3(16, 8, 4), 256, 0, stream>>>(
        ctx, 1024, wot, 1024, Pp, 1024, (const float*)nullptr, 256);
    // ln2: x += sum(P0..3) + bo; h = LN(x)
    ln_res_kernel<<<2048, 256, 0, stream>>>(
        x, Pp, 4, bo + l * 1024, g2 + l * 1024, be2 + l * 1024, h);
    // FFN1: M=2048 N=4096 K=1024, BM=128 -> 512 blocks
    gemm_pl<2, 128, 0><<<dim3(16, 32, 1), 256, 0, stream>>>(
        h, 1024, w1t, 1024, ff, 4096, b1 + l * 4096, 1024);
    // FFN2: M=2048 N=1024 K=4096, BM=128 + splitK4 -> 512 blocks, bf16 partials
    gemm_pl<3, 128, 0><<<dim3(16, 8, 4), 256, 0, stream>>>(
        ff, 4096, w2t, 4096, Pp, 1024, (const float*)nullptr, 1024);
  }

  // final LN folds layer-5 FFN2 partials
  ln_res_kernel<<<2048, 256, 0, stream>>>(x, Pp, 4, b2 + 5 * 1024, gf, bff, h);
  transpose_cast_kernel<<<dim3(500, 16), 256, 0, stream>>>(Wout, WoutT, 32000, 1024);
  // logits: M=2048 N=32000 K=1024 -> 256x256 phase-interleaved, 1000 blocks
  gemm256<<<dim3(8, 125), 512, 0, stream>>>(
      h, 1024, WoutT, 1024, out, 32000, bout, 1024);
}

// Round 10
// 1252.331 us; speedup vs baseline: 1.3156x; 1.0760x over previous
//
#include <hip/hip_runtime.h>
#include <hip/hip_bf16.h>
#include <stdint.h>

typedef __hip_bfloat16 bf16;
typedef __attribute__((ext_vector_type(8))) short bf16x8;
typedef __attribute__((ext_vector_type(4))) float f32x4;

#define DEV static __device__ __forceinline__

DEV float b2f(bf16 v) { return __bfloat162float(v); }
DEV bf16  f2b(float v) { return __float2bfloat16(v); }

DEV float u2f(unsigned short u) {
  unsigned int x = (unsigned int)u << 16;
  float f;
  __builtin_memcpy(&f, &x, 4);
  return f;
}

DEV unsigned short f2u(float v) {
  bf16 b = f2b(v);
  unsigned short u;
  __builtin_memcpy(&u, &b, 2);
  return u;
}

DEV void gload16(const void* g, void* l) {
  __builtin_amdgcn_global_load_lds(
      (__attribute__((address_space(1))) void*)(void*)g,
      (__attribute__((address_space(3))) void*)l, 16, 0, 0);
}

DEV f32x4 mfma16(bf16x8 a, bf16x8 b, f32x4 c) {
  return __builtin_amdgcn_mfma_f32_16x16x32_bf16(a, b, c, 0, 0, 0);
}

// ---------------- embed: x = emb[tok]*32 + pe (all f32) ----------------
__global__ __launch_bounds__(256) void embed_kernel(
    const int* __restrict__ tok, const float* __restrict__ emb,
    const float* __restrict__ pe, float* __restrict__ x)
{
  const int r = blockIdx.x, t = threadIdx.x;
  const int s = r & 1023;
  const int tk = tok[r];
  const int d = t * 4;
  const float* ep = emb + (size_t)tk * 1024 + d;
  const float* pp = pe + (size_t)s * 1024 + d;
  float* xp = x + (size_t)r * 1024 + d;
  #pragma unroll
  for (int j = 0; j < 4; ++j)
    xp[j] = ep[j] * 32.0f + pp[j];
}

// ---------------- layernorm: h = LN(x)*g + b (f32 in, bf16 out) ----------------
__global__ __launch_bounds__(256) void ln_kernel(
    const float* __restrict__ x, const float* __restrict__ g,
    const float* __restrict__ be, bf16* __restrict__ h)
{
  const int r = blockIdx.x, t = threadIdx.x;
  const float4 v = ((const float4*)(x + (size_t)r * 1024))[t];
  float s  = v.x + v.y + v.z + v.w;
  float sq = v.x * v.x + v.y * v.y + v.z * v.z + v.w * v.w;
  #pragma unroll
  for (int d = 1; d < 64; d <<= 1) {
    s  += __shfl_xor(s, d);
    sq += __shfl_xor(sq, d);
  }
  __shared__ float red[8];
  const int w = t >> 6, l = t & 63;
  if (l == 0) { red[w] = s; red[4 + w] = sq; }
  __syncthreads();
  s  = red[0] + red[1] + red[2] + red[3];
  sq = red[4] + red[5] + red[6] + red[7];
  const float mean = s * (1.0f / 1024.0f);
  const float var  = sq * (1.0f / 1024.0f) - mean * mean;
  const float inv  = 1.0f / sqrtf(var + 1e-5f);
  bf16* hp = h + (size_t)r * 1024 + t * 4;
  const float* gp = g + t * 4;
  const float* bp = be + t * 4;
  const float vv[4] = {v.x, v.y, v.z, v.w};
  #pragma unroll
  for (int j = 0; j < 4; ++j)
    hp[j] = f2b((vv[j] - mean) * inv * gp[j] + bp[j]);
}

// -- fused residual + layernorm: x += sum(bf16 P[0..np)) + bias; h = LN(x)*g+be
__global__ __launch_bounds__(256) void ln_res_kernel(
    float* __restrict__ x, const bf16* __restrict__ P, int np,
    const float* __restrict__ bias, const float* __restrict__ g,
    const float* __restrict__ be, bf16* __restrict__ h)
{
  const int r = blockIdx.x, t = threadIdx.x;
  float4 v = ((const float4*)(x + (size_t)r * 1024))[t];
  for (int i = 0; i < np; ++i) {
    const ushort4 pv = ((const ushort4*)(P + ((size_t)i * 2048 + r) * 1024))[t];
    v.x += u2f(pv.x); v.y += u2f(pv.y); v.z += u2f(pv.z); v.w += u2f(pv.w);
  }
  const float4 bv = ((const float4*)bias)[t];
  v.x += bv.x; v.y += bv.y; v.z += bv.z; v.w += bv.w;

  float s  = v.x + v.y + v.z + v.w;
  float sq = v.x * v.x + v.y * v.y + v.z * v.z + v.w * v.w;
  #pragma unroll
  for (int d = 1; d < 64; d <<= 1) {
    s  += __shfl_xor(s, d);
    sq += __shfl_xor(sq, d);
  }
  __shared__ float red[8];
  const int w = t >> 6, l = t & 63;
  if (l == 0) { red[w] = s; red[4 + w] = sq; }
  __syncthreads();
  s  = red[0] + red[1] + red[2] + red[3];
  sq = red[4] + red[5] + red[6] + red[7];
  const float mean = s * (1.0f / 1024.0f);
  const float var  = sq * (1.0f / 1024.0f) - mean * mean;
  const float inv  = 1.0f / sqrtf(var + 1e-5f);

  ((float4*)(x + (size_t)r * 1024))[t] = v;
  bf16* hp = h + (size_t)r * 1024 + t * 4;
  const float* gp = g + t * 4;
  const float* bp = be + t * 4;
  const float vv[4] = {v.x, v.y, v.z, v.w};
  #pragma unroll
  for (int j = 0; j < 4; ++j)
    hp[j] = f2b((vv[j] - mean) * inv * gp[j] + bp[j]);
}

// ------------- 64x64 transpose+cast tile body -------------
DEV void transpose_tile(const float* __restrict__ in, bf16* __restrict__ out,
                        int ldin, int ldout, int r0, int c0, int t)
{
  __shared__ bf16 tile[64][64];
  #pragma unroll
  for (int i = 0; i < 4; ++i) {
    const int r = i * 16 + (t >> 4), c = (t & 15) * 4;
    const float4 v = *(const float4*)&in[(size_t)(r0 + r) * ldin + c0 + c];
    tile[r][c + 0] = f2b(v.x);
    tile[r][c + 1] = f2b(v.y);
    tile[r][c + 2] = f2b(v.z);
    tile[r][c + 3] = f2b(v.w);
  }
  __syncthreads();
  #pragma unroll
  for (int i = 0; i < 2; ++i) {
    const int oc = i * 32 + (t >> 3);
    const int rr = (t & 7) * 8;
    unsigned short tmp[8] __attribute__((aligned(16)));
    #pragma unroll
    for (int j = 0; j < 8; ++j)
      tmp[j] = ((const unsigned short*)tile)[(rr + j) * 64 + oc];
    *(uint4*)&out[(size_t)(c0 + oc) * ldout + r0 + rr] = *(const uint4*)tmp;
  }
}

// generic single-matrix transpose+cast (used for Wout)
__global__ __launch_bounds__(256) void transpose_cast_kernel(
    const float* __restrict__ in, bf16* __restrict__ out, int ldin, int ldout)
{
  transpose_tile(in, out, ldin, ldout, blockIdx.y * 64, blockIdx.x * 64, threadIdx.x);
}

// dispatch one 64x64 tile of the per-layer weight set (3072 tiles/layer)
DEV void prep_dispatch(int wid,
    const float* Wq, const float* Wk, const float* Wv, const float* Wo,
    const float* W1, const float* W2,
    bf16* WqkvT, bf16* WoT, bf16* W1T, bf16* W2T, int t)
{
  const float* src; bf16* dst; int ldin, ldout, tx, ty;
  if (wid < 768) {
    const int m = wid >> 8, tt = wid & 255;
    src = (m == 0) ? Wq : (m == 1) ? Wk : Wv;
    dst = WqkvT + (size_t)m * 1024 * 1024;
    ldin = 1024; ldout = 1024; tx = tt & 15; ty = tt >> 4;
  } else if (wid < 1024) {
    const int tt = wid - 768;
    src = Wo; dst = WoT; ldin = 1024; ldout = 1024; tx = tt & 15; ty = tt >> 4;
  } else if (wid < 2048) {
    const int tt = wid - 1024;
    src = W1; dst = W1T; ldin = 4096; ldout = 1024; tx = tt & 63; ty = tt >> 6;
  } else {
    const int tt = wid - 2048;
    src = W2; dst = W2T; ldin = 1024; ldout = 4096; tx = tt & 15; ty = tt >> 4;
  }
  transpose_tile(src, dst, ldin, ldout, ty * 64, tx * 64, t);
}

// per-layer weight prep (fallback path)
__global__ __launch_bounds__(256) void prep_layer_kernel(
    const float* __restrict__ Wq, const float* __restrict__ Wk,
    const float* __restrict__ Wv, const float* __restrict__ Wo,
    const float* __restrict__ W1, const float* __restrict__ W2,
    bf16* __restrict__ WqkvT, bf16* __restrict__ WoT,
    bf16* __restrict__ W1T, bf16* __restrict__ W2T)
{
  prep_dispatch(blockIdx.x, Wq, Wk, Wv, Wo, W1, W2,
                WqkvT, WoT, W1T, W2T, threadIdx.x);
}

// all-layers weight prep (when ws permits): 6*3072 blocks
__global__ __launch_bounds__(256) void prep_all_kernel(
    const float* __restrict__ Wq, const float* __restrict__ Wk,
    const float* __restrict__ Wv, const float* __restrict__ Wo,
    const float* __restrict__ W1, const float* __restrict__ W2,
    bf16* __restrict__ WqkvT, bf16* __restrict__ WoT,
    bf16* __restrict__ W1T, bf16* __restrict__ W2T)
{
  const int layer = blockIdx.x / 3072;
  const int wid = blockIdx.x - layer * 3072;
  const size_t DD = (size_t)1024 * 1024, DF = (size_t)1024 * 4096;
  prep_dispatch(wid,
      Wq + layer * DD, Wk + layer * DD, Wv + layer * DD, Wo + layer * DD,
      W1 + layer * DF, W2 + layer * DF,
      WqkvT + layer * 3 * DD, WoT + layer * DD,
      W1T + layer * DF, W2T + layer * DF, threadIdx.x);
}

// ------------- pipelined GEMM: C(MxN) = A(MxK,row) * BT(NxK,row)^T -------------
// BM=BN=128, BK=32; 4-buffer LDS ring, 2 K-tiles per barrier-pair (32 MFMA),
// counted vmcnt(8) (T4), raw barriers, verified conflict-free T2 XOR swizzle.
// EPI: 0 = bf16 store; 1 = +bias f32 store; 2 = gelu(acc+bias) bf16;
//      3 = bf16 K-slice partial store P[z][M][N]; 4 = QKV fused: cols<2048 ->
//          qkv bf16, cols>=2048 -> vT[(b*1024+hk)*1024+s] transposed write
// grid: (M/128, N/128, KSLICES), block 256 (4 waves), K-slice length ksl
template<int EPI, int SWZ>
__global__ __launch_bounds__(256) void gemm_pl(
    const bf16* __restrict__ A, int lda,
    const bf16* __restrict__ BT, int ldb,
    void* __restrict__ Cp, int ldc,
    const float* __restrict__ bias,
    bf16* __restrict__ vTp,
    int ksl)
{
  __shared__ bf16 As[4][4096];
  __shared__ bf16 Bs[4][4096];
  const int t = threadIdx.x;

  int bm, bn;
  if constexpr (SWZ) {                        // XCD-chunked swizzle (nwg%8==0)
    const int nbm = gridDim.x;
    const int nwg = nbm * gridDim.y;
    int wid = blockIdx.x + nbm * blockIdx.y;
    wid = (wid & 7) * (nwg >> 3) + (wid >> 3);
    bm = wid % nbm; bn = wid / nbm;
  } else {
    bm = blockIdx.x; bn = blockIdx.y;
  }

  const int w = t >> 6, l = t & 63;
  const int wr = (w >> 1) * 64, wc = (w & 1) * 64;
  const int l15 = l & 15, l4 = l >> 4;
  const int kbeg = blockIdx.z * ksl;
  const int npairs = ksl >> 6;                // 2 K-tiles per iteration

  // T2: pre-swizzled global column-block; key = (lds_row>>1)&3 = (t>>3)&3
  const int colblk = (((t & 3) ^ ((t >> 3) & 3))) * 8;
  const bf16* gA = A  + (size_t)(bm * 128 + (t >> 2)) * lda + colblk + kbeg;
  const bf16* gB = BT + (size_t)(bn * 128 + (t >> 2)) * ldb + colblk + kbeg;
  const int dst = w * 512;

  auto stage = [&](int tile, int buf) {
    const int k0 = tile * 32;
    gload16(gA + k0, &As[buf][dst]);
    gload16(gA + (size_t)64 * lda + k0, &As[buf][2048 + dst]);
    gload16(gB + k0, &Bs[buf][dst]);
    gload16(gB + (size_t)64 * ldb + k0, &Bs[buf][2048 + dst]);
  };

  f32x4 acc[4][4];
  #pragma unroll
  for (int m = 0; m < 4; ++m)
    #pragma unroll
    for (int n = 0; n < 4; ++n)
      acc[m][n] = (f32x4){0.f, 0.f, 0.f, 0.f};

  // prologue: pairs 0 (bufs 0,1) and 1 (bufs 2,3)
  stage(0, 0); stage(1, 1);
  stage(2, 2); stage(3, 3);

  // T2 read-side swizzle: column-block = l4 ^ ((row>>1)&3); row%16 == l15
  const int rdcol = ((l4 ^ ((l15 >> 1) & 3))) * 8;

  for (int pp = 0; pp < npairs; ++pp) {
    const int base = (pp & 1) << 1;           // bufs base, base+1 hold this pair
    if (pp + 1 < npairs) asm volatile("s_waitcnt vmcnt(8)" ::: "memory");
    else                 asm volatile("s_waitcnt vmcnt(0)" ::: "memory");
    __builtin_amdgcn_s_barrier();             // pair pp resident for all waves
    __builtin_amdgcn_sched_barrier(0);

    bf16x8 af0[4], bf0[4], af1[4], bf1[4];
    #pragma unroll
    for (int m = 0; m < 4; ++m)
      af0[m] = *(const bf16x8*)&As[base][(wr + m * 16 + l15) * 32 + rdcol];
    #pragma unroll
    for (int n = 0; n < 4; ++n)
      bf0[n] = *(const bf16x8*)&Bs[base][(wc + n * 16 + l15) * 32 + rdcol];
    #pragma unroll
    for (int m = 0; m < 4; ++m)
      af1[m] = *(const bf16x8*)&As[base + 1][(wr + m * 16 + l15) * 32 + rdcol];
    #pragma unroll
    for (int n = 0; n < 4; ++n)
      bf1[n] = *(const bf16x8*)&Bs[base + 1][(wc + n * 16 + l15) * 32 + rdcol];
    asm volatile("s_waitcnt lgkmcnt(0)" ::: "memory");
    __builtin_amdgcn_sched_barrier(0);        // rule #18: pin MFMA below wait
    __builtin_amdgcn_s_barrier();             // all waves done reading pair pp

    if (pp + 2 < npairs) {                    // overwrite just-freed bufs
      stage(2 * pp + 4, base);
      stage(2 * pp + 5, base + 1);
    }

    __builtin_amdgcn_s_setprio(1);
    #pragma unroll
    for (int m = 0; m < 4; ++m)
      #pragma unroll
      for (int n = 0; n < 4; ++n)
        acc[m][n] = mfma16(af0[m], bf0[n], acc[m][n]);
    #pragma unroll
    for (int m = 0; m < 4; ++m)
      #pragma unroll
      for (int n = 0; n < 4; ++n)
        acc[m][n] = mfma16(af1[m], bf1[n], acc[m][n]);
    __builtin_amdgcn_s_setprio(0);
    __builtin_amdgcn_sched_barrier(0);
  }

  const int crow = bm * 128 + wr, ccol = bn * 128 + wc;
  #pragma unroll
  for (int n = 0; n < 4; ++n) {
    const int col = ccol + n * 16 + l15;
    float bv = 0.f;
    if (EPI == 1 || EPI == 2) bv = bias[col];
    #pragma unroll
    for (int m = 0; m < 4; ++m) {
      const int row = crow + m * 16 + l4 * 4;
      if (EPI == 4 && ccol >= 2048) {
        // V part: vT[(b*1024 + hk)][s], 4 consecutive s as one 8B store
        const int b = row >> 10, s = row & 1023;
        const int hk = col - 2048;
        ushort4 pk;
        pk.x = f2u(acc[m][n][0]); pk.y = f2u(acc[m][n][1]);
        pk.z = f2u(acc[m][n][2]); pk.w = f2u(acc[m][n][3]);
        *(ushort4*)&vTp[((size_t)b * 1024 + hk) * 1024 + s] = pk;
        continue;
      }
      #pragma unroll
      for (int r = 0; r < 4; ++r) {
        const float v = acc[m][n][r];
        if (EPI == 0 || EPI == 4) {
          ((bf16*)Cp)[(size_t)(row + r) * ldc + col] = f2b(v);
        } else if (EPI == 1) {
          ((float*)Cp)[(size_t)(row + r) * ldc + col] = v + bv;
        } else if (EPI == 2) {
          const float u = v + bv;
          const float gel = 0.5f * u * (1.0f + erff(u * 0.70710678118654752f));
          ((bf16*)Cp)[(size_t)(row + r) * ldc + col] = f2b(gel);
        } else {
          const int M = gridDim.x * 128;
          ((bf16*)Cp)[((size_t)blockIdx.z * M + row + r) * ldc + col] = f2b(v);
        }
      }
    }
  }
}

// ------------- 256x256 8-wave phase-interleaved GEMM (logits) -------------
// BK=32, 3-buffer LDS ring (96 KB), counted vmcnt(4), per K-tile 2 phases
// (m201/T3+T4+T5 schedule). Verified conflict-free swizzle, key=(row>>1)&3.
// grid: (M/256, N/256), nwg % 8 == 0 (XCD swizzle). 512 threads (2M x 4N waves).
__global__ __launch_bounds__(512, 2) void gemm256(
    const bf16* __restrict__ A, int lda,
    const bf16* __restrict__ BT, int ldb,
    float* __restrict__ C, int ldc,
    const float* __restrict__ bias, int K)
{
  __shared__ bf16 As[3][8192];
  __shared__ bf16 Bs[3][8192];
  const int t = threadIdx.x;

  const int nbm = gridDim.x;
  const int nwg = nbm * gridDim.y;
  int wid = blockIdx.x + nbm * blockIdx.y;
  wid = (wid & 7) * (nwg >> 3) + (wid >> 3);
  const int bm = wid % nbm, bn = wid / nbm;

  const int w = t >> 6, l = t & 63;
  const int wm = w >> 2, wn = w & 3;
  const int l15 = l & 15, l4 = l >> 4;

  const int colblk = ((t & 3) ^ ((t >> 3) & 3)) * 8;
  const bf16* gA = A  + (size_t)(bm * 256 + (t >> 2)) * lda + colblk;
  const bf16* gB = BT + (size_t)(bn * 256 + (t >> 2)) * ldb + colblk;
  const int dst = w * 512;

  const int rd = (l4 ^ ((l15 >> 1) & 3)) * 8;
  const int arow = wm * 128 + l15;
  const int brow = wn * 64 + l15;

  f32x4 acc[8][4];
  #pragma unroll
  for (int m = 0; m < 8; ++m)
    #pragma unroll
    for (int n = 0; n < 4; ++n)
      acc[m][n] = (f32x4){0.f, 0.f, 0.f, 0.f};

  const int NT = K >> 5;

  auto stageA = [&](int kt, int buf) {
    const int k0 = kt * 32;
    gload16(gA + k0, &As[buf][dst]);
    gload16(gA + (size_t)128 * lda + k0, &As[buf][4096 + dst]);
  };
  auto stageB = [&](int kt, int buf) {
    const int k0 = kt * 32;
    gload16(gB + k0, &Bs[buf][dst]);
    gload16(gB + (size_t)128 * ldb + k0, &Bs[buf][4096 + dst]);
  };

  stageA(0, 0); stageB(0, 0);
  stageA(1, 1); stageB(1, 1);

  int buf = 0;
  for (int kt = 0; kt < NT; ++kt) {
    if (kt + 1 < NT) asm volatile("s_waitcnt vmcnt(4)" ::: "memory");
    else             asm volatile("s_waitcnt vmcnt(0)" ::: "memory");
    __builtin_amdgcn_s_barrier();
    __builtin_amdgcn_sched_barrier(0);

    int pb = buf + 2; if (pb >= 3) pb -= 3;
    const bf16* Ab = As[buf];
    const bf16* Bb = Bs[buf];

    // ---- phase 0: B frags + A frags m0..3; prefetch A-half of kt+2
    bf16x8 bfr[4], af[4];
    #pragma unroll
    for (int n = 0; n < 4; ++n)
      bfr[n] = *(const bf16x8*)&Bb[(brow + n * 16) * 32 + rd];
    #pragma unroll
    for (int m = 0; m < 4; ++m)
      af[m] = *(const bf16x8*)&Ab[(arow + m * 16) * 32 + rd];
    if (kt + 2 < NT) stageA(kt + 2, pb);
    asm volatile("s_waitcnt lgkmcnt(0)" ::: "memory");
    __builtin_amdgcn_sched_barrier(0);
    __builtin_amdgcn_s_setprio(1);
    #pragma unroll
    for (int m = 0; m < 4; ++m)
      #pragma unroll
      for (int n = 0; n < 4; ++n)
        acc[m][n] = mfma16(af[m], bfr[n], acc[m][n]);
    __builtin_amdgcn_s_setprio(0);
    __builtin_amdgcn_sched_barrier(0);
    __builtin_amdgcn_s_barrier();

    // ---- phase 1: A frags m4..7; prefetch B-half of kt+2
    #pragma unroll
    for (int m = 0; m < 4; ++m)
      af[m] = *(const bf16x8*)&Ab[(arow + (m + 4) * 16) * 32 + rd];
    if (kt + 2 < NT) stageB(kt + 2, pb);
    asm volatile("s_waitcnt lgkmcnt(0)" ::: "memory");
    __builtin_amdgcn_sched_barrier(0);
    __builtin_amdgcn_s_setprio(1);
    #pragma unroll
    for (int m = 0; m < 4; ++m)
      #pragma unroll
      for (int n = 0; n < 4; ++n)
        acc[m + 4][n] = mfma16(af[m], bfr[n], acc[m + 4][n]);
    __builtin_amdgcn_s_setprio(0);
    __builtin_amdgcn_sched_barrier(0);
    __builtin_amdgcn_s_barrier();

    if (++buf >= 3) buf = 0;
  }

  #pragma unroll
  for (int n = 0; n < 4; ++n) {
    const int col = bn * 256 + wn * 64 + n * 16 + l15;
    const float bv = bias[col];
    #pragma unroll
    for (int m = 0; m < 8; ++m) {
      const int row = bm * 256 + wm * 128 + m * 16 + l4 * 4;
      #pragma unroll
      for (int r = 0; r < 4; ++r)
        C[(size_t)(row + r) * ldc + col] = acc[m][n][r] + bv;
    }
  }
}

// ---------------- flash attention (8 waves x 16 q-rows, LDS XOR-swizzled) ----
// grid: (S/128, B*H), block 512 (wave w owns q-rows w*16..w*16+15)
__global__ __launch_bounds__(512) void attn_kernel(
    const bf16* __restrict__ qkv, const bf16* __restrict__ vT,
    const int* __restrict__ tokens, bf16* __restrict__ ctx)
{
  __shared__ bf16 Ks[128 * 64];
  __shared__ bf16 VTs[64 * 128];
  __shared__ bf16 Ps[128 * 128];

  const int qt = blockIdx.x;
  const int bh = blockIdx.y;
  const int b = bh >> 4, h = bh & 15;
  const int t = threadIdx.x, w = t >> 6, l = t & 63;
  const int l15 = l & 15, l4 = l >> 4;
  const int q0 = qt * 128;

  bf16x8 aq[2];
  #pragma unroll
  for (int ks = 0; ks < 2; ++ks)
    aq[ks] = *(const bf16x8*)(qkv +
        (size_t)(b * 1024 + q0 + w * 16 + l15) * 3072 +
        h * 64 + ks * 32 + l4 * 8);

  f32x4 o[4];
  float m_run[4], l_run[4];
  #pragma unroll
  for (int r = 0; r < 4; ++r) { m_run[r] = -1e30f; l_run[r] = 0.f; }
  #pragma unroll
  for (int nn = 0; nn < 4; ++nn)
    o[nn] = (f32x4){0.f, 0.f, 0.f, 0.f};

  const bf16* kb = qkv + (size_t)(b * 1024) * 3072 + 1024 + h * 64;
  const bf16* vb = vT + (size_t)(bh * 64) * 1024;
  const int* tb = tokens + b * 1024;

  // staging swizzle (pre-swizzled global source, linear LDS dest)
  const int kSrcCol = ((t & 7) ^ ((t >> 3) & 7)) * 8;     // K key: row&7
  const int vSrcCol = ((t & 15) ^ ((t >> 4) & 15)) * 8;   // V key: row&15

  for (int jt = 0; jt <= qt; ++jt) {
    const int j0 = jt * 128;
    __syncthreads();  // previous iteration's LDS reads complete
    #pragma unroll
    for (int i = 0; i < 2; ++i)
      gload16(kb + (size_t)(j0 + i * 64 + (t >> 3)) * 3072 + kSrcCol,
              Ks + i * 4096 + w * 512);
    #pragma unroll
    for (int i = 0; i < 2; ++i)
      gload16(vb + (size_t)(i * 32 + (t >> 4)) * 1024 + j0 + vSrcCol,
              VTs + i * 4096 + w * 512);
    __syncthreads();  // staged tiles visible

    // S = Q K^T for this wave's 16 rows x 128 cols
    f32x4 s[8];
    #pragma unroll
    for (int n = 0; n < 8; ++n)
      s[n] = (f32x4){0.f, 0.f, 0.f, 0.f};
    #pragma unroll
    for (int ks = 0; ks < 2; ++ks) {
      #pragma unroll
      for (int n = 0; n < 8; ++n) {
        const bf16x8 bk = *(const bf16x8*)
            &Ks[(n * 16 + l15) * 64 + ((ks * 32 + l4 * 8) ^ ((l15 & 7) * 8))];
        s[n] = mfma16(aq[ks], bk, s[n]);
      }
    }

    float padv[8];
    #pragma unroll
    for (int n = 0; n < 8; ++n)
      padv[n] = (tb[j0 + n * 16 + l15] == 0) ? 1.f : 0.f;

    // online softmax per q-row; write P to LDS (swizzled, wave-local rows)
    #pragma unroll
    for (int r = 0; r < 4; ++r) {
      const int rloc = l4 * 4 + r;
      const int qrow = q0 + w * 16 + rloc;
      float vals[8];
      float mx = -1e30f;
      #pragma unroll
      for (int n = 0; n < 8; ++n) {
        const int jg = j0 + n * 16 + l15;
        float v = s[n][r] * 0.125f;
        if (jg > qrow || padv[n] != 0.f) v = -1e9f;
        vals[n] = v;
        mx = fmaxf(mx, v);
      }
      #pragma unroll
      for (int d = 1; d < 16; d <<= 1) mx = fmaxf(mx, __shfl_xor(mx, d));
      const float newm = fmaxf(m_run[r], mx);
      const float sc = __expf(m_run[r] - newm);
      m_run[r] = newm;
      float rs = 0.f;
      #pragma unroll
      for (int n = 0; n < 8; ++n) {
        const float pv = __expf(vals[n] - newm);
        vals[n] = pv;
        rs += pv;
      }
      #pragma unroll
      for (int d = 1; d < 16; d <<= 1) rs += __shfl_xor(rs, d);
      l_run[r] = l_run[r] * sc + rs;
      #pragma unroll
      for (int nn = 0; nn < 4; ++nn) o[nn][r] = o[nn][r] * sc;
      #pragma unroll
      for (int n = 0; n < 8; ++n)
        Ps[(w * 16 + rloc) * 128 + ((n * 16 + l15) ^ (rloc * 8))] = f2b(vals[n]);
    }
    // wave-local P rows: only need our own ds_writes complete (no block barrier)
    asm volatile("s_waitcnt lgkmcnt(0)" ::: "memory");

    // O += P V
    #pragma unroll
    for (int ks = 0; ks < 4; ++ks) {
      const bf16x8 ap = *(const bf16x8*)
          &Ps[(w * 16 + l15) * 128 + ((ks * 32 + l4 * 8) ^ (l15 * 8))];
      #pragma unroll
      for (int nn = 0; nn < 4; ++nn) {
        const bf16x8 bv = *(const bf16x8*)
            &VTs[(nn * 16 + l15) * 128 + ((ks * 32 + l4 * 8) ^ (l15 * 8))];
        o[nn] = mfma16(ap, bv, o[nn]);
      }
    }
  }

  // epilogue: ctx = O / l
  #pragma unroll
  for (int r = 0; r < 4; ++r) {
    const float inv = 1.0f / l_run[r];
    const int qrow = q0 + w * 16 + l4 * 4 + r;
    #pragma unroll
    for (int nn = 0; nn < 4; ++nn)
      ctx[(size_t)(b * 1024 + qrow) * 1024 + h * 64 + nn * 16 + l15] =
          f2b(o[nn][r] * inv);
  }
}

// ------------- fixup for all-masked rows (leading pad tokens) -------------
__global__ __launch_bounds__(64) void attn_fixup_kernel(
    const int* __restrict__ tokens, const bf16* __restrict__ vT,
    bf16* __restrict__ ctx)
{
  const int bh = blockIdx.x;
  const int b = bh >> 4, h = bh & 15;
  __shared__ int p0s;
  if (threadIdx.x == 0) {
    int p = 0;
    const int* tb = tokens + b * 1024;
    while (p < 1024 && tb[p] == 0) ++p;
    p0s = p;
  }
  __syncthreads();
  const int P0 = p0s;
  if (P0 == 0) return;
  const int dk = threadIdx.x;
  const bf16* vrow = vT + (size_t)(bh * 64 + dk) * 1024;
  float sum = 0.f;
  for (int sIdx = 0; sIdx < 1024; ++sIdx) sum += b2f(vrow[sIdx]);
  const bf16 mv = f2b(sum * (1.0f / 1024.0f));
  for (int q = 0; q < P0; ++q)
    ctx[(size_t)(b * 1024 + q) * 1024 + h * 64 + dk] = mv;
}

// ---------------- host ----------------
extern "C" void kernel_launch(void* const* d_in, const int* in_sizes, int n_in,
                              void* d_out, int out_size, void* d_ws, size_t ws_size,
                              hipStream_t stream)
{
  (void)in_sizes; (void)n_in; (void)out_size;
  const int*   tokens = (const int*)d_in[0];
  const float* emb  = (const float*)d_in[1];
  const float* pe   = (const float*)d_in[2];
  const float* Wq   = (const float*)d_in[3];
  const float* Wk   = (const float*)d_in[4];
  const float* Wv   = (const float*)d_in[5];
  const float* Wo   = (const float*)d_in[6];
  const float* bo   = (const float*)d_in[7];
  const float* g1   = (const float*)d_in[8];
  const float* be1  = (const float*)d_in[9];
  const float* g2   = (const float*)d_in[10];
  const float* be2  = (const float*)d_in[11];
  const float* W1   = (const float*)d_in[12];
  const float* b1   = (const float*)d_in[13];
  const float* W2   = (const float*)d_in[14];
  const float* b2   = (const float*)d_in[15];
  const float* gf   = (const float*)d_in[16];
  const float* bff  = (const float*)d_in[17];
  const float* Wout = (const float*)d_in[18];
  const float* bout = (const float*)d_in[19];
  float* out = (float*)d_out;

  char* p = (char*)d_ws;
  auto alloc = [&](size_t bytes) {
    char* q = p;
    p += (bytes + 255) & ~(size_t)255;
    return q;
  };
  float* x    = (float*)alloc((size_t)2048 * 1024 * 4);
  bf16* Pp    = (bf16*)alloc((size_t)4 * 2048 * 1024 * 2);  // bf16 K-slice partials
  bf16* h     = (bf16*)alloc((size_t)2048 * 1024 * 2);
  bf16* qkv   = (bf16*)alloc((size_t)2048 * 3072 * 2);
  bf16* vT    = (bf16*)alloc((size_t)2048 * 1024 * 2);
  bf16* ctx   = (bf16*)alloc((size_t)2048 * 1024 * 2);
  bf16* ff    = (bf16*)alloc((size_t)2048 * 4096 * 2);
  bf16* WoutT = (bf16*)alloc((size_t)32000 * 1024 * 2);

  const size_t DD = (size_t)1024 * 1024;
  const size_t DF = (size_t)1024 * 4096;

  const size_t perLayerW = (3 * DD + DD + DF + DF) * 2;
  const size_t used = (size_t)(p - (char*)d_ws);
  const bool fullprep = ws_size >= used + 6 * perLayerW + 8192;
  const int NL = fullprep ? 6 : 1;
  bf16* WqkvT = (bf16*)alloc((size_t)NL * 3 * DD * 2);
  bf16* WoT   = (bf16*)alloc((size_t)NL * DD * 2);
  bf16* W1T   = (bf16*)alloc((size_t)NL * DF * 2);
  bf16* W2T   = (bf16*)alloc((size_t)NL * DF * 2);

  if (fullprep)
    prep_all_kernel<<<6 * 3072, 256, 0, stream>>>(
        Wq, Wk, Wv, Wo, W1, W2, WqkvT, WoT, W1T, W2T);

  embed_kernel<<<2048, 256, 0, stream>>>(tokens, emb, pe, x);

  for (int l = 0; l < 6; ++l) {
    const bf16* wqkvt; const bf16* wot; const bf16* w1t; const bf16* w2t;
    if (fullprep) {
      wqkvt = WqkvT + (size_t)l * 3 * DD;
      wot   = WoT   + (size_t)l * DD;
      w1t   = W1T   + (size_t)l * DF;
      w2t   = W2T   + (size_t)l * DF;
    } else {
      prep_layer_kernel<<<3072, 256, 0, stream>>>(
          Wq + l * DD, Wk + l * DD, Wv + l * DD, Wo + l * DD,
          W1 + l * DF, W2 + l * DF, WqkvT, WoT, W1T, W2T);
      wqkvt = WqkvT; wot = WoT; w1t = W1T; w2t = W2T;
    }

    // ln1: layer 0 plain; later layers fold the previous FFN2 partials (np=4)
    if (l == 0)
      ln_kernel<<<2048, 256, 0, stream>>>(x, g1, be1, h);
    else
      ln_res_kernel<<<2048, 256, 0, stream>>>(
          x, Pp, 4, b2 + (l - 1) * 1024, g1 + l * 1024, be1 + l * 1024, h);

    // QKV: M=2048 N=3072 K=1024 -> 384 blocks; fused V-transpose epilogue
    gemm_pl<4, 0><<<dim3(16, 24, 1), 256, 0, stream>>>(
        h, 1024, wqkvt, 1024, qkv, 3072, (const float*)nullptr, vT, 1024);
    attn_kernel<<<dim3(8, 32), 512, 0, stream>>>(qkv, vT, tokens, ctx);
    attn_fixup_kernel<<<32, 64, 0, stream>>>(tokens, vT, ctx);
    // Wo: M=2048 N=1024 K=1024, splitK4 -> 512 blocks, bf16 partials
    gemm_pl<3, 0><<<dim3(16, 8, 4), 256, 0, stream>>>(
        ctx, 1024, wot, 1024, Pp, 1024, (const float*)nullptr,
        (bf16*)nullptr, 256);
    // ln2: x += sum(P0..3) + bo; h = LN(x)
    ln_res_kernel<<<2048, 256, 0, stream>>>(
        x, Pp, 4, bo + l * 1024, g2 + l * 1024, be2 + l * 1024, h);
    // FFN1: M=2048 N=4096 K=1024 -> 512 blocks
    gemm_pl<2, 0><<<dim3(16, 32, 1), 256, 0, stream>>>(
        h, 1024, w1t, 1024, ff, 4096, b1 + l * 4096, (bf16*)nullptr, 1024);
    // FFN2: M=2048 N=1024 K=4096, splitK4 -> 512 blocks, bf16 partials
    gemm_pl<3, 0><<<dim3(16, 8, 4), 256, 0, stream>>>(
        ff, 4096, w2t, 4096, Pp, 1024, (const float*)nullptr,
        (bf16*)nullptr, 1024);
  }

  // final LN folds layer-5 FFN2 partials
  ln_res_kernel<<<2048, 256, 0, stream>>>(x, Pp, 4, b2 + 5 * 1024, gf, bff, h);
  transpose_cast_kernel<<<dim3(500, 16), 256, 0, stream>>>(Wout, WoutT, 32000, 1024);
  // logits: M=2048 N=32000 K=1024 -> 256x256 phase-interleaved, 1000 blocks
  gemm256<<<dim3(8, 125), 512, 0, stream>>>(
      h, 1024, WoutT, 1024, out, 32000, bout, 1024);
}

// Round 11
// 1238.321 us; speedup vs baseline: 1.3305x; 1.0113x over previous
//
#include <hip/hip_runtime.h>
#include <hip/hip_bf16.h>
#include <stdint.h>

typedef __hip_bfloat16 bf16;
typedef __attribute__((ext_vector_type(8))) short bf16x8;
typedef __attribute__((ext_vector_type(4))) float f32x4;

#define DEV static __device__ __forceinline__

DEV float b2f(bf16 v) { return __bfloat162float(v); }
DEV bf16  f2b(float v) { return __float2bfloat16(v); }

DEV float u2f(unsigned short u) {
  unsigned int x = (unsigned int)u << 16;
  float f;
  __builtin_memcpy(&f, &x, 4);
  return f;
}

DEV unsigned short f2u(float v) {
  bf16 b = f2b(v);
  unsigned short u;
  __builtin_memcpy(&u, &b, 2);
  return u;
}

DEV void gload16(const void* g, void* l) {
  __builtin_amdgcn_global_load_lds(
      (__attribute__((address_space(1))) void*)(void*)g,
      (__attribute__((address_space(3))) void*)l, 16, 0, 0);
}

DEV f32x4 mfma16(bf16x8 a, bf16x8 b, f32x4 c) {
  return __builtin_amdgcn_mfma_f32_16x16x32_bf16(a, b, c, 0, 0, 0);
}

// ---------------- embed: x = emb[tok]*32 + pe (all f32) ----------------
__global__ __launch_bounds__(256) void embed_kernel(
    const int* __restrict__ tok, const float* __restrict__ emb,
    const float* __restrict__ pe, float* __restrict__ x)
{
  const int r = blockIdx.x, t = threadIdx.x;
  const int s = r & 1023;
  const int tk = tok[r];
  const int d = t * 4;
  const float* ep = emb + (size_t)tk * 1024 + d;
  const float* pp = pe + (size_t)s * 1024 + d;
  float* xp = x + (size_t)r * 1024 + d;
  #pragma unroll
  for (int j = 0; j < 4; ++j)
    xp[j] = ep[j] * 32.0f + pp[j];
}

// ---------------- layernorm: h = LN(x)*g + b (f32 in, bf16 out) ----------------
__global__ __launch_bounds__(256) void ln_kernel(
    const float* __restrict__ x, const float* __restrict__ g,
    const float* __restrict__ be, bf16* __restrict__ h)
{
  const int r = blockIdx.x, t = threadIdx.x;
  const float4 v = ((const float4*)(x + (size_t)r * 1024))[t];
  float s  = v.x + v.y + v.z + v.w;
  float sq = v.x * v.x + v.y * v.y + v.z * v.z + v.w * v.w;
  #pragma unroll
  for (int d = 1; d < 64; d <<= 1) {
    s  += __shfl_xor(s, d);
    sq += __shfl_xor(sq, d);
  }
  __shared__ float red[8];
  const int w = t >> 6, l = t & 63;
  if (l == 0) { red[w] = s; red[4 + w] = sq; }
  __syncthreads();
  s  = red[0] + red[1] + red[2] + red[3];
  sq = red[4] + red[5] + red[6] + red[7];
  const float mean = s * (1.0f / 1024.0f);
  const float var  = sq * (1.0f / 1024.0f) - mean * mean;
  const float inv  = 1.0f / sqrtf(var + 1e-5f);
  bf16* hp = h + (size_t)r * 1024 + t * 4;
  const float* gp = g + t * 4;
  const float* bp = be + t * 4;
  const float vv[4] = {v.x, v.y, v.z, v.w};
  #pragma unroll
  for (int j = 0; j < 4; ++j)
    hp[j] = f2b((vv[j] - mean) * inv * gp[j] + bp[j]);
}

// -- fused residual + layernorm: x += sum(bf16 P[0..np)) + bias; h = LN(x)*g+be
__global__ __launch_bounds__(256) void ln_res_kernel(
    float* __restrict__ x, const bf16* __restrict__ P, int np,
    const float* __restrict__ bias, const float* __restrict__ g,
    const float* __restrict__ be, bf16* __restrict__ h)
{
  const int r = blockIdx.x, t = threadIdx.x;
  float4 v = ((const float4*)(x + (size_t)r * 1024))[t];
  for (int i = 0; i < np; ++i) {
    const ushort4 pv = ((const ushort4*)(P + ((size_t)i * 2048 + r) * 1024))[t];
    v.x += u2f(pv.x); v.y += u2f(pv.y); v.z += u2f(pv.z); v.w += u2f(pv.w);
  }
  const float4 bv = ((const float4*)bias)[t];
  v.x += bv.x; v.y += bv.y; v.z += bv.z; v.w += bv.w;

  float s  = v.x + v.y + v.z + v.w;
  float sq = v.x * v.x + v.y * v.y + v.z * v.z + v.w * v.w;
  #pragma unroll
  for (int d = 1; d < 64; d <<= 1) {
    s  += __shfl_xor(s, d);
    sq += __shfl_xor(sq, d);
  }
  __shared__ float red[8];
  const int w = t >> 6, l = t & 63;
  if (l == 0) { red[w] = s; red[4 + w] = sq; }
  __syncthreads();
  s  = red[0] + red[1] + red[2] + red[3];
  sq = red[4] + red[5] + red[6] + red[7];
  const float mean = s * (1.0f / 1024.0f);
  const float var  = sq * (1.0f / 1024.0f) - mean * mean;
  const float inv  = 1.0f / sqrtf(var + 1e-5f);

  ((float4*)(x + (size_t)r * 1024))[t] = v;
  bf16* hp = h + (size_t)r * 1024 + t * 4;
  const float* gp = g + t * 4;
  const float* bp = be + t * 4;
  const float vv[4] = {v.x, v.y, v.z, v.w};
  #pragma unroll
  for (int j = 0; j < 4; ++j)
    hp[j] = f2b((vv[j] - mean) * inv * gp[j] + bp[j]);
}

// ------------- 64x64 transpose+cast tile body -------------
DEV void transpose_tile(const float* __restrict__ in, bf16* __restrict__ out,
                        int ldin, int ldout, int r0, int c0, int t)
{
  __shared__ bf16 tile[64][64];
  #pragma unroll
  for (int i = 0; i < 4; ++i) {
    const int r = i * 16 + (t >> 4), c = (t & 15) * 4;
    const float4 v = *(const float4*)&in[(size_t)(r0 + r) * ldin + c0 + c];
    tile[r][c + 0] = f2b(v.x);
    tile[r][c + 1] = f2b(v.y);
    tile[r][c + 2] = f2b(v.z);
    tile[r][c + 3] = f2b(v.w);
  }
  __syncthreads();
  #pragma unroll
  for (int i = 0; i < 2; ++i) {
    const int oc = i * 32 + (t >> 3);
    const int rr = (t & 7) * 8;
    unsigned short tmp[8] __attribute__((aligned(16)));
    #pragma unroll
    for (int j = 0; j < 8; ++j)
      tmp[j] = ((const unsigned short*)tile)[(rr + j) * 64 + oc];
    *(uint4*)&out[(size_t)(c0 + oc) * ldout + r0 + rr] = *(const uint4*)tmp;
  }
}

// generic single-matrix transpose+cast (used for Wout)
__global__ __launch_bounds__(256) void transpose_cast_kernel(
    const float* __restrict__ in, bf16* __restrict__ out, int ldin, int ldout)
{
  transpose_tile(in, out, ldin, ldout, blockIdx.y * 64, blockIdx.x * 64, threadIdx.x);
}

// dispatch one 64x64 tile of the per-layer weight set (3072 tiles/layer)
DEV void prep_dispatch(int wid,
    const float* Wq, const float* Wk, const float* Wv, const float* Wo,
    const float* W1, const float* W2,
    bf16* WqkvT, bf16* WoT, bf16* W1T, bf16* W2T, int t)
{
  const float* src; bf16* dst; int ldin, ldout, tx, ty;
  if (wid < 768) {
    const int m = wid >> 8, tt = wid & 255;
    src = (m == 0) ? Wq : (m == 1) ? Wk : Wv;
    dst = WqkvT + (size_t)m * 1024 * 1024;
    ldin = 1024; ldout = 1024; tx = tt & 15; ty = tt >> 4;
  } else if (wid < 1024) {
    const int tt = wid - 768;
    src = Wo; dst = WoT; ldin = 1024; ldout = 1024; tx = tt & 15; ty = tt >> 4;
  } else if (wid < 2048) {
    const int tt = wid - 1024;
    src = W1; dst = W1T; ldin = 4096; ldout = 1024; tx = tt & 63; ty = tt >> 6;
  } else {
    const int tt = wid - 2048;
    src = W2; dst = W2T; ldin = 1024; ldout = 4096; tx = tt & 15; ty = tt >> 4;
  }
  transpose_tile(src, dst, ldin, ldout, ty * 64, tx * 64, t);
}

// per-layer weight prep (fallback path)
__global__ __launch_bounds__(256) void prep_layer_kernel(
    const float* __restrict__ Wq, const float* __restrict__ Wk,
    const float* __restrict__ Wv, const float* __restrict__ Wo,
    const float* __restrict__ W1, const float* __restrict__ W2,
    bf16* __restrict__ WqkvT, bf16* __restrict__ WoT,
    bf16* __restrict__ W1T, bf16* __restrict__ W2T)
{
  prep_dispatch(blockIdx.x, Wq, Wk, Wv, Wo, W1, W2,
                WqkvT, WoT, W1T, W2T, threadIdx.x);
}

// all-layers weight prep (when ws permits): 6*3072 blocks
__global__ __launch_bounds__(256) void prep_all_kernel(
    const float* __restrict__ Wq, const float* __restrict__ Wk,
    const float* __restrict__ Wv, const float* __restrict__ Wo,
    const float* __restrict__ W1, const float* __restrict__ W2,
    bf16* __restrict__ WqkvT, bf16* __restrict__ WoT,
    bf16* __restrict__ W1T, bf16* __restrict__ W2T)
{
  const int layer = blockIdx.x / 3072;
  const int wid = blockIdx.x - layer * 3072;
  const size_t DD = (size_t)1024 * 1024, DF = (size_t)1024 * 4096;
  prep_dispatch(wid,
      Wq + layer * DD, Wk + layer * DD, Wv + layer * DD, Wo + layer * DD,
      W1 + layer * DF, W2 + layer * DF,
      WqkvT + layer * 3 * DD, WoT + layer * DD,
      W1T + layer * DF, W2T + layer * DF, threadIdx.x);
}

// ------------- pipelined GEMM: C(MxN) = A(MxK,row) * BT(NxK,row)^T -------------
// BM=BN=128, BK=32; 4-buffer LDS ring, 2 K-tiles per barrier-pair (32 MFMA),
// counted vmcnt(8) (T4), raw barriers, verified conflict-free T2 XOR swizzle.
// EPI: 0 = bf16 store; 1 = +bias f32 store; 2 = gelu(acc+bias) bf16;
//      3 = bf16 K-slice partial store P[z][M][N]; 4 = QKV fused: cols<2048 ->
//          qkv bf16, cols>=2048 -> vT[(b*1024+hk)*1024+s] transposed write
// grid: (M/128, N/128, KSLICES), block 256 (4 waves), K-slice length ksl
template<int EPI, int SWZ>
__global__ __launch_bounds__(256) void gemm_pl(
    const bf16* __restrict__ A, int lda,
    const bf16* __restrict__ BT, int ldb,
    void* __restrict__ Cp, int ldc,
    const float* __restrict__ bias,
    bf16* __restrict__ vTp,
    int ksl)
{
  __shared__ bf16 As[4][4096];
  __shared__ bf16 Bs[4][4096];
  const int t = threadIdx.x;

  int bm, bn;
  if constexpr (SWZ) {                        // XCD-chunked swizzle (nwg%8==0)
    const int nbm = gridDim.x;
    const int nwg = nbm * gridDim.y;
    int wid = blockIdx.x + nbm * blockIdx.y;
    wid = (wid & 7) * (nwg >> 3) + (wid >> 3);
    bm = wid % nbm; bn = wid / nbm;
  } else {
    bm = blockIdx.x; bn = blockIdx.y;
  }

  const int w = t >> 6, l = t & 63;
  const int wr = (w >> 1) * 64, wc = (w & 1) * 64;
  const int l15 = l & 15, l4 = l >> 4;
  const int kbeg = blockIdx.z * ksl;
  const int npairs = ksl >> 6;                // 2 K-tiles per iteration

  // T2: pre-swizzled global column-block; key = (lds_row>>1)&3 = (t>>3)&3
  const int colblk = (((t & 3) ^ ((t >> 3) & 3))) * 8;
  const bf16* gA = A  + (size_t)(bm * 128 + (t >> 2)) * lda + colblk + kbeg;
  const bf16* gB = BT + (size_t)(bn * 128 + (t >> 2)) * ldb + colblk + kbeg;
  const int dst = w * 512;

  auto stage = [&](int tile, int buf) {
    const int k0 = tile * 32;
    gload16(gA + k0, &As[buf][dst]);
    gload16(gA + (size_t)64 * lda + k0, &As[buf][2048 + dst]);
    gload16(gB + k0, &Bs[buf][dst]);
    gload16(gB + (size_t)64 * ldb + k0, &Bs[buf][2048 + dst]);
  };

  f32x4 acc[4][4];
  #pragma unroll
  for (int m = 0; m < 4; ++m)
    #pragma unroll
    for (int n = 0; n < 4; ++n)
      acc[m][n] = (f32x4){0.f, 0.f, 0.f, 0.f};

  // prologue: pairs 0 (bufs 0,1) and 1 (bufs 2,3)
  stage(0, 0); stage(1, 1);
  stage(2, 2); stage(3, 3);

  // T2 read-side swizzle: column-block = l4 ^ ((row>>1)&3); row%16 == l15
  const int rdcol = ((l4 ^ ((l15 >> 1) & 3))) * 8;

  for (int pp = 0; pp < npairs; ++pp) {
    const int base = (pp & 1) << 1;           // bufs base, base+1 hold this pair
    if (pp + 1 < npairs) asm volatile("s_waitcnt vmcnt(8)" ::: "memory");
    else                 asm volatile("s_waitcnt vmcnt(0)" ::: "memory");
    __builtin_amdgcn_s_barrier();             // pair pp resident for all waves
    __builtin_amdgcn_sched_barrier(0);

    bf16x8 af0[4], bf0[4], af1[4], bf1[4];
    #pragma unroll
    for (int m = 0; m < 4; ++m)
      af0[m] = *(const bf16x8*)&As[base][(wr + m * 16 + l15) * 32 + rdcol];
    #pragma unroll
    for (int n = 0; n < 4; ++n)
      bf0[n] = *(const bf16x8*)&Bs[base][(wc + n * 16 + l15) * 32 + rdcol];
    #pragma unroll
    for (int m = 0; m < 4; ++m)
      af1[m] = *(const bf16x8*)&As[base + 1][(wr + m * 16 + l15) * 32 + rdcol];
    #pragma unroll
    for (int n = 0; n < 4; ++n)
      bf1[n] = *(const bf16x8*)&Bs[base + 1][(wc + n * 16 + l15) * 32 + rdcol];
    asm volatile("s_waitcnt lgkmcnt(0)" ::: "memory");
    __builtin_amdgcn_sched_barrier(0);        // rule #18: pin MFMA below wait
    __builtin_amdgcn_s_barrier();             // all waves done reading pair pp

    if (pp + 2 < npairs) {                    // overwrite just-freed bufs
      stage(2 * pp + 4, base);
      stage(2 * pp + 5, base + 1);
    }

    __builtin_amdgcn_s_setprio(1);
    #pragma unroll
    for (int m = 0; m < 4; ++m)
      #pragma unroll
      for (int n = 0; n < 4; ++n)
        acc[m][n] = mfma16(af0[m], bf0[n], acc[m][n]);
    #pragma unroll
    for (int m = 0; m < 4; ++m)
      #pragma unroll
      for (int n = 0; n < 4; ++n)
        acc[m][n] = mfma16(af1[m], bf1[n], acc[m][n]);
    __builtin_amdgcn_s_setprio(0);
    __builtin_amdgcn_sched_barrier(0);
  }

  const int crow = bm * 128 + wr, ccol = bn * 128 + wc;
  #pragma unroll
  for (int n = 0; n < 4; ++n) {
    const int col = ccol + n * 16 + l15;
    float bv = 0.f;
    if (EPI == 1 || EPI == 2) bv = bias[col];
    #pragma unroll
    for (int m = 0; m < 4; ++m) {
      const int row = crow + m * 16 + l4 * 4;
      if (EPI == 4 && ccol >= 2048) {
        // V part: vT[(b*1024 + hk)][s], 4 consecutive s as one 8B store
        const int b = row >> 10, s = row & 1023;
        const int hk = col - 2048;
        ushort4 pk;
        pk.x = f2u(acc[m][n][0]); pk.y = f2u(acc[m][n][1]);
        pk.z = f2u(acc[m][n][2]); pk.w = f2u(acc[m][n][3]);
        *(ushort4*)&vTp[((size_t)b * 1024 + hk) * 1024 + s] = pk;
        continue;
      }
      #pragma unroll
      for (int r = 0; r < 4; ++r) {
        const float v = acc[m][n][r];
        if (EPI == 0 || EPI == 4) {
          ((bf16*)Cp)[(size_t)(row + r) * ldc + col] = f2b(v);
        } else if (EPI == 1) {
          ((float*)Cp)[(size_t)(row + r) * ldc + col] = v + bv;
        } else if (EPI == 2) {
          const float u = v + bv;
          const float gel = 0.5f * u * (1.0f + erff(u * 0.70710678118654752f));
          ((bf16*)Cp)[(size_t)(row + r) * ldc + col] = f2b(gel);
        } else {
          const int M = gridDim.x * 128;
          ((bf16*)Cp)[((size_t)blockIdx.z * M + row + r) * ldc + col] = f2b(v);
        }
      }
    }
  }
}

// ------------- 256x128 8-wave occupancy-first GEMM (logits) -------------
// 8 waves as 4m x 2n, per-wave 64x64 output (acc = 64 VGPR); 2-buffer BK=32
// ring (48 KB LDS) -> 2 blocks/CU, 4 waves/SIMD (launch_bounds(512,4)).
// Counted vmcnt(3) (T4), raw barriers, verified conflict-free XOR swizzle.
// grid: (M/256, N/128), nwg % 8 == 0 (XCD swizzle). 512 threads.
__global__ __launch_bounds__(512, 4) void gemm256(
    const bf16* __restrict__ A, int lda,
    const bf16* __restrict__ BT, int ldb,
    float* __restrict__ C, int ldc,
    const float* __restrict__ bias, int K)
{
  __shared__ bf16 As[2][8192];   // 256 rows x 32 cols
  __shared__ bf16 Bs[2][4096];   // 128 rows x 32 cols
  const int t = threadIdx.x;

  const int nbm = gridDim.x;
  const int nwg = nbm * gridDim.y;
  int wid = blockIdx.x + nbm * blockIdx.y;
  wid = (wid & 7) * (nwg >> 3) + (wid >> 3);
  const int bm = wid % nbm, bn = wid / nbm;

  const int w = t >> 6, l = t & 63;
  const int wm = w >> 1, wn = w & 1;          // 4m x 2n waves
  const int l15 = l & 15, l4 = l >> 4;

  // staging: thread t -> LDS row (t>>2), col-block (t&3);
  // pre-swizzled global col-block, key (row>>1)&3 = (t>>3)&3
  const int colblk = ((t & 3) ^ ((t >> 3) & 3)) * 8;
  const bf16* gA = A  + (size_t)(bm * 256 + (t >> 2)) * lda + colblk;
  const bf16* gB = BT + (size_t)(bn * 128 + (t >> 2)) * ldb + colblk;
  const int dst = w * 512;

  auto stage = [&](int kt, int buf) {
    const int k0 = kt * 32;
    gload16(gA + k0, &As[buf][dst]);                       // A rows 0..127
    gload16(gA + (size_t)128 * lda + k0, &As[buf][4096 + dst]);  // A rows 128..255
    gload16(gB + k0, &Bs[buf][dst]);                       // B rows 0..127
  };

  // read-side swizzle: col-block = l4 ^ ((row>>1)&3); row%16 == l15
  const int rd = (l4 ^ ((l15 >> 1) & 3)) * 8;
  const int arow = wm * 64 + l15;   // + m*16
  const int brow = wn * 64 + l15;   // + n*16

  f32x4 acc[4][4];
  #pragma unroll
  for (int m = 0; m < 4; ++m)
    #pragma unroll
    for (int n = 0; n < 4; ++n)
      acc[m][n] = (f32x4){0.f, 0.f, 0.f, 0.f};

  const int NT = K >> 5;
  stage(0, 0);
  stage(1, 1);

  for (int kt = 0; kt < NT; ++kt) {
    const int buf = kt & 1;
    // tile kt's 3 loads landed; kt+1's stay in flight
    if (kt + 1 < NT) asm volatile("s_waitcnt vmcnt(3)" ::: "memory");
    else             asm volatile("s_waitcnt vmcnt(0)" ::: "memory");
    __builtin_amdgcn_s_barrier();            // buf[kt] visible to all waves
    __builtin_amdgcn_sched_barrier(0);

    bf16x8 af[4], bfr[4];
    #pragma unroll
    for (int n = 0; n < 4; ++n)
      bfr[n] = *(const bf16x8*)&Bs[buf][(brow + n * 16) * 32 + rd];
    #pragma unroll
    for (int m = 0; m < 4; ++m)
      af[m] = *(const bf16x8*)&As[buf][(arow + m * 16) * 32 + rd];
    asm volatile("s_waitcnt lgkmcnt(0)" ::: "memory");
    __builtin_amdgcn_sched_barrier(0);       // rule #18: pin MFMA below wait
    __builtin_amdgcn_s_barrier();            // all waves done reading buf

    if (kt + 2 < NT) stage(kt + 2, buf);     // overwrite just-freed buffer

    __builtin_amdgcn_s_setprio(1);
    #pragma unroll
    for (int m = 0; m < 4; ++m)
      #pragma unroll
      for (int n = 0; n < 4; ++n)
        acc[m][n] = mfma16(af[m], bfr[n], acc[m][n]);
    __builtin_amdgcn_s_setprio(0);
    __builtin_amdgcn_sched_barrier(0);
  }

  #pragma unroll
  for (int n = 0; n < 4; ++n) {
    const int col = bn * 128 + wn * 64 + n * 16 + l15;
    const float bv = bias[col];
    #pragma unroll
    for (int m = 0; m < 4; ++m) {
      const int row = bm * 256 + wm * 64 + m * 16 + l4 * 4;
      #pragma unroll
      for (int r = 0; r < 4; ++r)
        C[(size_t)(row + r) * ldc + col] = acc[m][n][r] + bv;
    }
  }
}

// ---------------- flash attention (8 waves x 16 q-rows, LDS XOR-swizzled) ----
// grid: (S/128, B*H), block 512 (wave w owns q-rows w*16..w*16+15)
__global__ __launch_bounds__(512) void attn_kernel(
    const bf16* __restrict__ qkv, const bf16* __restrict__ vT,
    const int* __restrict__ tokens, bf16* __restrict__ ctx)
{
  __shared__ bf16 Ks[128 * 64];
  __shared__ bf16 VTs[64 * 128];
  __shared__ bf16 Ps[128 * 128];

  const int qt = blockIdx.x;
  const int bh = blockIdx.y;
  const int b = bh >> 4, h = bh & 15;
  const int t = threadIdx.x, w = t >> 6, l = t & 63;
  const int l15 = l & 15, l4 = l >> 4;
  const int q0 = qt * 128;

  bf16x8 aq[2];
  #pragma unroll
  for (int ks = 0; ks < 2; ++ks)
    aq[ks] = *(const bf16x8*)(qkv +
        (size_t)(b * 1024 + q0 + w * 16 + l15) * 3072 +
        h * 64 + ks * 32 + l4 * 8);

  f32x4 o[4];
  float m_run[4], l_run[4];
  #pragma unroll
  for (int r = 0; r < 4; ++r) { m_run[r] = -1e30f; l_run[r] = 0.f; }
  #pragma unroll
  for (int nn = 0; nn < 4; ++nn)
    o[nn] = (f32x4){0.f, 0.f, 0.f, 0.f};

  const bf16* kb = qkv + (size_t)(b * 1024) * 3072 + 1024 + h * 64;
  const bf16* vb = vT + (size_t)(bh * 64) * 1024;
  const int* tb = tokens + b * 1024;

  // staging swizzle (pre-swizzled global source, linear LDS dest)
  const int kSrcCol = ((t & 7) ^ ((t >> 3) & 7)) * 8;     // K key: row&7
  const int vSrcCol = ((t & 15) ^ ((t >> 4) & 15)) * 8;   // V key: row&15

  for (int jt = 0; jt <= qt; ++jt) {
    const int j0 = jt * 128;
    __syncthreads();  // previous iteration's LDS reads complete
    #pragma unroll
    for (int i = 0; i < 2; ++i)
      gload16(kb + (size_t)(j0 + i * 64 + (t >> 3)) * 3072 + kSrcCol,
              Ks + i * 4096 + w * 512);
    #pragma unroll
    for (int i = 0; i < 2; ++i)
      gload16(vb + (size_t)(i * 32 + (t >> 4)) * 1024 + j0 + vSrcCol,
              VTs + i * 4096 + w * 512);
    __syncthreads();  // staged tiles visible

    // S = Q K^T for this wave's 16 rows x 128 cols
    f32x4 s[8];
    #pragma unroll
    for (int n = 0; n < 8; ++n)
      s[n] = (f32x4){0.f, 0.f, 0.f, 0.f};
    #pragma unroll
    for (int ks = 0; ks < 2; ++ks) {
      #pragma unroll
      for (int n = 0; n < 8; ++n) {
        const bf16x8 bk = *(const bf16x8*)
            &Ks[(n * 16 + l15) * 64 + ((ks * 32 + l4 * 8) ^ ((l15 & 7) * 8))];
        s[n] = mfma16(aq[ks], bk, s[n]);
      }
    }

    float padv[8];
    #pragma unroll
    for (int n = 0; n < 8; ++n)
      padv[n] = (tb[j0 + n * 16 + l15] == 0) ? 1.f : 0.f;

    // online softmax per q-row; write P to LDS (swizzled, wave-local rows)
    #pragma unroll
    for (int r = 0; r < 4; ++r) {
      const int rloc = l4 * 4 + r;
      const int qrow = q0 + w * 16 + rloc;
      float vals[8];
      float mx = -1e30f;
      #pragma unroll
      for (int n = 0; n < 8; ++n) {
        const int jg = j0 + n * 16 + l15;
        float v = s[n][r] * 0.125f;
        if (jg > qrow || padv[n] != 0.f) v = -1e9f;
        vals[n] = v;
        mx = fmaxf(mx, v);
      }
      #pragma unroll
      for (int d = 1; d < 16; d <<= 1) mx = fmaxf(mx, __shfl_xor(mx, d));
      const float newm = fmaxf(m_run[r], mx);
      const float sc = __expf(m_run[r] - newm);
      m_run[r] = newm;
      float rs = 0.f;
      #pragma unroll
      for (int n = 0; n < 8; ++n) {
        const float pv = __expf(vals[n] - newm);
        vals[n] = pv;
        rs += pv;
      }
      #pragma unroll
      for (int d = 1; d < 16; d <<= 1) rs += __shfl_xor(rs, d);
      l_run[r] = l_run[r] * sc + rs;
      #pragma unroll
      for (int nn = 0; nn < 4; ++nn) o[nn][r] = o[nn][r] * sc;
      #pragma unroll
      for (int n = 0; n < 8; ++n)
        Ps[(w * 16 + rloc) * 128 + ((n * 16 + l15) ^ (rloc * 8))] = f2b(vals[n]);
    }
    // wave-local P rows: only need our own ds_writes complete (no block barrier)
    asm volatile("s_waitcnt lgkmcnt(0)" ::: "memory");

    // O += P V
    #pragma unroll
    for (int ks = 0; ks < 4; ++ks) {
      const bf16x8 ap = *(const bf16x8*)
          &Ps[(w * 16 + l15) * 128 + ((ks * 32 + l4 * 8) ^ (l15 * 8))];
      #pragma unroll
      for (int nn = 0; nn < 4; ++nn) {
        const bf16x8 bv = *(const bf16x8*)
            &VTs[(nn * 16 + l15) * 128 + ((ks * 32 + l4 * 8) ^ (l15 * 8))];
        o[nn] = mfma16(ap, bv, o[nn]);
      }
    }
  }

  // epilogue: ctx = O / l
  #pragma unroll
  for (int r = 0; r < 4; ++r) {
    const float inv = 1.0f / l_run[r];
    const int qrow = q0 + w * 16 + l4 * 4 + r;
    #pragma unroll
    for (int nn = 0; nn < 4; ++nn)
      ctx[(size_t)(b * 1024 + qrow) * 1024 + h * 64 + nn * 16 + l15] =
          f2b(o[nn][r] * inv);
  }
}

// ------------- fixup for all-masked rows (leading pad tokens) -------------
__global__ __launch_bounds__(64) void attn_fixup_kernel(
    const int* __restrict__ tokens, const bf16* __restrict__ vT,
    bf16* __restrict__ ctx)
{
  const int bh = blockIdx.x;
  const int b = bh >> 4, h = bh & 15;
  __shared__ int p0s;
  if (threadIdx.x == 0) {
    int p = 0;
    const int* tb = tokens + b * 1024;
    while (p < 1024 && tb[p] == 0) ++p;
    p0s = p;
  }
  __syncthreads();
  const int P0 = p0s;
  if (P0 == 0) return;
  const int dk = threadIdx.x;
  const bf16* vrow = vT + (size_t)(bh * 64 + dk) * 1024;
  float sum = 0.f;
  for (int sIdx = 0; sIdx < 1024; ++sIdx) sum += b2f(vrow[sIdx]);
  const bf16 mv = f2b(sum * (1.0f / 1024.0f));
  for (int q = 0; q < P0; ++q)
    ctx[(size_t)(b * 1024 + q) * 1024 + h * 64 + dk] = mv;
}

// ---------------- host ----------------
extern "C" void kernel_launch(void* const* d_in, const int* in_sizes, int n_in,
                              void* d_out, int out_size, void* d_ws, size_t ws_size,
                              hipStream_t stream)
{
  (void)in_sizes; (void)n_in; (void)out_size;
  const int*   tokens = (const int*)d_in[0];
  const float* emb  = (const float*)d_in[1];
  const float* pe   = (const float*)d_in[2];
  const float* Wq   = (const float*)d_in[3];
  const float* Wk   = (const float*)d_in[4];
  const float* Wv   = (const float*)d_in[5];
  const float* Wo   = (const float*)d_in[6];
  const float* bo   = (const float*)d_in[7];
  const float* g1   = (const float*)d_in[8];
  const float* be1  = (const float*)d_in[9];
  const float* g2   = (const float*)d_in[10];
  const float* be2  = (const float*)d_in[11];
  const float* W1   = (const float*)d_in[12];
  const float* b1   = (const float*)d_in[13];
  const float* W2   = (const float*)d_in[14];
  const float* b2   = (const float*)d_in[15];
  const float* gf   = (const float*)d_in[16];
  const float* bff  = (const float*)d_in[17];
  const float* Wout = (const float*)d_in[18];
  const float* bout = (const float*)d_in[19];
  float* out = (float*)d_out;

  char* p = (char*)d_ws;
  auto alloc = [&](size_t bytes) {
    char* q = p;
    p += (bytes + 255) & ~(size_t)255;
    return q;
  };
  float* x    = (float*)alloc((size_t)2048 * 1024 * 4);
  bf16* Pp    = (bf16*)alloc((size_t)4 * 2048 * 1024 * 2);  // bf16 K-slice partials
  bf16* h     = (bf16*)alloc((size_t)2048 * 1024 * 2);
  bf16* qkv   = (bf16*)alloc((size_t)2048 * 3072 * 2);
  bf16* vT    = (bf16*)alloc((size_t)2048 * 1024 * 2);
  bf16* ctx   = (bf16*)alloc((size_t)2048 * 1024 * 2);
  bf16* ff    = (bf16*)alloc((size_t)2048 * 4096 * 2);
  bf16* WoutT = (bf16*)alloc((size_t)32000 * 1024 * 2);

  const size_t DD = (size_t)1024 * 1024;
  const size_t DF = (size_t)1024 * 4096;

  const size_t perLayerW = (3 * DD + DD + DF + DF) * 2;
  const size_t used = (size_t)(p - (char*)d_ws);
  const bool fullprep = ws_size >= used + 6 * perLayerW + 8192;
  const int NL = fullprep ? 6 : 1;
  bf16* WqkvT = (bf16*)alloc((size_t)NL * 3 * DD * 2);
  bf16* WoT   = (bf16*)alloc((size_t)NL * DD * 2);
  bf16* W1T   = (bf16*)alloc((size_t)NL * DF * 2);
  bf16* W2T   = (bf16*)alloc((size_t)NL * DF * 2);

  if (fullprep)
    prep_all_kernel<<<6 * 3072, 256, 0, stream>>>(
        Wq, Wk, Wv, Wo, W1, W2, WqkvT, WoT, W1T, W2T);

  embed_kernel<<<2048, 256, 0, stream>>>(tokens, emb, pe, x);

  for (int l = 0; l < 6; ++l) {
    const bf16* wqkvt; const bf16* wot; const bf16* w1t; const bf16* w2t;
    if (fullprep) {
      wqkvt = WqkvT + (size_t)l * 3 * DD;
      wot   = WoT   + (size_t)l * DD;
      w1t   = W1T   + (size_t)l * DF;
      w2t   = W2T   + (size_t)l * DF;
    } else {
      prep_layer_kernel<<<3072, 256, 0, stream>>>(
          Wq + l * DD, Wk + l * DD, Wv + l * DD, Wo + l * DD,
          W1 + l * DF, W2 + l * DF, WqkvT, WoT, W1T, W2T);
      wqkvt = WqkvT; wot = WoT; w1t = W1T; w2t = W2T;
    }

    // ln1: layer 0 plain; later layers fold the previous FFN2 partials (np=4)
    if (l == 0)
      ln_kernel<<<2048, 256, 0, stream>>>(x, g1, be1, h);
    else
      ln_res_kernel<<<2048, 256, 0, stream>>>(
          x, Pp, 4, b2 + (l - 1) * 1024, g1 + l * 1024, be1 + l * 1024, h);

    // QKV: M=2048 N=3072 K=1024 -> 384 blocks; fused V-transpose epilogue
    gemm_pl<4, 0><<<dim3(16, 24, 1), 256, 0, stream>>>(
        h, 1024, wqkvt, 1024, qkv, 3072, (const float*)nullptr, vT, 1024);
    attn_kernel<<<dim3(8, 32), 512, 0, stream>>>(qkv, vT, tokens, ctx);
    attn_fixup_kernel<<<32, 64, 0, stream>>>(tokens, vT, ctx);
    // Wo: M=2048 N=1024 K=1024, splitK4 -> 512 blocks, bf16 partials
    gemm_pl<3, 0><<<dim3(16, 8, 4), 256, 0, stream>>>(
        ctx, 1024, wot, 1024, Pp, 1024, (const float*)nullptr,
        (bf16*)nullptr, 256);
    // ln2: x += sum(P0..3) + bo; h = LN(x)
    ln_res_kernel<<<2048, 256, 0, stream>>>(
        x, Pp, 4, bo + l * 1024, g2 + l * 1024, be2 + l * 1024, h);
    // FFN1: M=2048 N=4096 K=1024 -> 512 blocks
    gemm_pl<2, 0><<<dim3(16, 32, 1), 256, 0, stream>>>(
        h, 1024, w1t, 1024, ff, 4096, b1 + l * 4096, (bf16*)nullptr, 1024);
    // FFN2: M=2048 N=1024 K=4096, splitK4 -> 512 blocks, bf16 partials
    gemm_pl<3, 0><<<dim3(16, 8, 4), 256, 0, stream>>>(
        ff, 4096, w2t, 4096, Pp, 1024, (const float*)nullptr,
        (bf16*)nullptr, 1024);
  }

  // final LN folds layer-5 FFN2 partials
  ln_res_kernel<<<2048, 256, 0, stream>>>(x, Pp, 4, b2 + 5 * 1024, gf, bff, h);
  transpose_cast_kernel<<<dim3(500, 16), 256, 0, stream>>>(Wout, WoutT, 32000, 1024);
  // logits: M=2048 N=32000 K=1024 -> 256x128 occupancy-first, 2000 blocks
  gemm256<<<dim3(8, 250), 512, 0, stream>>>(
      h, 1024, WoutT, 1024, out, 32000, bout, 1024);
}

// Round 12
// 1223.411 us; speedup vs baseline: 1.3467x; 1.0122x over previous
//
#include <hip/hip_runtime.h>
#include <hip/hip_bf16.h>
#include <stdint.h>

typedef __hip_bfloat16 bf16;
typedef __attribute__((ext_vector_type(8))) short bf16x8;
typedef __attribute__((ext_vector_type(4))) float f32x4;

#define DEV static __device__ __forceinline__

DEV float b2f(bf16 v) { return __bfloat162float(v); }
DEV bf16  f2b(float v) { return __float2bfloat16(v); }

DEV float u2f(unsigned short u) {
  unsigned int x = (unsigned int)u << 16;
  float f;
  __builtin_memcpy(&f, &x, 4);
  return f;
}

DEV unsigned short f2u(float v) {
  bf16 b = f2b(v);
  unsigned short u;
  __builtin_memcpy(&u, &b, 2);
  return u;
}

DEV void gload16(const void* g, void* l) {
  __builtin_amdgcn_global_load_lds(
      (__attribute__((address_space(1))) void*)(void*)g,
      (__attribute__((address_space(3))) void*)l, 16, 0, 0);
}

DEV f32x4 mfma16(bf16x8 a, bf16x8 b, f32x4 c) {
  return __builtin_amdgcn_mfma_f32_16x16x32_bf16(a, b, c, 0, 0, 0);
}

// ---------------- embed: x = emb[tok]*32 + pe (all f32) ----------------
__global__ __launch_bounds__(256) void embed_kernel(
    const int* __restrict__ tok, const float* __restrict__ emb,
    const float* __restrict__ pe, float* __restrict__ x)
{
  const int r = blockIdx.x, t = threadIdx.x;
  const int s = r & 1023;
  const int tk = tok[r];
  const int d = t * 4;
  const float* ep = emb + (size_t)tk * 1024 + d;
  const float* pp = pe + (size_t)s * 1024 + d;
  float* xp = x + (size_t)r * 1024 + d;
  #pragma unroll
  for (int j = 0; j < 4; ++j)
    xp[j] = ep[j] * 32.0f + pp[j];
}

// ---------------- layernorm: h = LN(x)*g + b (f32 in, bf16 out) ----------------
__global__ __launch_bounds__(256) void ln_kernel(
    const float* __restrict__ x, const float* __restrict__ g,
    const float* __restrict__ be, bf16* __restrict__ h)
{
  const int r = blockIdx.x, t = threadIdx.x;
  const float4 v = ((const float4*)(x + (size_t)r * 1024))[t];
  float s  = v.x + v.y + v.z + v.w;
  float sq = v.x * v.x + v.y * v.y + v.z * v.z + v.w * v.w;
  #pragma unroll
  for (int d = 1; d < 64; d <<= 1) {
    s  += __shfl_xor(s, d);
    sq += __shfl_xor(sq, d);
  }
  __shared__ float red[8];
  const int w = t >> 6, l = t & 63;
  if (l == 0) { red[w] = s; red[4 + w] = sq; }
  __syncthreads();
  s  = red[0] + red[1] + red[2] + red[3];
  sq = red[4] + red[5] + red[6] + red[7];
  const float mean = s * (1.0f / 1024.0f);
  const float var  = sq * (1.0f / 1024.0f) - mean * mean;
  const float inv  = 1.0f / sqrtf(var + 1e-5f);
  bf16* hp = h + (size_t)r * 1024 + t * 4;
  const float* gp = g + t * 4;
  const float* bp = be + t * 4;
  const float vv[4] = {v.x, v.y, v.z, v.w};
  #pragma unroll
  for (int j = 0; j < 4; ++j)
    hp[j] = f2b((vv[j] - mean) * inv * gp[j] + bp[j]);
}

// -- fused residual + layernorm: x += sum(bf16 P[0..np)) + bias; h = LN(x)*g+be
__global__ __launch_bounds__(256) void ln_res_kernel(
    float* __restrict__ x, const bf16* __restrict__ P, int np,
    const float* __restrict__ bias, const float* __restrict__ g,
    const float* __restrict__ be, bf16* __restrict__ h)
{
  const int r = blockIdx.x, t = threadIdx.x;
  float4 v = ((const float4*)(x + (size_t)r * 1024))[t];
  for (int i = 0; i < np; ++i) {
    const ushort4 pv = ((const ushort4*)(P + ((size_t)i * 2048 + r) * 1024))[t];
    v.x += u2f(pv.x); v.y += u2f(pv.y); v.z += u2f(pv.z); v.w += u2f(pv.w);
  }
  const float4 bv = ((const float4*)bias)[t];
  v.x += bv.x; v.y += bv.y; v.z += bv.z; v.w += bv.w;

  float s  = v.x + v.y + v.z + v.w;
  float sq = v.x * v.x + v.y * v.y + v.z * v.z + v.w * v.w;
  #pragma unroll
  for (int d = 1; d < 64; d <<= 1) {
    s  += __shfl_xor(s, d);
    sq += __shfl_xor(sq, d);
  }
  __shared__ float red[8];
  const int w = t >> 6, l = t & 63;
  if (l == 0) { red[w] = s; red[4 + w] = sq; }
  __syncthreads();
  s  = red[0] + red[1] + red[2] + red[3];
  sq = red[4] + red[5] + red[6] + red[7];
  const float mean = s * (1.0f / 1024.0f);
  const float var  = sq * (1.0f / 1024.0f) - mean * mean;
  const float inv  = 1.0f / sqrtf(var + 1e-5f);

  ((float4*)(x + (size_t)r * 1024))[t] = v;
  bf16* hp = h + (size_t)r * 1024 + t * 4;
  const float* gp = g + t * 4;
  const float* bp = be + t * 4;
  const float vv[4] = {v.x, v.y, v.z, v.w};
  #pragma unroll
  for (int j = 0; j < 4; ++j)
    hp[j] = f2b((vv[j] - mean) * inv * gp[j] + bp[j]);
}

// ------------- 64x64 transpose+cast tile body -------------
DEV void transpose_tile(const float* __restrict__ in, bf16* __restrict__ out,
                        int ldin, int ldout, int r0, int c0, int t)
{
  __shared__ bf16 tile[64][64];
  #pragma unroll
  for (int i = 0; i < 4; ++i) {
    const int r = i * 16 + (t >> 4), c = (t & 15) * 4;
    const float4 v = *(const float4*)&in[(size_t)(r0 + r) * ldin + c0 + c];
    tile[r][c + 0] = f2b(v.x);
    tile[r][c + 1] = f2b(v.y);
    tile[r][c + 2] = f2b(v.z);
    tile[r][c + 3] = f2b(v.w);
  }
  __syncthreads();
  #pragma unroll
  for (int i = 0; i < 2; ++i) {
    const int oc = i * 32 + (t >> 3);
    const int rr = (t & 7) * 8;
    unsigned short tmp[8] __attribute__((aligned(16)));
    #pragma unroll
    for (int j = 0; j < 8; ++j)
      tmp[j] = ((const unsigned short*)tile)[(rr + j) * 64 + oc];
    *(uint4*)&out[(size_t)(c0 + oc) * ldout + r0 + rr] = *(const uint4*)tmp;
  }
}

// generic single-matrix transpose+cast (used for Wout)
__global__ __launch_bounds__(256) void transpose_cast_kernel(
    const float* __restrict__ in, bf16* __restrict__ out, int ldin, int ldout)
{
  transpose_tile(in, out, ldin, ldout, blockIdx.y * 64, blockIdx.x * 64, threadIdx.x);
}

// dispatch one 64x64 tile of the per-layer weight set (3072 tiles/layer)
DEV void prep_dispatch(int wid,
    const float* Wq, const float* Wk, const float* Wv, const float* Wo,
    const float* W1, const float* W2,
    bf16* WqkvT, bf16* WoT, bf16* W1T, bf16* W2T, int t)
{
  const float* src; bf16* dst; int ldin, ldout, tx, ty;
  if (wid < 768) {
    const int m = wid >> 8, tt = wid & 255;
    src = (m == 0) ? Wq : (m == 1) ? Wk : Wv;
    dst = WqkvT + (size_t)m * 1024 * 1024;
    ldin = 1024; ldout = 1024; tx = tt & 15; ty = tt >> 4;
  } else if (wid < 1024) {
    const int tt = wid - 768;
    src = Wo; dst = WoT; ldin = 1024; ldout = 1024; tx = tt & 15; ty = tt >> 4;
  } else if (wid < 2048) {
    const int tt = wid - 1024;
    src = W1; dst = W1T; ldin = 4096; ldout = 1024; tx = tt & 63; ty = tt >> 6;
  } else {
    const int tt = wid - 2048;
    src = W2; dst = W2T; ldin = 1024; ldout = 4096; tx = tt & 15; ty = tt >> 4;
  }
  transpose_tile(src, dst, ldin, ldout, ty * 64, tx * 64, t);
}

// per-layer weight prep (fallback path)
__global__ __launch_bounds__(256) void prep_layer_kernel(
    const float* __restrict__ Wq, const float* __restrict__ Wk,
    const float* __restrict__ Wv, const float* __restrict__ Wo,
    const float* __restrict__ W1, const float* __restrict__ W2,
    bf16* __restrict__ WqkvT, bf16* __restrict__ WoT,
    bf16* __restrict__ W1T, bf16* __restrict__ W2T)
{
  prep_dispatch(blockIdx.x, Wq, Wk, Wv, Wo, W1, W2,
                WqkvT, WoT, W1T, W2T, threadIdx.x);
}

// all-layers weight prep (when ws permits): 6*3072 blocks
__global__ __launch_bounds__(256) void prep_all_kernel(
    const float* __restrict__ Wq, const float* __restrict__ Wk,
    const float* __restrict__ Wv, const float* __restrict__ Wo,
    const float* __restrict__ W1, const float* __restrict__ W2,
    bf16* __restrict__ WqkvT, bf16* __restrict__ WoT,
    bf16* __restrict__ W1T, bf16* __restrict__ W2T)
{
  const int layer = blockIdx.x / 3072;
  const int wid = blockIdx.x - layer * 3072;
  const size_t DD = (size_t)1024 * 1024, DF = (size_t)1024 * 4096;
  prep_dispatch(wid,
      Wq + layer * DD, Wk + layer * DD, Wv + layer * DD, Wo + layer * DD,
      W1 + layer * DF, W2 + layer * DF,
      WqkvT + layer * 3 * DD, WoT + layer * DD,
      W1T + layer * DF, W2T + layer * DF, threadIdx.x);
}

// ------------- pipelined GEMM: C(MxN) = A(MxK,row) * BT(NxK,row)^T -------------
// BM=BN=128, BK=32; 4-buffer LDS ring, 2 K-tiles per barrier-pair (32 MFMA),
// counted vmcnt(8) (T4), raw barriers, verified conflict-free T2 XOR swizzle.
// EPI: 0 = bf16 store; 1 = +bias f32 store; 2 = gelu(acc+bias) bf16;
//      3 = bf16 K-slice partial store P[z][M][N]; 4 = QKV fused: cols<2048 ->
//          qkv bf16, cols>=2048 -> vT[(b*1024+hk)*1024+s] transposed write
// grid: (M/128, N/128, KSLICES), block 256 (4 waves), K-slice length ksl
template<int EPI, int SWZ>
__global__ __launch_bounds__(256) void gemm_pl(
    const bf16* __restrict__ A, int lda,
    const bf16* __restrict__ BT, int ldb,
    void* __restrict__ Cp, int ldc,
    const float* __restrict__ bias,
    bf16* __restrict__ vTp,
    int ksl)
{
  __shared__ bf16 As[4][4096];
  __shared__ bf16 Bs[4][4096];
  const int t = threadIdx.x;

  int bm, bn;
  if constexpr (SWZ) {                        // XCD-chunked swizzle (nwg%8==0)
    const int nbm = gridDim.x;
    const int nwg = nbm * gridDim.y;
    int wid = blockIdx.x + nbm * blockIdx.y;
    wid = (wid & 7) * (nwg >> 3) + (wid >> 3);
    bm = wid % nbm; bn = wid / nbm;
  } else {
    bm = blockIdx.x; bn = blockIdx.y;
  }

  const int w = t >> 6, l = t & 63;
  const int wr = (w >> 1) * 64, wc = (w & 1) * 64;
  const int l15 = l & 15, l4 = l >> 4;
  const int kbeg = blockIdx.z * ksl;
  const int npairs = ksl >> 6;                // 2 K-tiles per iteration

  // T2: pre-swizzled global column-block; key = (lds_row>>1)&3 = (t>>3)&3
  const int colblk = (((t & 3) ^ ((t >> 3) & 3))) * 8;
  const bf16* gA = A  + (size_t)(bm * 128 + (t >> 2)) * lda + colblk + kbeg;
  const bf16* gB = BT + (size_t)(bn * 128 + (t >> 2)) * ldb + colblk + kbeg;
  const int dst = w * 512;

  auto stage = [&](int tile, int buf) {
    const int k0 = tile * 32;
    gload16(gA + k0, &As[buf][dst]);
    gload16(gA + (size_t)64 * lda + k0, &As[buf][2048 + dst]);
    gload16(gB + k0, &Bs[buf][dst]);
    gload16(gB + (size_t)64 * ldb + k0, &Bs[buf][2048 + dst]);
  };

  f32x4 acc[4][4];
  #pragma unroll
  for (int m = 0; m < 4; ++m)
    #pragma unroll
    for (int n = 0; n < 4; ++n)
      acc[m][n] = (f32x4){0.f, 0.f, 0.f, 0.f};

  // prologue: pairs 0 (bufs 0,1) and 1 (bufs 2,3)
  stage(0, 0); stage(1, 1);
  stage(2, 2); stage(3, 3);

  // T2 read-side swizzle: column-block = l4 ^ ((row>>1)&3); row%16 == l15
  const int rdcol = ((l4 ^ ((l15 >> 1) & 3))) * 8;

  for (int pp = 0; pp < npairs; ++pp) {
    const int base = (pp & 1) << 1;           // bufs base, base+1 hold this pair
    if (pp + 1 < npairs) asm volatile("s_waitcnt vmcnt(8)" ::: "memory");
    else                 asm volatile("s_waitcnt vmcnt(0)" ::: "memory");
    __builtin_amdgcn_s_barrier();             // pair pp resident for all waves
    __builtin_amdgcn_sched_barrier(0);

    bf16x8 af0[4], bf0[4], af1[4], bf1[4];
    #pragma unroll
    for (int m = 0; m < 4; ++m)
      af0[m] = *(const bf16x8*)&As[base][(wr + m * 16 + l15) * 32 + rdcol];
    #pragma unroll
    for (int n = 0; n < 4; ++n)
      bf0[n] = *(const bf16x8*)&Bs[base][(wc + n * 16 + l15) * 32 + rdcol];
    #pragma unroll
    for (int m = 0; m < 4; ++m)
      af1[m] = *(const bf16x8*)&As[base + 1][(wr + m * 16 + l15) * 32 + rdcol];
    #pragma unroll
    for (int n = 0; n < 4; ++n)
      bf1[n] = *(const bf16x8*)&Bs[base + 1][(wc + n * 16 + l15) * 32 + rdcol];
    asm volatile("s_waitcnt lgkmcnt(0)" ::: "memory");
    __builtin_amdgcn_sched_barrier(0);        // rule #18: pin MFMA below wait
    __builtin_amdgcn_s_barrier();             // all waves done reading pair pp

    if (pp + 2 < npairs) {                    // overwrite just-freed bufs
      stage(2 * pp + 4, base);
      stage(2 * pp + 5, base + 1);
    }

    __builtin_amdgcn_s_setprio(1);
    #pragma unroll
    for (int m = 0; m < 4; ++m)
      #pragma unroll
      for (int n = 0; n < 4; ++n)
        acc[m][n] = mfma16(af0[m], bf0[n], acc[m][n]);
    #pragma unroll
    for (int m = 0; m < 4; ++m)
      #pragma unroll
      for (int n = 0; n < 4; ++n)
        acc[m][n] = mfma16(af1[m], bf1[n], acc[m][n]);
    __builtin_amdgcn_s_setprio(0);
    __builtin_amdgcn_sched_barrier(0);
  }

  const int crow = bm * 128 + wr, ccol = bn * 128 + wc;
  #pragma unroll
  for (int n = 0; n < 4; ++n) {
    const int col = ccol + n * 16 + l15;
    float bv = 0.f;
    if (EPI == 1 || EPI == 2) bv = bias[col];
    #pragma unroll
    for (int m = 0; m < 4; ++m) {
      const int row = crow + m * 16 + l4 * 4;
      if (EPI == 4 && ccol >= 2048) {
        // V part: vT[(b*1024 + hk)][s], 4 consecutive s as one 8B store
        const int b = row >> 10, s = row & 1023;
        const int hk = col - 2048;
        ushort4 pk;
        pk.x = f2u(acc[m][n][0]); pk.y = f2u(acc[m][n][1]);
        pk.z = f2u(acc[m][n][2]); pk.w = f2u(acc[m][n][3]);
        *(ushort4*)&vTp[((size_t)b * 1024 + hk) * 1024 + s] = pk;
        continue;
      }
      #pragma unroll
      for (int r = 0; r < 4; ++r) {
        const float v = acc[m][n][r];
        if (EPI == 0 || EPI == 4) {
          ((bf16*)Cp)[(size_t)(row + r) * ldc + col] = f2b(v);
        } else if (EPI == 1) {
          ((float*)Cp)[(size_t)(row + r) * ldc + col] = v + bv;
        } else if (EPI == 2) {
          const float u = v + bv;
          const float gel = 0.5f * u * (1.0f + erff(u * 0.70710678118654752f));
          ((bf16*)Cp)[(size_t)(row + r) * ldc + col] = f2b(gel);
        } else {
          const int M = gridDim.x * 128;
          ((bf16*)Cp)[((size_t)blockIdx.z * M + row + r) * ldc + col] = f2b(v);
        }
      }
    }
  }
}

// ------------- 256x128 8-wave single-barrier GEMM (logits) -------------
// 8 waves as 4m x 2n, per-wave 64x64 output; 3-buffer BK=32 ring (72 KB LDS)
// -> 2 blocks/CU, 4 waves/SIMD. ONE barrier per K-tile: buf (kt+2)%3 was
// last ds_read in iter kt-1, and every wave did lgkmcnt(0) after those reads
// before reaching the barrier at top of kt -> provably dead, no mid-barrier.
// Counted vmcnt(3) (T4). Verified conflict-free XOR swizzle, key=(row>>1)&3.
// grid: (M/256, N/128), nwg % 8 == 0 (XCD swizzle). 512 threads.
__global__ __launch_bounds__(512, 4) void gemm256(
    const bf16* __restrict__ A, int lda,
    const bf16* __restrict__ BT, int ldb,
    float* __restrict__ C, int ldc,
    const float* __restrict__ bias, int K)
{
  __shared__ bf16 As[3][8192];   // 256 rows x 32 cols per buffer
  __shared__ bf16 Bs[3][4096];   // 128 rows x 32 cols per buffer
  const int t = threadIdx.x;

  const int nbm = gridDim.x;
  const int nwg = nbm * gridDim.y;
  int wid = blockIdx.x + nbm * blockIdx.y;
  wid = (wid & 7) * (nwg >> 3) + (wid >> 3);
  const int bm = wid % nbm, bn = wid / nbm;

  const int w = t >> 6, l = t & 63;
  const int wm = w >> 1, wn = w & 1;          // 4m x 2n waves
  const int l15 = l & 15, l4 = l >> 4;

  // staging: thread t -> LDS row (t>>2), col-block (t&3);
  // pre-swizzled global col-block, key (row>>1)&3 = (t>>3)&3
  const int colblk = ((t & 3) ^ ((t >> 3) & 3)) * 8;
  const bf16* gA = A  + (size_t)(bm * 256 + (t >> 2)) * lda + colblk;
  const bf16* gB = BT + (size_t)(bn * 128 + (t >> 2)) * ldb + colblk;
  const int dst = w * 512;

  auto stage = [&](int kt, int buf) {
    const int k0 = kt * 32;
    gload16(gA + k0, &As[buf][dst]);                             // A rows 0..127
    gload16(gA + (size_t)128 * lda + k0, &As[buf][4096 + dst]);  // A rows 128..255
    gload16(gB + k0, &Bs[buf][dst]);                             // B rows 0..127
  };

  // read-side swizzle: col-block = l4 ^ ((row>>1)&3); row%16 == l15
  const int rd = (l4 ^ ((l15 >> 1) & 3)) * 8;
  const int arow = wm * 64 + l15;   // + m*16
  const int brow = wn * 64 + l15;   // + n*16

  f32x4 acc[4][4];
  #pragma unroll
  for (int m = 0; m < 4; ++m)
    #pragma unroll
    for (int n = 0; n < 4; ++n)
      acc[m][n] = (f32x4){0.f, 0.f, 0.f, 0.f};

  const int NT = K >> 5;
  stage(0, 0);
  stage(1, 1);

  int buf = 0;
  for (int kt = 0; kt < NT; ++kt) {
    // tile kt's 3 loads landed; kt+1's 3 stay in flight (never drain mid-loop)
    if (kt + 1 < NT) asm volatile("s_waitcnt vmcnt(3)" ::: "memory");
    else             asm volatile("s_waitcnt vmcnt(0)" ::: "memory");
    __builtin_amdgcn_s_barrier();            // single barrier per K-tile
    __builtin_amdgcn_sched_barrier(0);

    int nb = buf + 2; if (nb >= 3) nb -= 3;  // ring slot freed at end of kt-1

    bf16x8 af[4], bfr[4];
    #pragma unroll
    for (int n = 0; n < 4; ++n)
      bfr[n] = *(const bf16x8*)&Bs[buf][(brow + n * 16) * 32 + rd];
    #pragma unroll
    for (int m = 0; m < 4; ++m)
      af[m] = *(const bf16x8*)&As[buf][(arow + m * 16) * 32 + rd];
    if (kt + 2 < NT) stage(kt + 2, nb);      // overwrite provably-dead buffer
    asm volatile("s_waitcnt lgkmcnt(0)" ::: "memory");
    __builtin_amdgcn_sched_barrier(0);       // rule #18: pin MFMA below wait

    __builtin_amdgcn_s_setprio(1);
    #pragma unroll
    for (int m = 0; m < 4; ++m)
      #pragma unroll
      for (int n = 0; n < 4; ++n)
        acc[m][n] = mfma16(af[m], bfr[n], acc[m][n]);
    __builtin_amdgcn_s_setprio(0);
    __builtin_amdgcn_sched_barrier(0);

    if (++buf >= 3) buf = 0;
  }

  #pragma unroll
  for (int n = 0; n < 4; ++n) {
    const int col = bn * 128 + wn * 64 + n * 16 + l15;
    const float bv = bias[col];
    #pragma unroll
    for (int m = 0; m < 4; ++m) {
      const int row = bm * 256 + wm * 64 + m * 16 + l4 * 4;
      #pragma unroll
      for (int r = 0; r < 4; ++r)
        C[(size_t)(row + r) * ldc + col] = acc[m][n][r] + bv;
    }
  }
}

// ---------------- flash attention (8 waves x 16 q-rows, LDS XOR-swizzled) ----
// grid: (S/128, B*H), block 512 (wave w owns q-rows w*16..w*16+15)
// Fixup for all-masked rows (leading pads) folded into the epilogue.
__global__ __launch_bounds__(512) void attn_kernel(
    const bf16* __restrict__ qkv, const bf16* __restrict__ vT,
    const int* __restrict__ tokens, bf16* __restrict__ ctx)
{
  __shared__ bf16 Ks[128 * 64];
  __shared__ bf16 VTs[64 * 128];
  __shared__ bf16 Ps[128 * 128];

  const int qt = blockIdx.x;
  const int bh = blockIdx.y;
  const int b = bh >> 4, h = bh & 15;
  const int t = threadIdx.x, w = t >> 6, l = t & 63;
  const int l15 = l & 15, l4 = l >> 4;
  const int q0 = qt * 128;

  bf16x8 aq[2];
  #pragma unroll
  for (int ks = 0; ks < 2; ++ks)
    aq[ks] = *(const bf16x8*)(qkv +
        (size_t)(b * 1024 + q0 + w * 16 + l15) * 3072 +
        h * 64 + ks * 32 + l4 * 8);

  f32x4 o[4];
  float m_run[4], l_run[4];
  #pragma unroll
  for (int r = 0; r < 4; ++r) { m_run[r] = -1e30f; l_run[r] = 0.f; }
  #pragma unroll
  for (int nn = 0; nn < 4; ++nn)
    o[nn] = (f32x4){0.f, 0.f, 0.f, 0.f};

  const bf16* kb = qkv + (size_t)(b * 1024) * 3072 + 1024 + h * 64;
  const bf16* vb = vT + (size_t)(bh * 64) * 1024;
  const int* tb = tokens + b * 1024;

  // staging swizzle (pre-swizzled global source, linear LDS dest)
  const int kSrcCol = ((t & 7) ^ ((t >> 3) & 7)) * 8;     // K key: row&7
  const int vSrcCol = ((t & 15) ^ ((t >> 4) & 15)) * 8;   // V key: row&15

  for (int jt = 0; jt <= qt; ++jt) {
    const int j0 = jt * 128;
    __syncthreads();  // previous iteration's LDS reads complete
    #pragma unroll
    for (int i = 0; i < 2; ++i)
      gload16(kb + (size_t)(j0 + i * 64 + (t >> 3)) * 3072 + kSrcCol,
              Ks + i * 4096 + w * 512);
    #pragma unroll
    for (int i = 0; i < 2; ++i)
      gload16(vb + (size_t)(i * 32 + (t >> 4)) * 1024 + j0 + vSrcCol,
              VTs + i * 4096 + w * 512);
    __syncthreads();  // staged tiles visible

    // S = Q K^T for this wave's 16 rows x 128 cols
    f32x4 s[8];
    #pragma unroll
    for (int n = 0; n < 8; ++n)
      s[n] = (f32x4){0.f, 0.f, 0.f, 0.f};
    #pragma unroll
    for (int ks = 0; ks < 2; ++ks) {
      #pragma unroll
      for (int n = 0; n < 8; ++n) {
        const bf16x8 bk = *(const bf16x8*)
            &Ks[(n * 16 + l15) * 64 + ((ks * 32 + l4 * 8) ^ ((l15 & 7) * 8))];
        s[n] = mfma16(aq[ks], bk, s[n]);
      }
    }

    float padv[8];
    #pragma unroll
    for (int n = 0; n < 8; ++n)
      padv[n] = (tb[j0 + n * 16 + l15] == 0) ? 1.f : 0.f;

    // online softmax per q-row; write P to LDS (swizzled, wave-local rows)
    #pragma unroll
    for (int r = 0; r < 4; ++r) {
      const int rloc = l4 * 4 + r;
      const int qrow = q0 + w * 16 + rloc;
      float vals[8];
      float mx = -1e30f;
      #pragma unroll
      for (int n = 0; n < 8; ++n) {
        const int jg = j0 + n * 16 + l15;
        float v = s[n][r] * 0.125f;
        if (jg > qrow || padv[n] != 0.f) v = -1e9f;
        vals[n] = v;
        mx = fmaxf(mx, v);
      }
      #pragma unroll
      for (int d = 1; d < 16; d <<= 1) mx = fmaxf(mx, __shfl_xor(mx, d));
      const float newm = fmaxf(m_run[r], mx);
      const float sc = __expf(m_run[r] - newm);
      m_run[r] = newm;
      float rs = 0.f;
      #pragma unroll
      for (int n = 0; n < 8; ++n) {
        const float pv = __expf(vals[n] - newm);
        vals[n] = pv;
        rs += pv;
      }
      #pragma unroll
      for (int d = 1; d < 16; d <<= 1) rs += __shfl_xor(rs, d);
      l_run[r] = l_run[r] * sc + rs;
      #pragma unroll
      for (int nn = 0; nn < 4; ++nn) o[nn][r] = o[nn][r] * sc;
      #pragma unroll
      for (int n = 0; n < 8; ++n)
        Ps[(w * 16 + rloc) * 128 + ((n * 16 + l15) ^ (rloc * 8))] = f2b(vals[n]);
    }
    // wave-local P rows: only need our own ds_writes complete (no block barrier)
    asm volatile("s_waitcnt lgkmcnt(0)" ::: "memory");

    // O += P V
    #pragma unroll
    for (int ks = 0; ks < 4; ++ks) {
      const bf16x8 ap = *(const bf16x8*)
          &Ps[(w * 16 + l15) * 128 + ((ks * 32 + l4 * 8) ^ (l15 * 8))];
      #pragma unroll
      for (int nn = 0; nn < 4; ++nn) {
        const bf16x8 bv = *(const bf16x8*)
            &VTs[(nn * 16 + l15) * 128 + ((ks * 32 + l4 * 8) ^ (l15 * 8))];
        o[nn] = mfma16(ap, bv, o[nn]);
      }
    }
  }

  // epilogue: ctx = O / l
  #pragma unroll
  for (int r = 0; r < 4; ++r) {
    const float inv = 1.0f / l_run[r];
    const int qrow = q0 + w * 16 + l4 * 4 + r;
    #pragma unroll
    for (int nn = 0; nn < 4; ++nn)
      ctx[(size_t)(b * 1024 + qrow) * 1024 + h * 64 + nn * 16 + l15] =
          f2b(o[nn][r] * inv);
  }

  // fused fixup: rows < P0 (leading pads) -> ctx = mean over all S of V.
  // P0 = first-nonzero token index, computed by 16-token/lane scan + wave-min.
  int loc = 1024;
  #pragma unroll 4
  for (int j = 0; j < 16; ++j) {
    const int idx = l * 16 + j;
    if (tb[idx] != 0) { loc = idx; break; }
  }
  #pragma unroll
  for (int d = 1; d < 64; d <<= 1) {
    const int o2 = __shfl_xor(loc, d);
    loc = (o2 < loc) ? o2 : loc;
  }
  const int P0 = loc;                        // block-uniform
  if (P0 > q0) {
    __syncthreads();                         // order WAW on ctx vs epilogue
    const int rbeg = q0 + w * 16;
    if (P0 > rbeg) {
      // lane l owns dk=l: mean of vT[(bh*64+l)][0..1024)
      const bf16* vrow = vb + (size_t)l * 1024;
      float sum = 0.f;
      for (int sIdx = 0; sIdx < 1024; sIdx += 4) {
        const ushort4 pv = *(const ushort4*)&vrow[sIdx];
        sum += u2f(pv.x) + u2f(pv.y) + u2f(pv.z) + u2f(pv.w);
      }
      const bf16 mv = f2b(sum * (1.0f / 1024.0f));
      const int rend = (P0 < rbeg + 16) ? P0 : (rbeg + 16);
      for (int q = rbeg; q < rend; ++q)
        ctx[(size_t)(b * 1024 + q) * 1024 + h * 64 + l] = mv;
    }
  }
}

// ---------------- host ----------------
extern "C" void kernel_launch(void* const* d_in, const int* in_sizes, int n_in,
                              void* d_out, int out_size, void* d_ws, size_t ws_size,
                              hipStream_t stream)
{
  (void)in_sizes; (void)n_in; (void)out_size;
  const int*   tokens = (const int*)d_in[0];
  const float* emb  = (const float*)d_in[1];
  const float* pe   = (const float*)d_in[2];
  const float* Wq   = (const float*)d_in[3];
  const float* Wk   = (const float*)d_in[4];
  const float* Wv   = (const float*)d_in[5];
  const float* Wo   = (const float*)d_in[6];
  const float* bo   = (const float*)d_in[7];
  const float* g1   = (const float*)d_in[8];
  const float* be1  = (const float*)d_in[9];
  const float* g2   = (const float*)d_in[10];
  const float* be2  = (const float*)d_in[11];
  const float* W1   = (const float*)d_in[12];
  const float* b1   = (const float*)d_in[13];
  const float* W2   = (const float*)d_in[14];
  const float* b2   = (const float*)d_in[15];
  const float* gf   = (const float*)d_in[16];
  const float* bff  = (const float*)d_in[17];
  const float* Wout = (const float*)d_in[18];
  const float* bout = (const float*)d_in[19];
  float* out = (float*)d_out;

  char* p = (char*)d_ws;
  auto alloc = [&](size_t bytes) {
    char* q = p;
    p += (bytes + 255) & ~(size_t)255;
    return q;
  };
  float* x    = (float*)alloc((size_t)2048 * 1024 * 4);
  bf16* Pp    = (bf16*)alloc((size_t)4 * 2048 * 1024 * 2);  // bf16 K-slice partials
  bf16* h     = (bf16*)alloc((size_t)2048 * 1024 * 2);
  bf16* qkv   = (bf16*)alloc((size_t)2048 * 3072 * 2);
  bf16* vT    = (bf16*)alloc((size_t)2048 * 1024 * 2);
  bf16* ctx   = (bf16*)alloc((size_t)2048 * 1024 * 2);
  bf16* ff    = (bf16*)alloc((size_t)2048 * 4096 * 2);
  bf16* WoutT = (bf16*)alloc((size_t)32000 * 1024 * 2);

  const size_t DD = (size_t)1024 * 1024;
  const size_t DF = (size_t)1024 * 4096;

  const size_t perLayerW = (3 * DD + DD + DF + DF) * 2;
  const size_t used = (size_t)(p - (char*)d_ws);
  const bool fullprep = ws_size >= used + 6 * perLayerW + 8192;
  const int NL = fullprep ? 6 : 1;
  bf16* WqkvT = (bf16*)alloc((size_t)NL * 3 * DD * 2);
  bf16* WoT   = (bf16*)alloc((size_t)NL * DD * 2);
  bf16* W1T   = (bf16*)alloc((size_t)NL * DF * 2);
  bf16* W2T   = (bf16*)alloc((size_t)NL * DF * 2);

  if (fullprep)
    prep_all_kernel<<<6 * 3072, 256, 0, stream>>>(
        Wq, Wk, Wv, Wo, W1, W2, WqkvT, WoT, W1T, W2T);

  embed_kernel<<<2048, 256, 0, stream>>>(tokens, emb, pe, x);

  for (int l = 0; l < 6; ++l) {
    const bf16* wqkvt; const bf16* wot; const bf16* w1t; const bf16* w2t;
    if (fullprep) {
      wqkvt = WqkvT + (size_t)l * 3 * DD;
      wot   = WoT   + (size_t)l * DD;
      w1t   = W1T   + (size_t)l * DF;
      w2t   = W2T   + (size_t)l * DF;
    } else {
      prep_layer_kernel<<<3072, 256, 0, stream>>>(
          Wq + l * DD, Wk + l * DD, Wv + l * DD, Wo + l * DD,
          W1 + l * DF, W2 + l * DF, WqkvT, WoT, W1T, W2T);
      wqkvt = WqkvT; wot = WoT; w1t = W1T; w2t = W2T;
    }

    // ln1: layer 0 plain; later layers fold the previous FFN2 partials (np=4)
    if (l == 0)
      ln_kernel<<<2048, 256, 0, stream>>>(x, g1, be1, h);
    else
      ln_res_kernel<<<2048, 256, 0, stream>>>(
          x, Pp, 4, b2 + (l - 1) * 1024, g1 + l * 1024, be1 + l * 1024, h);

    // QKV: M=2048 N=3072 K=1024 -> 384 blocks; fused V-transpose epilogue
    gemm_pl<4, 0><<<dim3(16, 24, 1), 256, 0, stream>>>(
        h, 1024, wqkvt, 1024, qkv, 3072, (const float*)nullptr, vT, 1024);
    attn_kernel<<<dim3(8, 32), 512, 0, stream>>>(qkv, vT, tokens, ctx);
    // Wo: M=2048 N=1024 K=1024, splitK4 -> 512 blocks, bf16 partials
    gemm_pl<3, 0><<<dim3(16, 8, 4), 256, 0, stream>>>(
        ctx, 1024, wot, 1024, Pp, 1024, (const float*)nullptr,
        (bf16*)nullptr, 256);
    // ln2: x += sum(P0..3) + bo; h = LN(x)
    ln_res_kernel<<<2048, 256, 0, stream>>>(
        x, Pp, 4, bo + l * 1024, g2 + l * 1024, be2 + l * 1024, h);
    // FFN1: M=2048 N=4096 K=1024 -> 512 blocks
    gemm_pl<2, 0><<<dim3(16, 32, 1), 256, 0, stream>>>(
        h, 1024, w1t, 1024, ff, 4096, b1 + l * 4096, (bf16*)nullptr, 1024);
    // FFN2: M=2048 N=1024 K=4096, splitK4 -> 512 blocks, bf16 partials
    gemm_pl<3, 0><<<dim3(16, 8, 4), 256, 0, stream>>>(
        ff, 4096, w2t, 4096, Pp, 1024, (const float*)nullptr,
        (bf16*)nullptr, 1024);
  }

  // final LN folds layer-5 FFN2 partials
  ln_res_kernel<<<2048, 256, 0, stream>>>(x, Pp, 4, b2 + 5 * 1024, gf, bff, h);
  transpose_cast_kernel<<<dim3(500, 16), 256, 0, stream>>>(Wout, WoutT, 32000, 1024);
  // logits: M=2048 N=32000 K=1024 -> 256x128 single-barrier ring, 2000 blocks
  gemm256<<<dim3(8, 250), 512, 0, stream>>>(
      h, 1024, WoutT, 1024, out, 32000, bout, 1024);
}